// Round 1
// baseline (1398.967 us; speedup 1.0000x reference)
//
#include <hip/hip_runtime.h>

#define U_CNT 50000
#define I_CNT 50000
#define N_NODES 100000
#define DD 128
#define T_STEPS 3
#define E_CNT 3200000
#define B_SZ 4096

// ---------------- CSR build ----------------
__global__ void k_hist(const int* __restrict__ dst, int* __restrict__ cnt, int E) {
    int i = blockIdx.x * blockDim.x + threadIdx.x;
    int stride = gridDim.x * blockDim.x;
    for (; i < E; i += stride) atomicAdd(&cnt[dst[i]], 1);
}

__global__ void __launch_bounds__(1024) k_scan(const int* __restrict__ cnt,
                                               int* __restrict__ row_ptr,
                                               int* __restrict__ cursor, int n) {
    __shared__ int lds[1024];
    int tid = threadIdx.x;
    const int CH = (n + 1023) / 1024;
    int s0 = tid * CH;
    int s1 = min(n, s0 + CH);
    int mysum = 0;
    for (int i = s0; i < s1; ++i) mysum += cnt[i];
    lds[tid] = mysum;
    __syncthreads();
    for (int off = 1; off < 1024; off <<= 1) {
        int add = (tid >= off) ? lds[tid - off] : 0;
        __syncthreads();
        lds[tid] += add;
        __syncthreads();
    }
    if (tid == 1023) row_ptr[n] = lds[1023];
    int run = lds[tid] - mysum;  // exclusive prefix of this thread's chunk
    for (int i = s0; i < s1; ++i) {
        row_ptr[i] = run;
        cursor[i] = run;
        run += cnt[i];
    }
}

__global__ void k_scatter(const int* __restrict__ dst, const int* __restrict__ src,
                          const float* __restrict__ val, int* __restrict__ cursor,
                          int2* __restrict__ pack, int E) {
    int i = blockIdx.x * blockDim.x + threadIdx.x;
    int stride = gridDim.x * blockDim.x;
    for (; i < E; i += stride) {
        int d = dst[i];
        int pos = atomicAdd(&cursor[d], 1);
        pack[pos] = make_int2(src[i], __float_as_int(val[i]));
    }
}

// u_t = temporal_emb[t] @ W0  (tiny)
__global__ void k_uvec(const float* __restrict__ temb, const float* __restrict__ w0,
                       float* __restrict__ u) {
    int k = threadIdx.x;  // 0..127
    for (int t = 0; t < T_STEPS; ++t) {
        float acc = 0.f;
        for (int j = 0; j < DD; ++j) acc += temb[t * DD + j] * w0[j * DD + k];
        u[t * DD + k] = acc;
    }
}

// ---------------- full SpMM: P = A*S, r = A*1 (one wave per dst row) ----------------
__global__ void __launch_bounds__(256) k_spmm_full(const int* __restrict__ row_ptr,
                                                   const int2* __restrict__ pack,
                                                   const float* __restrict__ S,
                                                   float* __restrict__ P,
                                                   float* __restrict__ rvec) {
    int wave = (int)((blockIdx.x * blockDim.x + threadIdx.x) >> 6);
    int lane = threadIdx.x & 63;
    if (wave >= N_NODES) return;
    int beg = row_ptr[wave];
    int end = row_ptr[wave + 1];
    float2 acc = {0.f, 0.f};
    float vs = 0.f;
    for (int e = beg; e < end; ++e) {
        int2 p = pack[e];
        float v = __int_as_float(p.y);
        const float2 srow = *reinterpret_cast<const float2*>(&S[(size_t)p.x * DD + 2 * lane]);
        acc.x += v * srow.x;
        acc.y += v * srow.y;
        vs += v;
    }
    *reinterpret_cast<float2*>(&P[(size_t)wave * DD + 2 * lane]) = acc;
    if (lane == 0) rvec[wave] = vs;
}

// ---------------- GEMM: out = h @ W, h built in prologue ----------------
// MODE 0: h = x (concat tables).  MODE 1: h = relu(P + r*u_t + b0)
template <int MODE>
__global__ void __launch_bounds__(256) k_gemm(const float* __restrict__ inA,
                                              const float* __restrict__ inB,
                                              const float* __restrict__ W,
                                              const float* __restrict__ rv,
                                              const float* __restrict__ uv,
                                              const float* __restrict__ bias,
                                              float* __restrict__ out) {
    __shared__ float wlds[DD * DD];      // 64 KB
    __shared__ float hlds[4][4][DD];     // 8 KB (per-wave private slices)
    __shared__ float ub[2][DD];          // u_t, b0
    int tid = threadIdx.x;
    for (int i = tid; i < DD * DD / 4; i += 256)
        reinterpret_cast<float4*>(wlds)[i] = reinterpret_cast<const float4*>(W)[i];
    if (MODE == 1 && tid < DD) {
        ub[0][tid] = uv[tid];
        ub[1][tid] = bias[tid];
    }
    __syncthreads();
    int wave = tid >> 6, lane = tid & 63;
    const int ntiles = (N_NODES + 15) / 16;
    for (int tile = blockIdx.x; tile < ntiles; tile += gridDim.x) {
        int rbase = tile * 16 + wave * 4;
        // phase A: build h rows in LDS
        for (int j = 0; j < 4; ++j) {
            int row = rbase + j;
            float h0 = 0.f, h1 = 0.f;
            if (row < N_NODES) {
                if (MODE == 0) {
                    const float* x = (row < U_CNT) ? &inA[(size_t)row * DD]
                                                   : &inB[(size_t)(row - U_CNT) * DD];
                    h0 = x[lane];
                    h1 = x[lane + 64];
                } else {
                    float rr = rv[row];
                    float p0 = inA[(size_t)row * DD + lane];
                    float p1 = inA[(size_t)row * DD + lane + 64];
                    h0 = fmaxf(p0 + rr * ub[0][lane] + ub[1][lane], 0.f);
                    h1 = fmaxf(p1 + rr * ub[0][lane + 64] + ub[1][lane + 64], 0.f);
                }
            }
            hlds[wave][j][lane] = h0;
            hlds[wave][j][lane + 64] = h1;
        }
        __syncthreads();
        // phase B: 4-row x 2-col register tile per lane
        float2 acc0 = {0.f, 0.f}, acc1 = {0.f, 0.f}, acc2 = {0.f, 0.f}, acc3 = {0.f, 0.f};
        #pragma unroll 8
        for (int k = 0; k < DD; ++k) {
            float2 w2 = *reinterpret_cast<float2*>(&wlds[k * DD + 2 * lane]);
            float hA = hlds[wave][0][k];
            float hB = hlds[wave][1][k];
            float hC = hlds[wave][2][k];
            float hD = hlds[wave][3][k];
            acc0.x += hA * w2.x; acc0.y += hA * w2.y;
            acc1.x += hB * w2.x; acc1.y += hB * w2.y;
            acc2.x += hC * w2.x; acc2.y += hC * w2.y;
            acc3.x += hD * w2.x; acc3.y += hD * w2.y;
        }
        float2 accs[4] = {acc0, acc1, acc2, acc3};
        for (int j = 0; j < 4; ++j) {
            int row = rbase + j;
            if (row < N_NODES)
                *reinterpret_cast<float2*>(&out[(size_t)row * DD + 2 * lane]) = accs[j];
        }
        __syncthreads();
    }
}

// ---------------- restricted SpMM for the 8192 needed output rows ----------------
__global__ void __launch_bounds__(256) k_spmm_out(const int* __restrict__ row_ptr,
                                                  const int2* __restrict__ pack,
                                                  const float* __restrict__ S2,
                                                  const int* __restrict__ uidx,
                                                  const int* __restrict__ iidx,
                                                  const float* __restrict__ b1,
                                                  float* __restrict__ tstack, int t) {
    int slot = (int)((blockIdx.x * blockDim.x + threadIdx.x) >> 6);
    int lane = threadIdx.x & 63;
    if (slot >= 2 * B_SZ) return;
    int b = slot & (B_SZ - 1);
    int side = slot >> 12;
    int row = (side == 0) ? uidx[b] : (U_CNT + iidx[b]);
    int beg = row_ptr[row];
    int end = row_ptr[row + 1];
    float2 acc = {0.f, 0.f};
    for (int e = beg; e < end; ++e) {
        int2 p = pack[e];
        float v = __int_as_float(p.y);
        const float2 s = *reinterpret_cast<const float2*>(&S2[(size_t)p.x * DD + 2 * lane]);
        acc.x += v * s.x;
        acc.y += v * s.y;
    }
    float o0 = fmaxf(acc.x + b1[2 * lane], 0.f);
    float o1 = fmaxf(acc.y + b1[2 * lane + 1], 0.f);
    float* dstp = &tstack[(((size_t)b * T_STEPS + t) * 2 * DD) + side * DD + 2 * lane];
    dstp[0] = o0;
    dstp[1] = o1;
}

// ---------------- attention + prediction head (one block per batch row) ----------------
__global__ void __launch_bounds__(128) k_final(const int* __restrict__ uidx,
                                               const int* __restrict__ iidx,
                                               const float* __restrict__ utab,
                                               const float* __restrict__ itab,
                                               const float* __restrict__ aw1,
                                               const float* __restrict__ ab1,
                                               const float* __restrict__ aw2,
                                               const float* __restrict__ ab2,
                                               const float* __restrict__ pw1,
                                               const float* __restrict__ pb1,
                                               const float* __restrict__ pw2,
                                               const float* __restrict__ pb2,
                                               const float* __restrict__ tstack,
                                               float* __restrict__ outp) {
    __shared__ float s[2 * DD];
    __shared__ float ah[DD];
    __shared__ float attn[T_STEPS];
    __shared__ float summed[2 * DD];
    __shared__ float red[2];
    int b = blockIdx.x, tid = threadIdx.x;
    int u = uidx[b], it = iidx[b];
    s[tid] = utab[(size_t)u * DD + tid];
    s[tid + DD] = itab[(size_t)it * DD + tid];
    __syncthreads();
    float acc = ab1[tid];
    for (int k = 0; k < 2 * DD; ++k) acc += s[k] * aw1[k * DD + tid];
    ah[tid] = fmaxf(acc, 0.f);
    __syncthreads();
    if (tid < T_STEPS) {
        float lg = ab2[tid];
        for (int k = 0; k < DD; ++k) lg += ah[k] * aw2[k * T_STEPS + tid];
        attn[tid] = lg;
    }
    __syncthreads();
    if (tid == 0) {
        float m = fmaxf(attn[0], fmaxf(attn[1], attn[2]));
        float e0 = expf(attn[0] - m), e1 = expf(attn[1] - m), e2 = expf(attn[2] - m);
        float inv = 1.f / (e0 + e1 + e2);
        attn[0] = e0 * inv;
        attn[1] = e1 * inv;
        attn[2] = e2 * inv;
    }
    __syncthreads();
    const float* tb = &tstack[(size_t)b * T_STEPS * 2 * DD];
    for (int k = tid; k < 2 * DD; k += 128)
        summed[k] = attn[0] * tb[k] + attn[1] * tb[2 * DD + k] + attn[2] * tb[4 * DD + k];
    __syncthreads();
    float ph = pb1[tid];
    for (int k = 0; k < 2 * DD; ++k) ph += summed[k] * pw1[k * DD + tid];
    ph = fmaxf(ph, 0.f);
    float contrib = ph * pw2[tid];
    for (int off = 32; off > 0; off >>= 1) contrib += __shfl_down(contrib, off, 64);
    if ((tid & 63) == 0) red[tid >> 6] = contrib;
    __syncthreads();
    if (tid == 0) outp[b] = red[0] + red[1] + pb2[0];
}

extern "C" void kernel_launch(void* const* d_in, const int* in_sizes, int n_in,
                              void* d_out, int out_size, void* d_ws, size_t ws_size,
                              hipStream_t stream) {
    const int* uidx = (const int*)d_in[0];
    const int* iidx = (const int*)d_in[1];
    const int* eidx = (const int*)d_in[2];
    const float* adj = (const float*)d_in[3];
    const float* utab = (const float*)d_in[4];
    const float* itab = (const float*)d_in[5];
    const float* temb = (const float*)d_in[6];
    const float* gw = (const float*)d_in[7];
    const float* gb = (const float*)d_in[8];
    const float* aw1 = (const float*)d_in[9];
    const float* ab1 = (const float*)d_in[10];
    const float* aw2 = (const float*)d_in[11];
    const float* ab2 = (const float*)d_in[12];
    const float* pw1 = (const float*)d_in[13];
    const float* pb1 = (const float*)d_in[14];
    const float* pw2 = (const float*)d_in[15];
    const float* pb2 = (const float*)d_in[16];

    char* ws = (char*)d_ws;
    size_t off = 0;
    auto alloc = [&](size_t bytes) {
        void* p = ws + off;
        off += (bytes + 255) & ~(size_t)255;
        return p;
    };
    int* cnt = (int*)alloc((size_t)N_NODES * 4);
    int* row_ptr = (int*)alloc((size_t)(N_NODES + 1) * 4);
    int* cursor = (int*)alloc((size_t)N_NODES * 4);
    int2* pack = (int2*)alloc((size_t)E_CNT * 8);
    float* rvec = (float*)alloc((size_t)N_NODES * 4);
    float* uvec = (float*)alloc((size_t)T_STEPS * DD * 4);
    float* Sbuf = (float*)alloc((size_t)N_NODES * DD * 4);
    float* Pbuf = (float*)alloc((size_t)N_NODES * DD * 4);
    float* tstack = (float*)alloc((size_t)B_SZ * T_STEPS * 2 * DD * 4);

    hipMemsetAsync(cnt, 0, (size_t)N_NODES * 4, stream);
    k_hist<<<2048, 256, 0, stream>>>(eidx, cnt, E_CNT);
    k_scan<<<1, 1024, 0, stream>>>(cnt, row_ptr, cursor, N_NODES);
    k_scatter<<<2048, 256, 0, stream>>>(eidx, eidx + E_CNT, adj, cursor, pack, E_CNT);
    k_uvec<<<1, DD, 0, stream>>>(temb, gw, uvec);

    // S = x @ W0
    k_gemm<0><<<2048, 256, 0, stream>>>(utab, itab, gw, nullptr, nullptr, nullptr, Sbuf);
    // P = A @ S, r = A @ 1
    k_spmm_full<<<(N_NODES + 3) / 4, 256, 0, stream>>>(row_ptr, pack, Sbuf, Pbuf, rvec);

    for (int t = 0; t < T_STEPS; ++t) {
        // S2 = relu(P + r*u_t + b0) @ W1   (reuses Sbuf)
        k_gemm<1><<<2048, 256, 0, stream>>>(Pbuf, nullptr, gw + DD * DD, rvec,
                                            uvec + t * DD, gb, Sbuf);
        // temporal_out[:, t, :] = relu(A_restricted @ S2 + b1) at the 8192 needed rows
        k_spmm_out<<<(2 * B_SZ) / 4, 256, 0, stream>>>(row_ptr, pack, Sbuf, uidx, iidx,
                                                       gb + DD, tstack, t);
    }
    k_final<<<B_SZ, 128, 0, stream>>>(uidx, iidx, utab, itab, aw1, ab1, aw2, ab2, pw1,
                                      pb1, pw2, pb2, tstack, (float*)d_out);
}

// Round 2
// 984.725 us; speedup vs baseline: 1.4207x; 1.4207x over previous
//
#include <hip/hip_runtime.h>

#define U_CNT 50000
#define I_CNT 50000
#define N_NODES 100000
#define DD 128
#define T_STEPS 3
#define E_CNT 3200000
#define B_SZ 4096

__device__ __forceinline__ float bf2f(unsigned short u) {
    return __uint_as_float(((unsigned int)u) << 16);
}
__device__ __forceinline__ unsigned short f2bf(float f) {
    unsigned int x = __float_as_uint(f);
    x += 0x7FFF + ((x >> 16) & 1);
    return (unsigned short)(x >> 16);
}

// ---------------- CSR build ----------------
__global__ void k_hist(const int* __restrict__ dst, int* __restrict__ cnt, int E) {
    int i = blockIdx.x * blockDim.x + threadIdx.x;
    int stride = gridDim.x * blockDim.x;
    for (; i < E; i += stride) atomicAdd(&cnt[dst[i]], 1);
}

__global__ void __launch_bounds__(1024) k_scan(const int* __restrict__ cnt,
                                               int* __restrict__ row_ptr,
                                               int* __restrict__ cursor, int n) {
    __shared__ int lds[1024];
    int tid = threadIdx.x;
    const int CH = (n + 1023) / 1024;
    int s0 = tid * CH;
    int s1 = min(n, s0 + CH);
    int mysum = 0;
    for (int i = s0; i < s1; ++i) mysum += cnt[i];
    lds[tid] = mysum;
    __syncthreads();
    for (int off = 1; off < 1024; off <<= 1) {
        int add = (tid >= off) ? lds[tid - off] : 0;
        __syncthreads();
        lds[tid] += add;
        __syncthreads();
    }
    if (tid == 1023) row_ptr[n] = lds[1023];
    int run = lds[tid] - mysum;
    for (int i = s0; i < s1; ++i) {
        row_ptr[i] = run;
        cursor[i] = run;
        run += cnt[i];
    }
}

__global__ void k_scatter(const int* __restrict__ dst, const int* __restrict__ src,
                          const float* __restrict__ val, int* __restrict__ cursor,
                          int2* __restrict__ pack, int E) {
    int i = blockIdx.x * blockDim.x + threadIdx.x;
    int stride = gridDim.x * blockDim.x;
    for (; i < E; i += stride) {
        int d = dst[i];
        int pos = atomicAdd(&cursor[d], 1);
        pack[pos] = make_int2(src[i], __float_as_int(val[i]));
    }
}

// u_t = temporal_emb[t] @ W0  (tiny)
__global__ void k_uvec(const float* __restrict__ temb, const float* __restrict__ w0,
                       float* __restrict__ u) {
    int k = threadIdx.x;
    for (int t = 0; t < T_STEPS; ++t) {
        float acc = 0.f;
        for (int j = 0; j < DD; ++j) acc += temb[t * DD + j] * w0[j * DD + k];
        u[t * DD + k] = acc;
    }
}

// ---------------- GEMM: S = x @ W0 (fp32 compute, bf16 store) ----------------
__global__ void __launch_bounds__(256) k_gemm0(const float* __restrict__ utab,
                                               const float* __restrict__ itab,
                                               const float* __restrict__ W,
                                               unsigned short* __restrict__ outb) {
    __shared__ float wlds[DD * DD];
    __shared__ float hlds[4][4][DD];
    int tid = threadIdx.x;
    for (int i = tid; i < DD * DD / 4; i += 256)
        reinterpret_cast<float4*>(wlds)[i] = reinterpret_cast<const float4*>(W)[i];
    __syncthreads();
    int wave = tid >> 6, lane = tid & 63;
    const int ntiles = (N_NODES + 15) / 16;
    for (int tile = blockIdx.x; tile < ntiles; tile += gridDim.x) {
        int rbase = tile * 16 + wave * 4;
        for (int j = 0; j < 4; ++j) {
            int row = rbase + j;
            float h0 = 0.f, h1 = 0.f;
            if (row < N_NODES) {
                const float* x = (row < U_CNT) ? &utab[(size_t)row * DD]
                                               : &itab[(size_t)(row - U_CNT) * DD];
                h0 = x[lane];
                h1 = x[lane + 64];
            }
            hlds[wave][j][lane] = h0;      // per-wave private slice: no block sync needed
            hlds[wave][j][lane + 64] = h1;
        }
        float2 acc0 = {0.f, 0.f}, acc1 = {0.f, 0.f}, acc2 = {0.f, 0.f}, acc3 = {0.f, 0.f};
        #pragma unroll 8
        for (int k = 0; k < DD; ++k) {
            float2 w2 = *reinterpret_cast<float2*>(&wlds[k * DD + 2 * lane]);
            float hA = hlds[wave][0][k];
            float hB = hlds[wave][1][k];
            float hC = hlds[wave][2][k];
            float hD = hlds[wave][3][k];
            acc0.x += hA * w2.x; acc0.y += hA * w2.y;
            acc1.x += hB * w2.x; acc1.y += hB * w2.y;
            acc2.x += hC * w2.x; acc2.y += hC * w2.y;
            acc3.x += hD * w2.x; acc3.y += hD * w2.y;
        }
        float2 accs[4] = {acc0, acc1, acc2, acc3};
        for (int j = 0; j < 4; ++j) {
            int row = rbase + j;
            if (row < N_NODES) {
                ushort2 o = {f2bf(accs[j].x), f2bf(accs[j].y)};
                *reinterpret_cast<ushort2*>(&outb[(size_t)row * DD + 2 * lane]) = o;
            }
        }
    }
}

// ---------------- full SpMM: P = A*S (bf16 in/out), r = A*1 ----------------
// one wave per dst row; 2 edges per iteration; lane loads ushort4 (4 cols, 8B)
__global__ void __launch_bounds__(256) k_spmm_full(const int* __restrict__ row_ptr,
                                                   const int2* __restrict__ pack,
                                                   const unsigned short* __restrict__ Sb,
                                                   unsigned short* __restrict__ Pb,
                                                   float* __restrict__ rvec) {
    int wave = (int)((blockIdx.x * blockDim.x + threadIdx.x) >> 6);
    int lane = threadIdx.x & 63;
    if (wave >= N_NODES) return;
    int beg = row_ptr[wave], end = row_ptr[wave + 1];
    int half = lane >> 5, cg = lane & 31;
    float acc0 = 0.f, acc1 = 0.f, acc2 = 0.f, acc3 = 0.f, vs = 0.f;
    for (int e = beg; e < end; e += 2) {
        int ee = e + half;
        int2 p = (ee < end) ? pack[ee] : make_int2(0, 0);
        float v = __int_as_float(p.y);
        ushort4 s4 = *reinterpret_cast<const ushort4*>(&Sb[(size_t)p.x * DD + cg * 4]);
        acc0 += v * bf2f(s4.x);
        acc1 += v * bf2f(s4.y);
        acc2 += v * bf2f(s4.z);
        acc3 += v * bf2f(s4.w);
        if (cg == 0) vs += v;
    }
    acc0 += __shfl_down(acc0, 32, 64);
    acc1 += __shfl_down(acc1, 32, 64);
    acc2 += __shfl_down(acc2, 32, 64);
    acc3 += __shfl_down(acc3, 32, 64);
    vs += __shfl_down(vs, 32, 64);
    if (lane < 32) {
        ushort4 o = {f2bf(acc0), f2bf(acc1), f2bf(acc2), f2bf(acc3)};
        *reinterpret_cast<ushort4*>(&Pb[(size_t)wave * DD + lane * 4]) = o;
        if (lane == 0) rvec[wave] = vs;
    }
}

// ---------------- restricted SpMM, all 3 t's fused: agg[slot][t] = A_r @ relu(P + r*u_t + b0) ----------------
__global__ void __launch_bounds__(256) k_spmm_out3(const int* __restrict__ row_ptr,
                                                   const int2* __restrict__ pack,
                                                   const unsigned short* __restrict__ Pb,
                                                   const float* __restrict__ rvec,
                                                   const int* __restrict__ uidx,
                                                   const int* __restrict__ iidx,
                                                   const float* __restrict__ uvec,
                                                   const float* __restrict__ b0,
                                                   float* __restrict__ agg) {
    int slot = (int)((blockIdx.x * blockDim.x + threadIdx.x) >> 6);
    int lane = threadIdx.x & 63;
    if (slot >= 2 * B_SZ) return;
    int b = slot & (B_SZ - 1), side = slot >> 12;
    int row = side ? (U_CNT + iidx[b]) : uidx[b];
    int beg = row_ptr[row], end = row_ptr[row + 1];
    int half = lane >> 5, cg = lane & 31;
    float u0[4], u1[4], u2[4], bb[4];
    #pragma unroll
    for (int j = 0; j < 4; ++j) {
        int c = cg * 4 + j;
        u0[j] = uvec[c];
        u1[j] = uvec[DD + c];
        u2[j] = uvec[2 * DD + c];
        bb[j] = b0[c];
    }
    float a0[4] = {0, 0, 0, 0}, a1[4] = {0, 0, 0, 0}, a2[4] = {0, 0, 0, 0};
    for (int e = beg; e < end; e += 2) {
        int ee = e + half;
        int2 p = (ee < end) ? pack[ee] : make_int2(0, 0);
        float v = __int_as_float(p.y);
        float rr = rvec[p.x];
        ushort4 s4 = *reinterpret_cast<const ushort4*>(&Pb[(size_t)p.x * DD + cg * 4]);
        float pc[4] = {bf2f(s4.x), bf2f(s4.y), bf2f(s4.z), bf2f(s4.w)};
        #pragma unroll
        for (int j = 0; j < 4; ++j) {
            float base = pc[j] + bb[j];
            a0[j] += v * fmaxf(base + rr * u0[j], 0.f);
            a1[j] += v * fmaxf(base + rr * u1[j], 0.f);
            a2[j] += v * fmaxf(base + rr * u2[j], 0.f);
        }
    }
    #pragma unroll
    for (int j = 0; j < 4; ++j) {
        a0[j] += __shfl_down(a0[j], 32, 64);
        a1[j] += __shfl_down(a1[j], 32, 64);
        a2[j] += __shfl_down(a2[j], 32, 64);
    }
    if (lane < 32) {
        size_t rb = (size_t)slot * 3;
        float4 o0 = {a0[0], a0[1], a0[2], a0[3]};
        float4 o1 = {a1[0], a1[1], a1[2], a1[3]};
        float4 o2 = {a2[0], a2[1], a2[2], a2[3]};
        *reinterpret_cast<float4*>(&agg[(rb + 0) * DD + lane * 4]) = o0;
        *reinterpret_cast<float4*>(&agg[(rb + 1) * DD + lane * 4]) = o1;
        *reinterpret_cast<float4*>(&agg[(rb + 2) * DD + lane * 4]) = o2;
    }
}

// ---------------- head GEMM: tstack = relu(agg @ W1 + b1), scattered to [b][t][side] ----------------
__global__ void __launch_bounds__(256) k_head(const float* __restrict__ agg,
                                              const float* __restrict__ W,
                                              const float* __restrict__ b1,
                                              float* __restrict__ tstack) {
    __shared__ float wlds[DD * DD];
    __shared__ float blds[DD];
    __shared__ float hlds[4][4][DD];
    int tid = threadIdx.x;
    for (int i = tid; i < DD * DD / 4; i += 256)
        reinterpret_cast<float4*>(wlds)[i] = reinterpret_cast<const float4*>(W)[i];
    if (tid < DD) blds[tid] = b1[tid];
    __syncthreads();
    int wave = tid >> 6, lane = tid & 63;
    const int NR = 2 * B_SZ * T_STEPS;
    const int ntiles = NR / 16;
    for (int tile = blockIdx.x; tile < ntiles; tile += gridDim.x) {
        int rbase = tile * 16 + wave * 4;
        for (int j = 0; j < 4; ++j) {
            int row = rbase + j;
            hlds[wave][j][lane] = agg[(size_t)row * DD + lane];
            hlds[wave][j][lane + 64] = agg[(size_t)row * DD + lane + 64];
        }
        float2 acc0 = {0.f, 0.f}, acc1 = {0.f, 0.f}, acc2 = {0.f, 0.f}, acc3 = {0.f, 0.f};
        #pragma unroll 8
        for (int k = 0; k < DD; ++k) {
            float2 w2 = *reinterpret_cast<float2*>(&wlds[k * DD + 2 * lane]);
            float hA = hlds[wave][0][k];
            float hB = hlds[wave][1][k];
            float hC = hlds[wave][2][k];
            float hD = hlds[wave][3][k];
            acc0.x += hA * w2.x; acc0.y += hA * w2.y;
            acc1.x += hB * w2.x; acc1.y += hB * w2.y;
            acc2.x += hC * w2.x; acc2.y += hC * w2.y;
            acc3.x += hD * w2.x; acc3.y += hD * w2.y;
        }
        float2 accs[4] = {acc0, acc1, acc2, acc3};
        for (int j = 0; j < 4; ++j) {
            int row = rbase + j;
            int slot = row / 3, t = row - slot * 3;
            int b = slot & (B_SZ - 1), side = slot >> 12;
            float2 o;
            o.x = fmaxf(accs[j].x + blds[2 * lane], 0.f);
            o.y = fmaxf(accs[j].y + blds[2 * lane + 1], 0.f);
            *reinterpret_cast<float2*>(
                &tstack[((size_t)b * T_STEPS + t) * 2 * DD + side * DD + 2 * lane]) = o;
        }
    }
}

// ---------------- attention + prediction head ----------------
__global__ void __launch_bounds__(128) k_final(const int* __restrict__ uidx,
                                               const int* __restrict__ iidx,
                                               const float* __restrict__ utab,
                                               const float* __restrict__ itab,
                                               const float* __restrict__ aw1,
                                               const float* __restrict__ ab1,
                                               const float* __restrict__ aw2,
                                               const float* __restrict__ ab2,
                                               const float* __restrict__ pw1,
                                               const float* __restrict__ pb1,
                                               const float* __restrict__ pw2,
                                               const float* __restrict__ pb2,
                                               const float* __restrict__ tstack,
                                               float* __restrict__ outp) {
    __shared__ float s[2 * DD];
    __shared__ float ah[DD];
    __shared__ float attn[T_STEPS];
    __shared__ float summed[2 * DD];
    __shared__ float red[2];
    int b = blockIdx.x, tid = threadIdx.x;
    int u = uidx[b], it = iidx[b];
    s[tid] = utab[(size_t)u * DD + tid];
    s[tid + DD] = itab[(size_t)it * DD + tid];
    __syncthreads();
    float acc = ab1[tid];
    for (int k = 0; k < 2 * DD; ++k) acc += s[k] * aw1[k * DD + tid];
    ah[tid] = fmaxf(acc, 0.f);
    __syncthreads();
    if (tid < T_STEPS) {
        float lg = ab2[tid];
        for (int k = 0; k < DD; ++k) lg += ah[k] * aw2[k * T_STEPS + tid];
        attn[tid] = lg;
    }
    __syncthreads();
    if (tid == 0) {
        float m = fmaxf(attn[0], fmaxf(attn[1], attn[2]));
        float e0 = expf(attn[0] - m), e1 = expf(attn[1] - m), e2 = expf(attn[2] - m);
        float inv = 1.f / (e0 + e1 + e2);
        attn[0] = e0 * inv;
        attn[1] = e1 * inv;
        attn[2] = e2 * inv;
    }
    __syncthreads();
    const float* tb = &tstack[(size_t)b * T_STEPS * 2 * DD];
    for (int k = tid; k < 2 * DD; k += 128)
        summed[k] = attn[0] * tb[k] + attn[1] * tb[2 * DD + k] + attn[2] * tb[4 * DD + k];
    __syncthreads();
    float ph = pb1[tid];
    for (int k = 0; k < 2 * DD; ++k) ph += summed[k] * pw1[k * DD + tid];
    ph = fmaxf(ph, 0.f);
    float contrib = ph * pw2[tid];
    for (int off = 32; off > 0; off >>= 1) contrib += __shfl_down(contrib, off, 64);
    if ((tid & 63) == 0) red[tid >> 6] = contrib;
    __syncthreads();
    if (tid == 0) outp[b] = red[0] + red[1] + pb2[0];
}

extern "C" void kernel_launch(void* const* d_in, const int* in_sizes, int n_in,
                              void* d_out, int out_size, void* d_ws, size_t ws_size,
                              hipStream_t stream) {
    const int* uidx = (const int*)d_in[0];
    const int* iidx = (const int*)d_in[1];
    const int* eidx = (const int*)d_in[2];
    const float* adj = (const float*)d_in[3];
    const float* utab = (const float*)d_in[4];
    const float* itab = (const float*)d_in[5];
    const float* temb = (const float*)d_in[6];
    const float* gw = (const float*)d_in[7];
    const float* gb = (const float*)d_in[8];
    const float* aw1 = (const float*)d_in[9];
    const float* ab1 = (const float*)d_in[10];
    const float* aw2 = (const float*)d_in[11];
    const float* ab2 = (const float*)d_in[12];
    const float* pw1 = (const float*)d_in[13];
    const float* pb1 = (const float*)d_in[14];
    const float* pw2 = (const float*)d_in[15];
    const float* pb2 = (const float*)d_in[16];

    char* ws = (char*)d_ws;
    size_t off = 0;
    auto alloc = [&](size_t bytes) {
        void* p = ws + off;
        off += (bytes + 255) & ~(size_t)255;
        return p;
    };
    int* cnt = (int*)alloc((size_t)N_NODES * 4);
    int* row_ptr = (int*)alloc((size_t)(N_NODES + 1) * 4);
    int* cursor = (int*)alloc((size_t)N_NODES * 4);
    int2* pack = (int2*)alloc((size_t)E_CNT * 8);
    float* rvec = (float*)alloc((size_t)N_NODES * 4);
    float* uvec = (float*)alloc((size_t)T_STEPS * DD * 4);
    unsigned short* Sb = (unsigned short*)alloc((size_t)N_NODES * DD * 2);
    unsigned short* Pb = (unsigned short*)alloc((size_t)N_NODES * DD * 2);
    float* agg = (float*)alloc((size_t)2 * B_SZ * T_STEPS * DD * 4);
    float* tstack = (float*)alloc((size_t)B_SZ * T_STEPS * 2 * DD * 4);

    hipMemsetAsync(cnt, 0, (size_t)N_NODES * 4, stream);
    k_hist<<<2048, 256, 0, stream>>>(eidx, cnt, E_CNT);
    k_scan<<<1, 1024, 0, stream>>>(cnt, row_ptr, cursor, N_NODES);
    k_scatter<<<2048, 256, 0, stream>>>(eidx, eidx + E_CNT, adj, cursor, pack, E_CNT);
    k_uvec<<<1, DD, 0, stream>>>(temb, gw, uvec);

    // S = x @ W0 (bf16 store)
    k_gemm0<<<2048, 256, 0, stream>>>(utab, itab, gw, Sb);
    // P = A @ S (bf16), r = A @ 1
    k_spmm_full<<<(N_NODES * 64) / 256 + 1, 256, 0, stream>>>(row_ptr, pack, Sb, Pb, rvec);
    // agg[slot][t] = A_restricted @ relu(P + r*u_t + b0), all t fused
    k_spmm_out3<<<(2 * B_SZ * 64) / 256, 256, 0, stream>>>(row_ptr, pack, Pb, rvec, uidx,
                                                           iidx, uvec, gb, agg);
    // tstack = relu(agg @ W1 + b1)
    k_head<<<512, 256, 0, stream>>>(agg, gw + DD * DD, gb + DD, tstack);
    k_final<<<B_SZ, 128, 0, stream>>>(uidx, iidx, utab, itab, aw1, ab1, aw2, ab2, pw1,
                                      pb1, pw2, pb2, tstack, (float*)d_out);
}

// Round 3
// 912.911 us; speedup vs baseline: 1.5324x; 1.0787x over previous
//
#include <hip/hip_runtime.h>

#define U_CNT 50000
#define I_CNT 50000
#define N_NODES 100000
#define DD 128
#define T_STEPS 3
#define E_CNT 3200000
#define B_SZ 4096

#define NCOARSE 391   // ceil(100000 / 256): coarse bucket = dst >> 8
#define CAPB 16       // LDS staging slots per bucket
#define SORT_CAP 10240

__device__ __forceinline__ float bf2f(unsigned short u) {
    return __uint_as_float(((unsigned int)u) << 16);
}
__device__ __forceinline__ unsigned short f2bf(float f) {
    unsigned int x = __float_as_uint(f);
    x += 0x7FFF + ((x >> 16) & 1);
    return (unsigned short)(x >> 16);
}

// ---------------- coarse bucket histogram (LDS-aggregated) ----------------
__global__ void __launch_bounds__(256) k_bin_count(const int* __restrict__ dst,
                                                   int* __restrict__ gcnt) {
    __shared__ int c[NCOARSE];
    int tid = threadIdx.x;
    for (int j = tid; j < NCOARSE; j += 256) c[j] = 0;
    __syncthreads();
    int i = blockIdx.x * blockDim.x + tid;
    int stride = gridDim.x * blockDim.x;
    for (; i < E_CNT; i += stride) atomicAdd(&c[dst[i] >> 8], 1);
    __syncthreads();
    for (int j = tid; j < NCOARSE; j += 256)
        if (c[j]) atomicAdd(&gcnt[j], c[j]);
}

// ---------------- tiny serial scan over 391 buckets ----------------
__global__ void k_bin_scan(const int* __restrict__ cnt, int* __restrict__ pad_base,
                           int* __restrict__ exact_base, int* __restrict__ bcur,
                           int* __restrict__ row_ptr) {
    if (threadIdx.x == 0 && blockIdx.x == 0) {
        int pb = 0, eb = 0;
        for (int b = 0; b < NCOARSE; ++b) {
            pad_base[b] = pb;
            exact_base[b] = eb;
            bcur[b] = pb;
            int c = cnt[b];
            eb += c;
            pb += (c + 7) & ~7;  // keep flush bases 64B-aligned
        }
        exact_base[NCOARSE] = eb;
        row_ptr[N_NODES] = eb;  // == E_CNT
    }
}

// ---------------- LDS-staged coarse binning: coalesced 64-128B flushes ----------------
__global__ void __launch_bounds__(256) k_bin_scatter(const int* __restrict__ dst,
                                                     const int* __restrict__ src,
                                                     const float* __restrict__ val,
                                                     int* __restrict__ bcur,
                                                     int2* __restrict__ binned) {
    __shared__ int scnt[NCOARSE];
    __shared__ int2 stage[NCOARSE][CAPB];
    int tid = threadIdx.x, wid = tid >> 6, lane = tid & 63;
    for (int j = tid; j < NCOARSE; j += 256) scnt[j] = 0;
    __syncthreads();
    const int perRound = gridDim.x * 512;
    const int nrounds = (E_CNT + perRound - 1) / perRound;
    for (int r = 0; r < nrounds; ++r) {
        int base_i = (r * gridDim.x + blockIdx.x) * 512;
        #pragma unroll
        for (int k = 0; k < 2; ++k) {
            int i = base_i + k * 256 + tid;
            if (i < E_CNT) {
                int d = dst[i];
                int b = d >> 8;
                int2 pay = make_int2(src[i] | ((d & 255) << 20), __float_as_int(val[i]));
                int pos = atomicAdd(&scnt[b], 1);
                if (pos < CAPB) stage[b][pos] = pay;
                else {  // astronomically rare within-round overflow: direct write
                    int gp = atomicAdd(&bcur[b], 1);
                    binned[gp] = pay;
                }
            }
        }
        __syncthreads();
        for (int b = wid; b < NCOARSE; b += 4) {
            int c = scnt[b];
            if (c > CAPB) c = CAPB;
            int nf = c & ~7;
            if (nf > 0) {
                int gb = 0;
                if (lane == 0) gb = atomicAdd(&bcur[b], nf);
                gb = __shfl(gb, 0, 64);
                if (lane < nf) binned[gb + lane] = stage[b][lane];
                int rem = c - nf;
                int2 tmp;
                if (lane < rem) tmp = stage[b][nf + lane];
                if (lane < rem) stage[b][lane] = tmp;
                if (lane == 0) scnt[b] = rem;
            }
        }
        __syncthreads();
    }
    for (int b = wid; b < NCOARSE; b += 4) {  // drain remainders
        int c = scnt[b];
        if (c > CAPB) c = CAPB;
        if (c > 0) {
            int gb = 0;
            if (lane == 0) gb = atomicAdd(&bcur[b], c);
            gb = __shfl(gb, 0, 64);
            if (lane < c) binned[gb + lane] = stage[b][lane];
        }
    }
}

// ---------------- per-bucket exact sort: emit dst-sorted pack + row_ptr ----------------
__global__ void __launch_bounds__(256) k_sort(const int* __restrict__ bucket_cnt,
                                              const int* __restrict__ pad_base,
                                              const int* __restrict__ exact_base,
                                              const int2* __restrict__ binned,
                                              int2* __restrict__ outp,
                                              int* __restrict__ row_ptr) {
    __shared__ int hist[256], scn[256], cur[256];
    __shared__ unsigned short perm[SORT_CAP];
    int b = blockIdx.x, tid = threadIdx.x;
    int cnt = bucket_cnt[b];
    if (cnt > SORT_CAP) cnt = SORT_CAP;  // safety clamp (never hit for this input)
    const int2* rbase = binned + pad_base[b];
    int ebase = exact_base[b];
    int n0 = b << 8;
    hist[tid] = 0;
    __syncthreads();
    for (int i = tid; i < cnt; i += 256) atomicAdd(&hist[(rbase[i].x >> 20) & 255], 1);
    __syncthreads();
    scn[tid] = hist[tid];
    __syncthreads();
    for (int off = 1; off < 256; off <<= 1) {
        int v = (tid >= off) ? scn[tid - off] : 0;
        __syncthreads();
        scn[tid] += v;
        __syncthreads();
    }
    int excl = scn[tid] - hist[tid];
    cur[tid] = excl;
    if (n0 + tid < N_NODES) row_ptr[n0 + tid] = ebase + excl;
    __syncthreads();
    for (int i = tid; i < cnt; i += 256) {
        int dloc = (rbase[i].x >> 20) & 255;
        int pos = atomicAdd(&cur[dloc], 1);
        perm[pos] = (unsigned short)i;
    }
    __syncthreads();
    for (int i = tid; i < cnt; i += 256) {
        int2 p = rbase[perm[i]];
        p.x &= 0xFFFFF;
        outp[ebase + i] = p;
    }
}

// u_t = temporal_emb[t] @ W0  (tiny)
__global__ void k_uvec(const float* __restrict__ temb, const float* __restrict__ w0,
                       float* __restrict__ u) {
    int k = threadIdx.x;
    for (int t = 0; t < T_STEPS; ++t) {
        float acc = 0.f;
        for (int j = 0; j < DD; ++j) acc += temb[t * DD + j] * w0[j * DD + k];
        u[t * DD + k] = acc;
    }
}

// ---------------- GEMM: S = x @ W0 (fp32 compute, bf16 store) ----------------
__global__ void __launch_bounds__(256) k_gemm0(const float* __restrict__ utab,
                                               const float* __restrict__ itab,
                                               const float* __restrict__ W,
                                               unsigned short* __restrict__ outb) {
    __shared__ float wlds[DD * DD];
    __shared__ float hlds[4][4][DD];
    int tid = threadIdx.x;
    for (int i = tid; i < DD * DD / 4; i += 256)
        reinterpret_cast<float4*>(wlds)[i] = reinterpret_cast<const float4*>(W)[i];
    __syncthreads();
    int wave = tid >> 6, lane = tid & 63;
    const int ntiles = (N_NODES + 15) / 16;
    for (int tile = blockIdx.x; tile < ntiles; tile += gridDim.x) {
        int rbase = tile * 16 + wave * 4;
        for (int j = 0; j < 4; ++j) {
            int row = rbase + j;
            float h0 = 0.f, h1 = 0.f;
            if (row < N_NODES) {
                const float* x = (row < U_CNT) ? &utab[(size_t)row * DD]
                                               : &itab[(size_t)(row - U_CNT) * DD];
                h0 = x[lane];
                h1 = x[lane + 64];
            }
            hlds[wave][j][lane] = h0;
            hlds[wave][j][lane + 64] = h1;
        }
        float2 acc0 = {0.f, 0.f}, acc1 = {0.f, 0.f}, acc2 = {0.f, 0.f}, acc3 = {0.f, 0.f};
        #pragma unroll 8
        for (int k = 0; k < DD; ++k) {
            float2 w2 = *reinterpret_cast<float2*>(&wlds[k * DD + 2 * lane]);
            float hA = hlds[wave][0][k];
            float hB = hlds[wave][1][k];
            float hC = hlds[wave][2][k];
            float hD = hlds[wave][3][k];
            acc0.x += hA * w2.x; acc0.y += hA * w2.y;
            acc1.x += hB * w2.x; acc1.y += hB * w2.y;
            acc2.x += hC * w2.x; acc2.y += hC * w2.y;
            acc3.x += hD * w2.x; acc3.y += hD * w2.y;
        }
        float2 accs[4] = {acc0, acc1, acc2, acc3};
        for (int j = 0; j < 4; ++j) {
            int row = rbase + j;
            if (row < N_NODES) {
                ushort2 o = {f2bf(accs[j].x), f2bf(accs[j].y)};
                *reinterpret_cast<ushort2*>(&outb[(size_t)row * DD + 2 * lane]) = o;
            }
        }
    }
}

// ---------------- full SpMM: P = A*S (bf16 in/out), r = A*1 ----------------
__global__ void __launch_bounds__(256) k_spmm_full(const int* __restrict__ row_ptr,
                                                   const int2* __restrict__ pack,
                                                   const unsigned short* __restrict__ Sb,
                                                   unsigned short* __restrict__ Pb,
                                                   float* __restrict__ rvec) {
    int wave = (int)((blockIdx.x * blockDim.x + threadIdx.x) >> 6);
    int lane = threadIdx.x & 63;
    if (wave >= N_NODES) return;
    int beg = row_ptr[wave], end = row_ptr[wave + 1];
    int half = lane >> 5, cg = lane & 31;
    float acc0 = 0.f, acc1 = 0.f, acc2 = 0.f, acc3 = 0.f, vs = 0.f;
    for (int e = beg; e < end; e += 2) {
        int ee = e + half;
        int2 p = (ee < end) ? pack[ee] : make_int2(0, 0);
        float v = __int_as_float(p.y);
        ushort4 s4 = *reinterpret_cast<const ushort4*>(&Sb[(size_t)p.x * DD + cg * 4]);
        acc0 += v * bf2f(s4.x);
        acc1 += v * bf2f(s4.y);
        acc2 += v * bf2f(s4.z);
        acc3 += v * bf2f(s4.w);
        if (cg == 0) vs += v;
    }
    acc0 += __shfl_down(acc0, 32, 64);
    acc1 += __shfl_down(acc1, 32, 64);
    acc2 += __shfl_down(acc2, 32, 64);
    acc3 += __shfl_down(acc3, 32, 64);
    vs += __shfl_down(vs, 32, 64);
    if (lane < 32) {
        ushort4 o = {f2bf(acc0), f2bf(acc1), f2bf(acc2), f2bf(acc3)};
        *reinterpret_cast<ushort4*>(&Pb[(size_t)wave * DD + lane * 4]) = o;
        if (lane == 0) rvec[wave] = vs;
    }
}

// ---------------- restricted SpMM, all 3 t's fused ----------------
__global__ void __launch_bounds__(256) k_spmm_out3(const int* __restrict__ row_ptr,
                                                   const int2* __restrict__ pack,
                                                   const unsigned short* __restrict__ Pb,
                                                   const float* __restrict__ rvec,
                                                   const int* __restrict__ uidx,
                                                   const int* __restrict__ iidx,
                                                   const float* __restrict__ uvec,
                                                   const float* __restrict__ b0,
                                                   float* __restrict__ agg) {
    int slot = (int)((blockIdx.x * blockDim.x + threadIdx.x) >> 6);
    int lane = threadIdx.x & 63;
    if (slot >= 2 * B_SZ) return;
    int b = slot & (B_SZ - 1), side = slot >> 12;
    int row = side ? (U_CNT + iidx[b]) : uidx[b];
    int beg = row_ptr[row], end = row_ptr[row + 1];
    int half = lane >> 5, cg = lane & 31;
    float u0[4], u1[4], u2[4], bb[4];
    #pragma unroll
    for (int j = 0; j < 4; ++j) {
        int c = cg * 4 + j;
        u0[j] = uvec[c];
        u1[j] = uvec[DD + c];
        u2[j] = uvec[2 * DD + c];
        bb[j] = b0[c];
    }
    float a0[4] = {0, 0, 0, 0}, a1[4] = {0, 0, 0, 0}, a2[4] = {0, 0, 0, 0};
    for (int e = beg; e < end; e += 2) {
        int ee = e + half;
        int2 p = (ee < end) ? pack[ee] : make_int2(0, 0);
        float v = __int_as_float(p.y);
        float rr = rvec[p.x];
        ushort4 s4 = *reinterpret_cast<const ushort4*>(&Pb[(size_t)p.x * DD + cg * 4]);
        float pc[4] = {bf2f(s4.x), bf2f(s4.y), bf2f(s4.z), bf2f(s4.w)};
        #pragma unroll
        for (int j = 0; j < 4; ++j) {
            float base = pc[j] + bb[j];
            a0[j] += v * fmaxf(base + rr * u0[j], 0.f);
            a1[j] += v * fmaxf(base + rr * u1[j], 0.f);
            a2[j] += v * fmaxf(base + rr * u2[j], 0.f);
        }
    }
    #pragma unroll
    for (int j = 0; j < 4; ++j) {
        a0[j] += __shfl_down(a0[j], 32, 64);
        a1[j] += __shfl_down(a1[j], 32, 64);
        a2[j] += __shfl_down(a2[j], 32, 64);
    }
    if (lane < 32) {
        size_t rb = (size_t)slot * 3;
        float4 o0 = {a0[0], a0[1], a0[2], a0[3]};
        float4 o1 = {a1[0], a1[1], a1[2], a1[3]};
        float4 o2 = {a2[0], a2[1], a2[2], a2[3]};
        *reinterpret_cast<float4*>(&agg[(rb + 0) * DD + lane * 4]) = o0;
        *reinterpret_cast<float4*>(&agg[(rb + 1) * DD + lane * 4]) = o1;
        *reinterpret_cast<float4*>(&agg[(rb + 2) * DD + lane * 4]) = o2;
    }
}

// ---------------- head GEMM: tstack = relu(agg @ W1 + b1) ----------------
__global__ void __launch_bounds__(256) k_head(const float* __restrict__ agg,
                                              const float* __restrict__ W,
                                              const float* __restrict__ b1,
                                              float* __restrict__ tstack) {
    __shared__ float wlds[DD * DD];
    __shared__ float blds[DD];
    __shared__ float hlds[4][4][DD];
    int tid = threadIdx.x;
    for (int i = tid; i < DD * DD / 4; i += 256)
        reinterpret_cast<float4*>(wlds)[i] = reinterpret_cast<const float4*>(W)[i];
    if (tid < DD) blds[tid] = b1[tid];
    __syncthreads();
    int wave = tid >> 6, lane = tid & 63;
    const int NR = 2 * B_SZ * T_STEPS;
    const int ntiles = NR / 16;
    for (int tile = blockIdx.x; tile < ntiles; tile += gridDim.x) {
        int rbase = tile * 16 + wave * 4;
        for (int j = 0; j < 4; ++j) {
            int row = rbase + j;
            hlds[wave][j][lane] = agg[(size_t)row * DD + lane];
            hlds[wave][j][lane + 64] = agg[(size_t)row * DD + lane + 64];
        }
        float2 acc0 = {0.f, 0.f}, acc1 = {0.f, 0.f}, acc2 = {0.f, 0.f}, acc3 = {0.f, 0.f};
        #pragma unroll 8
        for (int k = 0; k < DD; ++k) {
            float2 w2 = *reinterpret_cast<float2*>(&wlds[k * DD + 2 * lane]);
            float hA = hlds[wave][0][k];
            float hB = hlds[wave][1][k];
            float hC = hlds[wave][2][k];
            float hD = hlds[wave][3][k];
            acc0.x += hA * w2.x; acc0.y += hA * w2.y;
            acc1.x += hB * w2.x; acc1.y += hB * w2.y;
            acc2.x += hC * w2.x; acc2.y += hC * w2.y;
            acc3.x += hD * w2.x; acc3.y += hD * w2.y;
        }
        float2 accs[4] = {acc0, acc1, acc2, acc3};
        for (int j = 0; j < 4; ++j) {
            int row = rbase + j;
            int slot = row / 3, t = row - slot * 3;
            int b = slot & (B_SZ - 1), side = slot >> 12;
            float2 o;
            o.x = fmaxf(accs[j].x + blds[2 * lane], 0.f);
            o.y = fmaxf(accs[j].y + blds[2 * lane + 1], 0.f);
            *reinterpret_cast<float2*>(
                &tstack[((size_t)b * T_STEPS + t) * 2 * DD + side * DD + 2 * lane]) = o;
        }
    }
}

// ---------------- attention + prediction head ----------------
__global__ void __launch_bounds__(128) k_final(const int* __restrict__ uidx,
                                               const int* __restrict__ iidx,
                                               const float* __restrict__ utab,
                                               const float* __restrict__ itab,
                                               const float* __restrict__ aw1,
                                               const float* __restrict__ ab1,
                                               const float* __restrict__ aw2,
                                               const float* __restrict__ ab2,
                                               const float* __restrict__ pw1,
                                               const float* __restrict__ pb1,
                                               const float* __restrict__ pw2,
                                               const float* __restrict__ pb2,
                                               const float* __restrict__ tstack,
                                               float* __restrict__ outp) {
    __shared__ float s[2 * DD];
    __shared__ float ah[DD];
    __shared__ float attn[T_STEPS];
    __shared__ float summed[2 * DD];
    __shared__ float red[2];
    int b = blockIdx.x, tid = threadIdx.x;
    int u = uidx[b], it = iidx[b];
    s[tid] = utab[(size_t)u * DD + tid];
    s[tid + DD] = itab[(size_t)it * DD + tid];
    __syncthreads();
    float acc = ab1[tid];
    for (int k = 0; k < 2 * DD; ++k) acc += s[k] * aw1[k * DD + tid];
    ah[tid] = fmaxf(acc, 0.f);
    __syncthreads();
    if (tid < T_STEPS) {
        float lg = ab2[tid];
        for (int k = 0; k < DD; ++k) lg += ah[k] * aw2[k * T_STEPS + tid];
        attn[tid] = lg;
    }
    __syncthreads();
    if (tid == 0) {
        float m = fmaxf(attn[0], fmaxf(attn[1], attn[2]));
        float e0 = expf(attn[0] - m), e1 = expf(attn[1] - m), e2 = expf(attn[2] - m);
        float inv = 1.f / (e0 + e1 + e2);
        attn[0] = e0 * inv;
        attn[1] = e1 * inv;
        attn[2] = e2 * inv;
    }
    __syncthreads();
    const float* tb = &tstack[(size_t)b * T_STEPS * 2 * DD];
    for (int k = tid; k < 2 * DD; k += 128)
        summed[k] = attn[0] * tb[k] + attn[1] * tb[2 * DD + k] + attn[2] * tb[4 * DD + k];
    __syncthreads();
    float ph = pb1[tid];
    for (int k = 0; k < 2 * DD; ++k) ph += summed[k] * pw1[k * DD + tid];
    ph = fmaxf(ph, 0.f);
    float contrib = ph * pw2[tid];
    for (int off = 32; off > 0; off >>= 1) contrib += __shfl_down(contrib, off, 64);
    if ((tid & 63) == 0) red[tid >> 6] = contrib;
    __syncthreads();
    if (tid == 0) outp[b] = red[0] + red[1] + pb2[0];
}

extern "C" void kernel_launch(void* const* d_in, const int* in_sizes, int n_in,
                              void* d_out, int out_size, void* d_ws, size_t ws_size,
                              hipStream_t stream) {
    const int* uidx = (const int*)d_in[0];
    const int* iidx = (const int*)d_in[1];
    const int* eidx = (const int*)d_in[2];
    const float* adj = (const float*)d_in[3];
    const float* utab = (const float*)d_in[4];
    const float* itab = (const float*)d_in[5];
    const float* temb = (const float*)d_in[6];
    const float* gw = (const float*)d_in[7];
    const float* gb = (const float*)d_in[8];
    const float* aw1 = (const float*)d_in[9];
    const float* ab1 = (const float*)d_in[10];
    const float* aw2 = (const float*)d_in[11];
    const float* ab2 = (const float*)d_in[12];
    const float* pw1 = (const float*)d_in[13];
    const float* pb1 = (const float*)d_in[14];
    const float* pw2 = (const float*)d_in[15];
    const float* pb2 = (const float*)d_in[16];

    char* ws = (char*)d_ws;
    size_t off = 0;
    auto alloc = [&](size_t bytes) {
        void* p = ws + off;
        off += (bytes + 255) & ~(size_t)255;
        return p;
    };
    int* bucket_cnt = (int*)alloc(NCOARSE * 4);
    int* pad_base = (int*)alloc((NCOARSE + 1) * 4);
    int* exact_base = (int*)alloc((NCOARSE + 1) * 4);
    int* bcur = (int*)alloc(NCOARSE * 4);
    int* row_ptr = (int*)alloc((size_t)(N_NODES + 1) * 4);
    int2* sorted = (int2*)alloc((size_t)E_CNT * 8);
    float* rvec = (float*)alloc((size_t)N_NODES * 4);
    float* uvec = (float*)alloc((size_t)T_STEPS * DD * 4);
    // union: binned (consumed by k_sort) then Sb (written by k_gemm0 afterwards)
    void* un = alloc((size_t)(E_CNT + 4096) * 8);
    int2* binned = (int2*)un;
    unsigned short* Sb = (unsigned short*)un;
    unsigned short* Pb = (unsigned short*)alloc((size_t)N_NODES * DD * 2);
    float* agg = (float*)alloc((size_t)2 * B_SZ * T_STEPS * DD * 4);
    float* tstack = (float*)alloc((size_t)B_SZ * T_STEPS * 2 * DD * 4);

    hipMemsetAsync(bucket_cnt, 0, NCOARSE * 4, stream);
    k_bin_count<<<256, 256, 0, stream>>>(eidx, bucket_cnt);
    k_bin_scan<<<1, 64, 0, stream>>>(bucket_cnt, pad_base, exact_base, bcur, row_ptr);
    k_bin_scatter<<<256, 256, 0, stream>>>(eidx, eidx + E_CNT, adj, bcur, binned);
    k_sort<<<NCOARSE, 256, 0, stream>>>(bucket_cnt, pad_base, exact_base, binned, sorted,
                                        row_ptr);
    // S = x @ W0 (bf16 store) — overwrites binned, which is dead after k_sort
    k_gemm0<<<2048, 256, 0, stream>>>(utab, itab, gw, Sb);
    k_uvec<<<1, DD, 0, stream>>>(temb, gw, uvec);
    // P = A @ S (bf16), r = A @ 1
    k_spmm_full<<<(N_NODES * 64) / 256 + 1, 256, 0, stream>>>(row_ptr, sorted, Sb, Pb,
                                                              rvec);
    // agg[slot][t] = A_restricted @ relu(P + r*u_t + b0), all t fused
    k_spmm_out3<<<(2 * B_SZ * 64) / 256, 256, 0, stream>>>(row_ptr, sorted, Pb, rvec,
                                                           uidx, iidx, uvec, gb, agg);
    // tstack = relu(agg @ W1 + b1)
    k_head<<<512, 256, 0, stream>>>(agg, gw + DD * DD, gb + DD, tstack);
    k_final<<<B_SZ, 128, 0, stream>>>(uidx, iidx, utab, itab, aw1, ab1, aw2, ab2, pw1,
                                      pb1, pw2, pb2, tstack, (float*)d_out);
}

// Round 4
// 460.181 us; speedup vs baseline: 3.0400x; 1.9838x over previous
//
#include <hip/hip_runtime.h>

#define U_CNT 50000
#define I_CNT 50000
#define N_NODES 100000
#define DD 128
#define T_STEPS 3
#define E_CNT 3200000
#define B_SZ 4096

#define NCOARSE 391   // ceil(100000 / 256): coarse bucket = dst >> 8
#define NBLK_BIN 256  // binning blocks; each owns a contiguous edge slice
#define CHUNK ((E_CNT + NBLK_BIN - 1) / NBLK_BIN)
#define SORT_CAP 10240

__device__ __forceinline__ float bf2f(unsigned short u) {
    return __uint_as_float(((unsigned int)u) << 16);
}
__device__ __forceinline__ unsigned short f2bf(float f) {
    unsigned int x = __float_as_uint(f);
    x += 0x7FFF + ((x >> 16) & 1);
    return (unsigned short)(x >> 16);
}

// ---------------- pass 1: per-block coarse histogram (non-atomic global write) ----------------
__global__ void __launch_bounds__(256) k_bin_count(const int* __restrict__ dst,
                                                   int* __restrict__ hist) {
    __shared__ int c[NCOARSE];
    int blk = blockIdx.x, tid = threadIdx.x;
    for (int j = tid; j < NCOARSE; j += 256) c[j] = 0;
    __syncthreads();
    int s0 = blk * CHUNK, s1 = min(E_CNT, s0 + CHUNK);
    for (int i = s0 + tid; i < s1; i += 256) atomicAdd(&c[dst[i] >> 8], 1);
    __syncthreads();
    for (int j = tid; j < NCOARSE; j += 256) hist[blk * NCOARSE + j] = c[j];
}

// ---------------- pass 2a: bucket totals + exclusive bucket bases ----------------
__global__ void __launch_bounds__(512) k_scan_a(const int* __restrict__ hist,
                                                int* __restrict__ exact_base,
                                                int* __restrict__ row_ptr) {
    __shared__ int tot[NCOARSE];
    int tid = threadIdx.x;
    for (int b = tid; b < NCOARSE; b += 512) {
        int s = 0;
        for (int blk = 0; blk < NBLK_BIN; ++blk) s += hist[blk * NCOARSE + b];
        tot[b] = s;
    }
    __syncthreads();
    if (tid == 0) {
        int run = 0;
        for (int b = 0; b < NCOARSE; ++b) {
            exact_base[b] = run;
            run += tot[b];
        }
        exact_base[NCOARSE] = run;
        row_ptr[N_NODES] = run;  // == E_CNT
    }
}

// ---------------- pass 2b: per-bucket scan over blocks -> exclusive (block,bucket) bases ----------------
__global__ void __launch_bounds__(NBLK_BIN) k_scan_b(int* __restrict__ hist,
                                                     const int* __restrict__ exact_base) {
    __shared__ int lds[NBLK_BIN];
    int b = blockIdx.x, tid = threadIdx.x;
    int v = hist[tid * NCOARSE + b];
    lds[tid] = v;
    __syncthreads();
    for (int off = 1; off < NBLK_BIN; off <<= 1) {
        int add = (tid >= off) ? lds[tid - off] : 0;
        __syncthreads();
        lds[tid] += add;
        __syncthreads();
    }
    hist[tid * NCOARSE + b] = exact_base[b] + lds[tid] - v;  // exclusive prefix
}

// ---------------- pass 3: deterministic scatter into exclusive regions ----------------
__global__ void __launch_bounds__(256) k_bin_scatter(const int* __restrict__ dst,
                                                     const int* __restrict__ src,
                                                     const float* __restrict__ val,
                                                     const int* __restrict__ blkbase,
                                                     int2* __restrict__ binned) {
    __shared__ int cur[NCOARSE];
    int blk = blockIdx.x, tid = threadIdx.x;
    for (int b = tid; b < NCOARSE; b += 256) cur[b] = blkbase[blk * NCOARSE + b];
    __syncthreads();
    int s0 = blk * CHUNK, s1 = min(E_CNT, s0 + CHUNK);
    for (int i = s0 + tid; i < s1; i += 256) {
        int d = dst[i];
        int b = d >> 8;
        int pos = atomicAdd(&cur[b], 1);
        binned[pos] = make_int2(src[i] | ((d & 255) << 20), __float_as_int(val[i]));
    }
}

// ---------------- per-bucket exact sort: emit dst-sorted pack + row_ptr ----------------
__global__ void __launch_bounds__(256) k_sort(const int* __restrict__ exact_base,
                                              const int2* __restrict__ binned,
                                              int2* __restrict__ outp,
                                              int* __restrict__ row_ptr) {
    __shared__ int hist[256], scn[256], cur[256];
    __shared__ unsigned short perm[SORT_CAP];
    int b = blockIdx.x, tid = threadIdx.x;
    int ebase = exact_base[b];
    int cnt = exact_base[b + 1] - ebase;
    if (cnt > SORT_CAP) cnt = SORT_CAP;  // safety clamp (never hit for this input)
    const int2* rbase = binned + ebase;
    int n0 = b << 8;
    hist[tid] = 0;
    __syncthreads();
    for (int i = tid; i < cnt; i += 256) atomicAdd(&hist[(rbase[i].x >> 20) & 255], 1);
    __syncthreads();
    scn[tid] = hist[tid];
    __syncthreads();
    for (int off = 1; off < 256; off <<= 1) {
        int v = (tid >= off) ? scn[tid - off] : 0;
        __syncthreads();
        scn[tid] += v;
        __syncthreads();
    }
    int excl = scn[tid] - hist[tid];
    cur[tid] = excl;
    if (n0 + tid < N_NODES) row_ptr[n0 + tid] = ebase + excl;
    __syncthreads();
    for (int i = tid; i < cnt; i += 256) {
        int dloc = (rbase[i].x >> 20) & 255;
        int pos = atomicAdd(&cur[dloc], 1);
        perm[pos] = (unsigned short)i;
    }
    __syncthreads();
    for (int i = tid; i < cnt; i += 256) {
        int2 p = rbase[perm[i]];
        p.x &= 0xFFFFF;
        outp[ebase + i] = p;
    }
}

// u_t = temporal_emb[t] @ W0  (tiny)
__global__ void k_uvec(const float* __restrict__ temb, const float* __restrict__ w0,
                       float* __restrict__ u) {
    int k = threadIdx.x;
    for (int t = 0; t < T_STEPS; ++t) {
        float acc = 0.f;
        for (int j = 0; j < DD; ++j) acc += temb[t * DD + j] * w0[j * DD + k];
        u[t * DD + k] = acc;
    }
}

// ---------------- GEMM: S = x @ W0 (fp32 compute, bf16 store) ----------------
__global__ void __launch_bounds__(256) k_gemm0(const float* __restrict__ utab,
                                               const float* __restrict__ itab,
                                               const float* __restrict__ W,
                                               unsigned short* __restrict__ outb) {
    __shared__ float wlds[DD * DD];
    __shared__ float hlds[4][4][DD];
    int tid = threadIdx.x;
    for (int i = tid; i < DD * DD / 4; i += 256)
        reinterpret_cast<float4*>(wlds)[i] = reinterpret_cast<const float4*>(W)[i];
    __syncthreads();
    int wave = tid >> 6, lane = tid & 63;
    const int ntiles = (N_NODES + 15) / 16;
    for (int tile = blockIdx.x; tile < ntiles; tile += gridDim.x) {
        int rbase = tile * 16 + wave * 4;
        for (int j = 0; j < 4; ++j) {
            int row = rbase + j;
            float h0 = 0.f, h1 = 0.f;
            if (row < N_NODES) {
                const float* x = (row < U_CNT) ? &utab[(size_t)row * DD]
                                               : &itab[(size_t)(row - U_CNT) * DD];
                h0 = x[lane];
                h1 = x[lane + 64];
            }
            hlds[wave][j][lane] = h0;
            hlds[wave][j][lane + 64] = h1;
        }
        float2 acc0 = {0.f, 0.f}, acc1 = {0.f, 0.f}, acc2 = {0.f, 0.f}, acc3 = {0.f, 0.f};
        #pragma unroll 8
        for (int k = 0; k < DD; ++k) {
            float2 w2 = *reinterpret_cast<float2*>(&wlds[k * DD + 2 * lane]);
            float hA = hlds[wave][0][k];
            float hB = hlds[wave][1][k];
            float hC = hlds[wave][2][k];
            float hD = hlds[wave][3][k];
            acc0.x += hA * w2.x; acc0.y += hA * w2.y;
            acc1.x += hB * w2.x; acc1.y += hB * w2.y;
            acc2.x += hC * w2.x; acc2.y += hC * w2.y;
            acc3.x += hD * w2.x; acc3.y += hD * w2.y;
        }
        float2 accs[4] = {acc0, acc1, acc2, acc3};
        for (int j = 0; j < 4; ++j) {
            int row = rbase + j;
            if (row < N_NODES) {
                ushort2 o = {f2bf(accs[j].x), f2bf(accs[j].y)};
                *reinterpret_cast<ushort2*>(&outb[(size_t)row * DD + 2 * lane]) = o;
            }
        }
    }
}

// ---------------- full SpMM: P = A*S (bf16 in/out), r = A*1 ----------------
__global__ void __launch_bounds__(256) k_spmm_full(const int* __restrict__ row_ptr,
                                                   const int2* __restrict__ pack,
                                                   const unsigned short* __restrict__ Sb,
                                                   unsigned short* __restrict__ Pb,
                                                   float* __restrict__ rvec) {
    int wave = (int)((blockIdx.x * blockDim.x + threadIdx.x) >> 6);
    int lane = threadIdx.x & 63;
    if (wave >= N_NODES) return;
    int beg = row_ptr[wave], end = row_ptr[wave + 1];
    int half = lane >> 5, cg = lane & 31;
    float acc0 = 0.f, acc1 = 0.f, acc2 = 0.f, acc3 = 0.f, vs = 0.f;
    for (int e = beg; e < end; e += 2) {
        int ee = e + half;
        int2 p = (ee < end) ? pack[ee] : make_int2(0, 0);
        float v = __int_as_float(p.y);
        ushort4 s4 = *reinterpret_cast<const ushort4*>(&Sb[(size_t)p.x * DD + cg * 4]);
        acc0 += v * bf2f(s4.x);
        acc1 += v * bf2f(s4.y);
        acc2 += v * bf2f(s4.z);
        acc3 += v * bf2f(s4.w);
        if (cg == 0) vs += v;
    }
    acc0 += __shfl_down(acc0, 32, 64);
    acc1 += __shfl_down(acc1, 32, 64);
    acc2 += __shfl_down(acc2, 32, 64);
    acc3 += __shfl_down(acc3, 32, 64);
    vs += __shfl_down(vs, 32, 64);
    if (lane < 32) {
        ushort4 o = {f2bf(acc0), f2bf(acc1), f2bf(acc2), f2bf(acc3)};
        *reinterpret_cast<ushort4*>(&Pb[(size_t)wave * DD + lane * 4]) = o;
        if (lane == 0) rvec[wave] = vs;
    }
}

// ---------------- restricted SpMM, all 3 t's fused ----------------
__global__ void __launch_bounds__(256) k_spmm_out3(const int* __restrict__ row_ptr,
                                                   const int2* __restrict__ pack,
                                                   const unsigned short* __restrict__ Pb,
                                                   const float* __restrict__ rvec,
                                                   const int* __restrict__ uidx,
                                                   const int* __restrict__ iidx,
                                                   const float* __restrict__ uvec,
                                                   const float* __restrict__ b0,
                                                   float* __restrict__ agg) {
    int slot = (int)((blockIdx.x * blockDim.x + threadIdx.x) >> 6);
    int lane = threadIdx.x & 63;
    if (slot >= 2 * B_SZ) return;
    int b = slot & (B_SZ - 1), side = slot >> 12;
    int row = side ? (U_CNT + iidx[b]) : uidx[b];
    int beg = row_ptr[row], end = row_ptr[row + 1];
    int half = lane >> 5, cg = lane & 31;
    float u0[4], u1[4], u2[4], bb[4];
    #pragma unroll
    for (int j = 0; j < 4; ++j) {
        int c = cg * 4 + j;
        u0[j] = uvec[c];
        u1[j] = uvec[DD + c];
        u2[j] = uvec[2 * DD + c];
        bb[j] = b0[c];
    }
    float a0[4] = {0, 0, 0, 0}, a1[4] = {0, 0, 0, 0}, a2[4] = {0, 0, 0, 0};
    for (int e = beg; e < end; e += 2) {
        int ee = e + half;
        int2 p = (ee < end) ? pack[ee] : make_int2(0, 0);
        float v = __int_as_float(p.y);
        float rr = rvec[p.x];
        ushort4 s4 = *reinterpret_cast<const ushort4*>(&Pb[(size_t)p.x * DD + cg * 4]);
        float pc[4] = {bf2f(s4.x), bf2f(s4.y), bf2f(s4.z), bf2f(s4.w)};
        #pragma unroll
        for (int j = 0; j < 4; ++j) {
            float base = pc[j] + bb[j];
            a0[j] += v * fmaxf(base + rr * u0[j], 0.f);
            a1[j] += v * fmaxf(base + rr * u1[j], 0.f);
            a2[j] += v * fmaxf(base + rr * u2[j], 0.f);
        }
    }
    #pragma unroll
    for (int j = 0; j < 4; ++j) {
        a0[j] += __shfl_down(a0[j], 32, 64);
        a1[j] += __shfl_down(a1[j], 32, 64);
        a2[j] += __shfl_down(a2[j], 32, 64);
    }
    if (lane < 32) {
        size_t rb = (size_t)slot * 3;
        float4 o0 = {a0[0], a0[1], a0[2], a0[3]};
        float4 o1 = {a1[0], a1[1], a1[2], a1[3]};
        float4 o2 = {a2[0], a2[1], a2[2], a2[3]};
        *reinterpret_cast<float4*>(&agg[(rb + 0) * DD + lane * 4]) = o0;
        *reinterpret_cast<float4*>(&agg[(rb + 1) * DD + lane * 4]) = o1;
        *reinterpret_cast<float4*>(&agg[(rb + 2) * DD + lane * 4]) = o2;
    }
}

// ---------------- head GEMM: tstack = relu(agg @ W1 + b1) ----------------
__global__ void __launch_bounds__(256) k_head(const float* __restrict__ agg,
                                              const float* __restrict__ W,
                                              const float* __restrict__ b1,
                                              float* __restrict__ tstack) {
    __shared__ float wlds[DD * DD];
    __shared__ float blds[DD];
    __shared__ float hlds[4][4][DD];
    int tid = threadIdx.x;
    for (int i = tid; i < DD * DD / 4; i += 256)
        reinterpret_cast<float4*>(wlds)[i] = reinterpret_cast<const float4*>(W)[i];
    if (tid < DD) blds[tid] = b1[tid];
    __syncthreads();
    int wave = tid >> 6, lane = tid & 63;
    const int NR = 2 * B_SZ * T_STEPS;
    const int ntiles = NR / 16;
    for (int tile = blockIdx.x; tile < ntiles; tile += gridDim.x) {
        int rbase = tile * 16 + wave * 4;
        for (int j = 0; j < 4; ++j) {
            int row = rbase + j;
            hlds[wave][j][lane] = agg[(size_t)row * DD + lane];
            hlds[wave][j][lane + 64] = agg[(size_t)row * DD + lane + 64];
        }
        float2 acc0 = {0.f, 0.f}, acc1 = {0.f, 0.f}, acc2 = {0.f, 0.f}, acc3 = {0.f, 0.f};
        #pragma unroll 8
        for (int k = 0; k < DD; ++k) {
            float2 w2 = *reinterpret_cast<float2*>(&wlds[k * DD + 2 * lane]);
            float hA = hlds[wave][0][k];
            float hB = hlds[wave][1][k];
            float hC = hlds[wave][2][k];
            float hD = hlds[wave][3][k];
            acc0.x += hA * w2.x; acc0.y += hA * w2.y;
            acc1.x += hB * w2.x; acc1.y += hB * w2.y;
            acc2.x += hC * w2.x; acc2.y += hC * w2.y;
            acc3.x += hD * w2.x; acc3.y += hD * w2.y;
        }
        float2 accs[4] = {acc0, acc1, acc2, acc3};
        for (int j = 0; j < 4; ++j) {
            int row = rbase + j;
            int slot = row / 3, t = row - slot * 3;
            int b = slot & (B_SZ - 1), side = slot >> 12;
            float2 o;
            o.x = fmaxf(accs[j].x + blds[2 * lane], 0.f);
            o.y = fmaxf(accs[j].y + blds[2 * lane + 1], 0.f);
            *reinterpret_cast<float2*>(
                &tstack[((size_t)b * T_STEPS + t) * 2 * DD + side * DD + 2 * lane]) = o;
        }
    }
}

// ---------------- attention + prediction head ----------------
__global__ void __launch_bounds__(128) k_final(const int* __restrict__ uidx,
                                               const int* __restrict__ iidx,
                                               const float* __restrict__ utab,
                                               const float* __restrict__ itab,
                                               const float* __restrict__ aw1,
                                               const float* __restrict__ ab1,
                                               const float* __restrict__ aw2,
                                               const float* __restrict__ ab2,
                                               const float* __restrict__ pw1,
                                               const float* __restrict__ pb1,
                                               const float* __restrict__ pw2,
                                               const float* __restrict__ pb2,
                                               const float* __restrict__ tstack,
                                               float* __restrict__ outp) {
    __shared__ float s[2 * DD];
    __shared__ float ah[DD];
    __shared__ float attn[T_STEPS];
    __shared__ float summed[2 * DD];
    __shared__ float red[2];
    int b = blockIdx.x, tid = threadIdx.x;
    int u = uidx[b], it = iidx[b];
    s[tid] = utab[(size_t)u * DD + tid];
    s[tid + DD] = itab[(size_t)it * DD + tid];
    __syncthreads();
    float acc = ab1[tid];
    for (int k = 0; k < 2 * DD; ++k) acc += s[k] * aw1[k * DD + tid];
    ah[tid] = fmaxf(acc, 0.f);
    __syncthreads();
    if (tid < T_STEPS) {
        float lg = ab2[tid];
        for (int k = 0; k < DD; ++k) lg += ah[k] * aw2[k * T_STEPS + tid];
        attn[tid] = lg;
    }
    __syncthreads();
    if (tid == 0) {
        float m = fmaxf(attn[0], fmaxf(attn[1], attn[2]));
        float e0 = expf(attn[0] - m), e1 = expf(attn[1] - m), e2 = expf(attn[2] - m);
        float inv = 1.f / (e0 + e1 + e2);
        attn[0] = e0 * inv;
        attn[1] = e1 * inv;
        attn[2] = e2 * inv;
    }
    __syncthreads();
    const float* tb = &tstack[(size_t)b * T_STEPS * 2 * DD];
    for (int k = tid; k < 2 * DD; k += 128)
        summed[k] = attn[0] * tb[k] + attn[1] * tb[2 * DD + k] + attn[2] * tb[4 * DD + k];
    __syncthreads();
    float ph = pb1[tid];
    for (int k = 0; k < 2 * DD; ++k) ph += summed[k] * pw1[k * DD + tid];
    ph = fmaxf(ph, 0.f);
    float contrib = ph * pw2[tid];
    for (int off = 32; off > 0; off >>= 1) contrib += __shfl_down(contrib, off, 64);
    if ((tid & 63) == 0) red[tid >> 6] = contrib;
    __syncthreads();
    if (tid == 0) outp[b] = red[0] + red[1] + pb2[0];
}

extern "C" void kernel_launch(void* const* d_in, const int* in_sizes, int n_in,
                              void* d_out, int out_size, void* d_ws, size_t ws_size,
                              hipStream_t stream) {
    const int* uidx = (const int*)d_in[0];
    const int* iidx = (const int*)d_in[1];
    const int* eidx = (const int*)d_in[2];
    const float* adj = (const float*)d_in[3];
    const float* utab = (const float*)d_in[4];
    const float* itab = (const float*)d_in[5];
    const float* temb = (const float*)d_in[6];
    const float* gw = (const float*)d_in[7];
    const float* gb = (const float*)d_in[8];
    const float* aw1 = (const float*)d_in[9];
    const float* ab1 = (const float*)d_in[10];
    const float* aw2 = (const float*)d_in[11];
    const float* ab2 = (const float*)d_in[12];
    const float* pw1 = (const float*)d_in[13];
    const float* pb1 = (const float*)d_in[14];
    const float* pw2 = (const float*)d_in[15];
    const float* pb2 = (const float*)d_in[16];

    char* ws = (char*)d_ws;
    size_t off = 0;
    auto alloc = [&](size_t bytes) {
        void* p = ws + off;
        off += (bytes + 255) & ~(size_t)255;
        return p;
    };
    int* hist = (int*)alloc((size_t)NBLK_BIN * NCOARSE * 4);
    int* exact_base = (int*)alloc((NCOARSE + 1) * 4);
    int* row_ptr = (int*)alloc((size_t)(N_NODES + 1) * 4);
    int2* sorted = (int2*)alloc((size_t)E_CNT * 8);
    float* rvec = (float*)alloc((size_t)N_NODES * 4);
    float* uvec = (float*)alloc((size_t)T_STEPS * DD * 4);
    // union: binned (consumed by k_sort) then Sb (written by k_gemm0 afterwards)
    void* un = alloc((size_t)E_CNT * 8);
    int2* binned = (int2*)un;
    unsigned short* Sb = (unsigned short*)un;
    unsigned short* Pb = (unsigned short*)alloc((size_t)N_NODES * DD * 2);
    float* agg = (float*)alloc((size_t)2 * B_SZ * T_STEPS * DD * 4);
    float* tstack = (float*)alloc((size_t)B_SZ * T_STEPS * 2 * DD * 4);

    k_bin_count<<<NBLK_BIN, 256, 0, stream>>>(eidx, hist);
    k_scan_a<<<1, 512, 0, stream>>>(hist, exact_base, row_ptr);
    k_scan_b<<<NCOARSE, NBLK_BIN, 0, stream>>>(hist, exact_base);
    k_bin_scatter<<<NBLK_BIN, 256, 0, stream>>>(eidx, eidx + E_CNT, adj, hist, binned);
    k_sort<<<NCOARSE, 256, 0, stream>>>(exact_base, binned, sorted, row_ptr);
    // S = x @ W0 (bf16 store) — overwrites binned, which is dead after k_sort
    k_gemm0<<<2048, 256, 0, stream>>>(utab, itab, gw, Sb);
    k_uvec<<<1, DD, 0, stream>>>(temb, gw, uvec);
    // P = A @ S (bf16), r = A @ 1
    k_spmm_full<<<(N_NODES * 64) / 256 + 1, 256, 0, stream>>>(row_ptr, sorted, Sb, Pb,
                                                              rvec);
    // agg[slot][t] = A_restricted @ relu(P + r*u_t + b0), all t fused
    k_spmm_out3<<<(2 * B_SZ * 64) / 256, 256, 0, stream>>>(row_ptr, sorted, Pb, rvec,
                                                           uidx, iidx, uvec, gb, agg);
    // tstack = relu(agg @ W1 + b1)
    k_head<<<512, 256, 0, stream>>>(agg, gw + DD * DD, gb + DD, tstack);
    k_final<<<B_SZ, 128, 0, stream>>>(uidx, iidx, utab, itab, aw1, ab1, aw2, ab2, pw1,
                                      pb1, pw2, pb2, tstack, (float*)d_out);
}

// Round 5
// 438.442 us; speedup vs baseline: 3.1908x; 1.0496x over previous
//
#include <hip/hip_runtime.h>

#define U_CNT 50000
#define I_CNT 50000
#define N_NODES 100000
#define DD 128
#define T_STEPS 3
#define E_CNT 3200000
#define B_SZ 4096

#define NCOARSE 391   // ceil(100000 / 256): coarse bucket = dst >> 8
#define NBLK_BIN 256  // binning blocks; each owns a contiguous edge slice
#define CHUNK ((E_CNT + NBLK_BIN - 1) / NBLK_BIN)
#define SORT_CAP 10240

__device__ __forceinline__ float bf2f(unsigned short u) {
    return __uint_as_float(((unsigned int)u) << 16);
}
__device__ __forceinline__ unsigned short f2bf(float f) {
    unsigned int x = __float_as_uint(f);
    x += 0x7FFF + ((x >> 16) & 1);
    return (unsigned short)(x >> 16);
}

// ---------------- pass 1: per-block coarse histogram (non-atomic global write) ----------------
__global__ void __launch_bounds__(256) k_bin_count(const int* __restrict__ dst,
                                                   int* __restrict__ hist) {
    __shared__ int c[NCOARSE];
    int blk = blockIdx.x, tid = threadIdx.x;
    for (int j = tid; j < NCOARSE; j += 256) c[j] = 0;
    __syncthreads();
    int s0 = blk * CHUNK, s1 = min(E_CNT, s0 + CHUNK);
    for (int i = s0 + tid; i < s1; i += 256)
        atomicAdd(&c[__builtin_nontemporal_load(&dst[i]) >> 8], 1);
    __syncthreads();
    for (int j = tid; j < NCOARSE; j += 256) hist[blk * NCOARSE + j] = c[j];
}

// ---------------- pass 2a: bucket totals + exclusive bucket bases ----------------
__global__ void __launch_bounds__(512) k_scan_a(const int* __restrict__ hist,
                                                int* __restrict__ exact_base,
                                                int* __restrict__ row_ptr) {
    __shared__ int tot[NCOARSE];
    int tid = threadIdx.x;
    for (int b = tid; b < NCOARSE; b += 512) {
        int s = 0;
        for (int blk = 0; blk < NBLK_BIN; ++blk) s += hist[blk * NCOARSE + b];
        tot[b] = s;
    }
    __syncthreads();
    if (tid == 0) {
        int run = 0;
        for (int b = 0; b < NCOARSE; ++b) {
            exact_base[b] = run;
            run += tot[b];
        }
        exact_base[NCOARSE] = run;
        row_ptr[N_NODES] = run;  // == E_CNT
    }
}

// ---------------- pass 2b: per-bucket scan over blocks -> exclusive (block,bucket) bases ----------------
__global__ void __launch_bounds__(NBLK_BIN) k_scan_b(int* __restrict__ hist,
                                                     const int* __restrict__ exact_base) {
    __shared__ int lds[NBLK_BIN];
    int b = blockIdx.x, tid = threadIdx.x;
    int v = hist[tid * NCOARSE + b];
    lds[tid] = v;
    __syncthreads();
    for (int off = 1; off < NBLK_BIN; off <<= 1) {
        int add = (tid >= off) ? lds[tid - off] : 0;
        __syncthreads();
        lds[tid] += add;
        __syncthreads();
    }
    hist[tid * NCOARSE + b] = exact_base[b] + lds[tid] - v;  // exclusive prefix
}

// ---------------- pass 3: deterministic scatter into exclusive regions ----------------
__global__ void __launch_bounds__(256) k_bin_scatter(const int* __restrict__ dst,
                                                     const int* __restrict__ src,
                                                     const float* __restrict__ val,
                                                     const int* __restrict__ blkbase,
                                                     int2* __restrict__ binned) {
    __shared__ int cur[NCOARSE];
    int blk = blockIdx.x, tid = threadIdx.x;
    for (int b = tid; b < NCOARSE; b += 256) cur[b] = blkbase[blk * NCOARSE + b];
    __syncthreads();
    int s0 = blk * CHUNK, s1 = min(E_CNT, s0 + CHUNK);
    for (int i = s0 + tid; i < s1; i += 256) {
        int d = __builtin_nontemporal_load(&dst[i]);
        int s = __builtin_nontemporal_load(&src[i]);
        float w = __builtin_nontemporal_load(&val[i]);
        int b = d >> 8;
        int pos = atomicAdd(&cur[b], 1);
        binned[pos] = make_int2(s | ((d & 255) << 20), __float_as_int(w));
    }
}

// ---------------- per-bucket exact sort: emit dst-sorted pack + row_ptr ----------------
__global__ void __launch_bounds__(256) k_sort(const int* __restrict__ exact_base,
                                              const int2* __restrict__ binned,
                                              int2* __restrict__ outp,
                                              int* __restrict__ row_ptr) {
    __shared__ int hist[256], scn[256], cur[256];
    __shared__ unsigned short perm[SORT_CAP];
    int b = blockIdx.x, tid = threadIdx.x;
    int ebase = exact_base[b];
    int cnt = exact_base[b + 1] - ebase;
    if (cnt > SORT_CAP) cnt = SORT_CAP;  // safety clamp (never hit for this input)
    const int2* rbase = binned + ebase;
    int n0 = b << 8;
    hist[tid] = 0;
    __syncthreads();
    for (int i = tid; i < cnt; i += 256) atomicAdd(&hist[(rbase[i].x >> 20) & 255], 1);
    __syncthreads();
    scn[tid] = hist[tid];
    __syncthreads();
    for (int off = 1; off < 256; off <<= 1) {
        int v = (tid >= off) ? scn[tid - off] : 0;
        __syncthreads();
        scn[tid] += v;
        __syncthreads();
    }
    int excl = scn[tid] - hist[tid];
    cur[tid] = excl;
    if (n0 + tid < N_NODES) row_ptr[n0 + tid] = ebase + excl;
    __syncthreads();
    for (int i = tid; i < cnt; i += 256) {
        int dloc = (rbase[i].x >> 20) & 255;
        int pos = atomicAdd(&cur[dloc], 1);
        perm[pos] = (unsigned short)i;
    }
    __syncthreads();
    for (int i = tid; i < cnt; i += 256) {
        int2 p = rbase[perm[i]];
        p.x &= 0xFFFFF;
        outp[ebase + i] = p;
    }
}

// u_t = temporal_emb[t] @ W0  (tiny)
__global__ void k_uvec(const float* __restrict__ temb, const float* __restrict__ w0,
                       float* __restrict__ u) {
    int k = threadIdx.x;
    for (int t = 0; t < T_STEPS; ++t) {
        float acc = 0.f;
        for (int j = 0; j < DD; ++j) acc += temb[t * DD + j] * w0[j * DD + k];
        u[t * DD + k] = acc;
    }
}

// ---------------- GEMM: S = x @ W0 (fp32 compute, bf16 store) ----------------
__global__ void __launch_bounds__(256) k_gemm0(const float* __restrict__ utab,
                                               const float* __restrict__ itab,
                                               const float* __restrict__ W,
                                               unsigned short* __restrict__ outb) {
    __shared__ float wlds[DD * DD];
    __shared__ float hlds[4][4][DD];
    int tid = threadIdx.x;
    for (int i = tid; i < DD * DD / 4; i += 256)
        reinterpret_cast<float4*>(wlds)[i] = reinterpret_cast<const float4*>(W)[i];
    __syncthreads();
    int wave = tid >> 6, lane = tid & 63;
    const int ntiles = (N_NODES + 15) / 16;
    for (int tile = blockIdx.x; tile < ntiles; tile += gridDim.x) {
        int rbase = tile * 16 + wave * 4;
        for (int j = 0; j < 4; ++j) {
            int row = rbase + j;
            float h0 = 0.f, h1 = 0.f;
            if (row < N_NODES) {
                const float* x = (row < U_CNT) ? &utab[(size_t)row * DD]
                                               : &itab[(size_t)(row - U_CNT) * DD];
                h0 = x[lane];
                h1 = x[lane + 64];
            }
            hlds[wave][j][lane] = h0;
            hlds[wave][j][lane + 64] = h1;
        }
        float2 acc0 = {0.f, 0.f}, acc1 = {0.f, 0.f}, acc2 = {0.f, 0.f}, acc3 = {0.f, 0.f};
        #pragma unroll 8
        for (int k = 0; k < DD; ++k) {
            float2 w2 = *reinterpret_cast<float2*>(&wlds[k * DD + 2 * lane]);
            float hA = hlds[wave][0][k];
            float hB = hlds[wave][1][k];
            float hC = hlds[wave][2][k];
            float hD = hlds[wave][3][k];
            acc0.x += hA * w2.x; acc0.y += hA * w2.y;
            acc1.x += hB * w2.x; acc1.y += hB * w2.y;
            acc2.x += hC * w2.x; acc2.y += hC * w2.y;
            acc3.x += hD * w2.x; acc3.y += hD * w2.y;
        }
        float2 accs[4] = {acc0, acc1, acc2, acc3};
        for (int j = 0; j < 4; ++j) {
            int row = rbase + j;
            if (row < N_NODES) {
                ushort2 o = {f2bf(accs[j].x), f2bf(accs[j].y)};
                *reinterpret_cast<ushort2*>(&outb[(size_t)row * DD + 2 * lane]) = o;
            }
        }
    }
}

// ---------------- full SpMM: P = A*S (bf16 in/out), r = A*1 ----------------
// one wave per dst row; 4 edges/iter, 16 lanes x 16B (int4 = 8 bf16 cols) per edge
__global__ void __launch_bounds__(256) k_spmm_full(const int* __restrict__ row_ptr,
                                                   const long long* __restrict__ packll,
                                                   const unsigned short* __restrict__ Sb,
                                                   unsigned short* __restrict__ Pb,
                                                   float* __restrict__ rvec) {
    int wave = (int)((blockIdx.x * blockDim.x + threadIdx.x) >> 6);
    int lane = threadIdx.x & 63;
    if (wave >= N_NODES) return;
    int beg = row_ptr[wave], end = row_ptr[wave + 1];
    int q = lane >> 4;    // which of 4 edges this lane serves
    int cg = lane & 15;   // 16 lanes x 8 cols = 128 cols
    float acc[8] = {0.f, 0.f, 0.f, 0.f, 0.f, 0.f, 0.f, 0.f};
    float vs = 0.f;
    for (int e = beg; e < end; e += 4) {
        int ee = e + q;
        long long pl = 0;
        if (ee < end) pl = __builtin_nontemporal_load(&packll[ee]);
        int sx = (int)(unsigned int)(pl & 0xFFFFFFFFLL);
        float v = __int_as_float((int)(pl >> 32));
        const int4 s4 = *reinterpret_cast<const int4*>(&Sb[((size_t)sx << 7) + (cg << 3)]);
        float f0 = __uint_as_float(((unsigned)s4.x) << 16);
        float f1 = __uint_as_float(((unsigned)s4.x) & 0xFFFF0000u);
        float f2 = __uint_as_float(((unsigned)s4.y) << 16);
        float f3 = __uint_as_float(((unsigned)s4.y) & 0xFFFF0000u);
        float f4 = __uint_as_float(((unsigned)s4.z) << 16);
        float f5 = __uint_as_float(((unsigned)s4.z) & 0xFFFF0000u);
        float f6 = __uint_as_float(((unsigned)s4.w) << 16);
        float f7 = __uint_as_float(((unsigned)s4.w) & 0xFFFF0000u);
        acc[0] += v * f0;
        acc[1] += v * f1;
        acc[2] += v * f2;
        acc[3] += v * f3;
        acc[4] += v * f4;
        acc[5] += v * f5;
        acc[6] += v * f6;
        acc[7] += v * f7;
        if (cg == 0) vs += v;
    }
    #pragma unroll
    for (int j = 0; j < 8; ++j) {
        acc[j] += __shfl_down(acc[j], 32, 64);
        acc[j] += __shfl_down(acc[j], 16, 64);
    }
    vs += __shfl_down(vs, 32, 64);
    vs += __shfl_down(vs, 16, 64);
    if (lane < 16) {
        unsigned w0 = ((unsigned)f2bf(acc[1]) << 16) | f2bf(acc[0]);
        unsigned w1 = ((unsigned)f2bf(acc[3]) << 16) | f2bf(acc[2]);
        unsigned w2 = ((unsigned)f2bf(acc[5]) << 16) | f2bf(acc[4]);
        unsigned w3 = ((unsigned)f2bf(acc[7]) << 16) | f2bf(acc[6]);
        int4 o = make_int4(w0, w1, w2, w3);
        *reinterpret_cast<int4*>(&Pb[((size_t)wave << 7) + (lane << 3)]) = o;
        if (lane == 0) rvec[wave] = vs;
    }
}

// ---------------- restricted SpMM, all 3 t's fused ----------------
__global__ void __launch_bounds__(256) k_spmm_out3(const int* __restrict__ row_ptr,
                                                   const long long* __restrict__ packll,
                                                   const unsigned short* __restrict__ Pb,
                                                   const float* __restrict__ rvec,
                                                   const int* __restrict__ uidx,
                                                   const int* __restrict__ iidx,
                                                   const float* __restrict__ uvec,
                                                   const float* __restrict__ b0,
                                                   float* __restrict__ agg) {
    int slot = (int)((blockIdx.x * blockDim.x + threadIdx.x) >> 6);
    int lane = threadIdx.x & 63;
    if (slot >= 2 * B_SZ) return;
    int b = slot & (B_SZ - 1), side = slot >> 12;
    int row = side ? (U_CNT + iidx[b]) : uidx[b];
    int beg = row_ptr[row], end = row_ptr[row + 1];
    int half = lane >> 5, cg = lane & 31;
    float u0[4], u1[4], u2[4], bb[4];
    #pragma unroll
    for (int j = 0; j < 4; ++j) {
        int c = cg * 4 + j;
        u0[j] = uvec[c];
        u1[j] = uvec[DD + c];
        u2[j] = uvec[2 * DD + c];
        bb[j] = b0[c];
    }
    float a0[4] = {0, 0, 0, 0}, a1[4] = {0, 0, 0, 0}, a2[4] = {0, 0, 0, 0};
    for (int e = beg; e < end; e += 2) {
        int ee = e + half;
        long long pl = 0;
        if (ee < end) pl = __builtin_nontemporal_load(&packll[ee]);
        int sx = (int)(unsigned int)(pl & 0xFFFFFFFFLL);
        float v = __int_as_float((int)(pl >> 32));
        float rr = rvec[sx];
        ushort4 s4 = *reinterpret_cast<const ushort4*>(&Pb[(size_t)sx * DD + cg * 4]);
        float pc[4] = {bf2f(s4.x), bf2f(s4.y), bf2f(s4.z), bf2f(s4.w)};
        #pragma unroll
        for (int j = 0; j < 4; ++j) {
            float base = pc[j] + bb[j];
            a0[j] += v * fmaxf(base + rr * u0[j], 0.f);
            a1[j] += v * fmaxf(base + rr * u1[j], 0.f);
            a2[j] += v * fmaxf(base + rr * u2[j], 0.f);
        }
    }
    #pragma unroll
    for (int j = 0; j < 4; ++j) {
        a0[j] += __shfl_down(a0[j], 32, 64);
        a1[j] += __shfl_down(a1[j], 32, 64);
        a2[j] += __shfl_down(a2[j], 32, 64);
    }
    if (lane < 32) {
        size_t rb = (size_t)slot * 3;
        float4 o0 = {a0[0], a0[1], a0[2], a0[3]};
        float4 o1 = {a1[0], a1[1], a1[2], a1[3]};
        float4 o2 = {a2[0], a2[1], a2[2], a2[3]};
        *reinterpret_cast<float4*>(&agg[(rb + 0) * DD + lane * 4]) = o0;
        *reinterpret_cast<float4*>(&agg[(rb + 1) * DD + lane * 4]) = o1;
        *reinterpret_cast<float4*>(&agg[(rb + 2) * DD + lane * 4]) = o2;
    }
}

// ---------------- head GEMM: tstack = relu(agg @ W1 + b1) ----------------
__global__ void __launch_bounds__(256) k_head(const float* __restrict__ agg,
                                              const float* __restrict__ W,
                                              const float* __restrict__ b1,
                                              float* __restrict__ tstack) {
    __shared__ float wlds[DD * DD];
    __shared__ float blds[DD];
    __shared__ float hlds[4][4][DD];
    int tid = threadIdx.x;
    for (int i = tid; i < DD * DD / 4; i += 256)
        reinterpret_cast<float4*>(wlds)[i] = reinterpret_cast<const float4*>(W)[i];
    if (tid < DD) blds[tid] = b1[tid];
    __syncthreads();
    int wave = tid >> 6, lane = tid & 63;
    const int NR = 2 * B_SZ * T_STEPS;
    const int ntiles = NR / 16;
    for (int tile = blockIdx.x; tile < ntiles; tile += gridDim.x) {
        int rbase = tile * 16 + wave * 4;
        for (int j = 0; j < 4; ++j) {
            int row = rbase + j;
            hlds[wave][j][lane] = agg[(size_t)row * DD + lane];
            hlds[wave][j][lane + 64] = agg[(size_t)row * DD + lane + 64];
        }
        float2 acc0 = {0.f, 0.f}, acc1 = {0.f, 0.f}, acc2 = {0.f, 0.f}, acc3 = {0.f, 0.f};
        #pragma unroll 8
        for (int k = 0; k < DD; ++k) {
            float2 w2 = *reinterpret_cast<float2*>(&wlds[k * DD + 2 * lane]);
            float hA = hlds[wave][0][k];
            float hB = hlds[wave][1][k];
            float hC = hlds[wave][2][k];
            float hD = hlds[wave][3][k];
            acc0.x += hA * w2.x; acc0.y += hA * w2.y;
            acc1.x += hB * w2.x; acc1.y += hB * w2.y;
            acc2.x += hC * w2.x; acc2.y += hC * w2.y;
            acc3.x += hD * w2.x; acc3.y += hD * w2.y;
        }
        float2 accs[4] = {acc0, acc1, acc2, acc3};
        for (int j = 0; j < 4; ++j) {
            int row = rbase + j;
            int slot = row / 3, t = row - slot * 3;
            int b = slot & (B_SZ - 1), side = slot >> 12;
            float2 o;
            o.x = fmaxf(accs[j].x + blds[2 * lane], 0.f);
            o.y = fmaxf(accs[j].y + blds[2 * lane + 1], 0.f);
            *reinterpret_cast<float2*>(
                &tstack[((size_t)b * T_STEPS + t) * 2 * DD + side * DD + 2 * lane]) = o;
        }
    }
}

// ---------------- attention + prediction head ----------------
__global__ void __launch_bounds__(128) k_final(const int* __restrict__ uidx,
                                               const int* __restrict__ iidx,
                                               const float* __restrict__ utab,
                                               const float* __restrict__ itab,
                                               const float* __restrict__ aw1,
                                               const float* __restrict__ ab1,
                                               const float* __restrict__ aw2,
                                               const float* __restrict__ ab2,
                                               const float* __restrict__ pw1,
                                               const float* __restrict__ pb1,
                                               const float* __restrict__ pw2,
                                               const float* __restrict__ pb2,
                                               const float* __restrict__ tstack,
                                               float* __restrict__ outp) {
    __shared__ float s[2 * DD];
    __shared__ float ah[DD];
    __shared__ float attn[T_STEPS];
    __shared__ float summed[2 * DD];
    __shared__ float red[2];
    int b = blockIdx.x, tid = threadIdx.x;
    int u = uidx[b], it = iidx[b];
    s[tid] = utab[(size_t)u * DD + tid];
    s[tid + DD] = itab[(size_t)it * DD + tid];
    __syncthreads();
    float acc = ab1[tid];
    for (int k = 0; k < 2 * DD; ++k) acc += s[k] * aw1[k * DD + tid];
    ah[tid] = fmaxf(acc, 0.f);
    __syncthreads();
    if (tid < T_STEPS) {
        float lg = ab2[tid];
        for (int k = 0; k < DD; ++k) lg += ah[k] * aw2[k * T_STEPS + tid];
        attn[tid] = lg;
    }
    __syncthreads();
    if (tid == 0) {
        float m = fmaxf(attn[0], fmaxf(attn[1], attn[2]));
        float e0 = expf(attn[0] - m), e1 = expf(attn[1] - m), e2 = expf(attn[2] - m);
        float inv = 1.f / (e0 + e1 + e2);
        attn[0] = e0 * inv;
        attn[1] = e1 * inv;
        attn[2] = e2 * inv;
    }
    __syncthreads();
    const float* tb = &tstack[(size_t)b * T_STEPS * 2 * DD];
    for (int k = tid; k < 2 * DD; k += 128)
        summed[k] = attn[0] * tb[k] + attn[1] * tb[2 * DD + k] + attn[2] * tb[4 * DD + k];
    __syncthreads();
    float ph = pb1[tid];
    for (int k = 0; k < 2 * DD; ++k) ph += summed[k] * pw1[k * DD + tid];
    ph = fmaxf(ph, 0.f);
    float contrib = ph * pw2[tid];
    for (int off = 32; off > 0; off >>= 1) contrib += __shfl_down(contrib, off, 64);
    if ((tid & 63) == 0) red[tid >> 6] = contrib;
    __syncthreads();
    if (tid == 0) outp[b] = red[0] + red[1] + pb2[0];
}

extern "C" void kernel_launch(void* const* d_in, const int* in_sizes, int n_in,
                              void* d_out, int out_size, void* d_ws, size_t ws_size,
                              hipStream_t stream) {
    const int* uidx = (const int*)d_in[0];
    const int* iidx = (const int*)d_in[1];
    const int* eidx = (const int*)d_in[2];
    const float* adj = (const float*)d_in[3];
    const float* utab = (const float*)d_in[4];
    const float* itab = (const float*)d_in[5];
    const float* temb = (const float*)d_in[6];
    const float* gw = (const float*)d_in[7];
    const float* gb = (const float*)d_in[8];
    const float* aw1 = (const float*)d_in[9];
    const float* ab1 = (const float*)d_in[10];
    const float* aw2 = (const float*)d_in[11];
    const float* ab2 = (const float*)d_in[12];
    const float* pw1 = (const float*)d_in[13];
    const float* pb1 = (const float*)d_in[14];
    const float* pw2 = (const float*)d_in[15];
    const float* pb2 = (const float*)d_in[16];

    char* ws = (char*)d_ws;
    size_t off = 0;
    auto alloc = [&](size_t bytes) {
        void* p = ws + off;
        off += (bytes + 255) & ~(size_t)255;
        return p;
    };
    int* hist = (int*)alloc((size_t)NBLK_BIN * NCOARSE * 4);
    int* exact_base = (int*)alloc((NCOARSE + 1) * 4);
    int* row_ptr = (int*)alloc((size_t)(N_NODES + 1) * 4);
    int2* sorted = (int2*)alloc((size_t)E_CNT * 8);
    float* rvec = (float*)alloc((size_t)N_NODES * 4);
    float* uvec = (float*)alloc((size_t)T_STEPS * DD * 4);
    // union: binned (consumed by k_sort) then Sb (written by k_gemm0 afterwards)
    void* un = alloc((size_t)E_CNT * 8);
    int2* binned = (int2*)un;
    unsigned short* Sb = (unsigned short*)un;
    unsigned short* Pb = (unsigned short*)alloc((size_t)N_NODES * DD * 2);
    float* agg = (float*)alloc((size_t)2 * B_SZ * T_STEPS * DD * 4);
    float* tstack = (float*)alloc((size_t)B_SZ * T_STEPS * 2 * DD * 4);

    k_bin_count<<<NBLK_BIN, 256, 0, stream>>>(eidx, hist);
    k_scan_a<<<1, 512, 0, stream>>>(hist, exact_base, row_ptr);
    k_scan_b<<<NCOARSE, NBLK_BIN, 0, stream>>>(hist, exact_base);
    k_bin_scatter<<<NBLK_BIN, 256, 0, stream>>>(eidx, eidx + E_CNT, adj, hist, binned);
    k_sort<<<NCOARSE, 256, 0, stream>>>(exact_base, binned, sorted, row_ptr);
    // S = x @ W0 (bf16 store) — overwrites binned, which is dead after k_sort
    k_gemm0<<<2048, 256, 0, stream>>>(utab, itab, gw, Sb);
    k_uvec<<<1, DD, 0, stream>>>(temb, gw, uvec);
    // P = A @ S (bf16), r = A @ 1
    k_spmm_full<<<(N_NODES + 3) / 4, 256, 0, stream>>>(row_ptr, (const long long*)sorted,
                                                       Sb, Pb, rvec);
    // agg[slot][t] = A_restricted @ relu(P + r*u_t + b0), all t fused
    k_spmm_out3<<<(2 * B_SZ * 64) / 256, 256, 0, stream>>>(
        row_ptr, (const long long*)sorted, Pb, rvec, uidx, iidx, uvec, gb, agg);
    // tstack = relu(agg @ W1 + b1)
    k_head<<<512, 256, 0, stream>>>(agg, gw + DD * DD, gb + DD, tstack);
    k_final<<<B_SZ, 128, 0, stream>>>(uidx, iidx, utab, itab, aw1, ab1, aw2, ab2, pw1,
                                      pb1, pw2, pb2, tstack, (float*)d_out);
}

// Round 6
// 426.917 us; speedup vs baseline: 3.2769x; 1.0270x over previous
//
#include <hip/hip_runtime.h>

#define U_CNT 50000
#define I_CNT 50000
#define N_NODES 100000
#define DD 128
#define T_STEPS 3
#define E_CNT 3200000
#define B_SZ 4096

#define NCOARSE 391   // ceil(100000 / 256): coarse bucket = dst >> 8
#define NBLK_BIN 256  // binning blocks; each owns a contiguous edge slice
#define CHUNK ((E_CNT + NBLK_BIN - 1) / NBLK_BIN)
#define SORT_CAP 10240
#define S_SCALE 256.0f
#define S_INV (1.0f / 256.0f)

typedef float v2f __attribute__((ext_vector_type(2)));

__device__ __forceinline__ float bf2f(unsigned short u) {
    return __uint_as_float(((unsigned int)u) << 16);
}
__device__ __forceinline__ unsigned short f2bf(float f) {
    unsigned int x = __float_as_uint(f);
    x += 0x7FFF + ((x >> 16) & 1);
    return (unsigned short)(x >> 16);
}

// ---------------- pass 1: per-block coarse histogram (non-atomic global write) ----------------
__global__ void __launch_bounds__(256) k_bin_count(const int* __restrict__ dst,
                                                   int* __restrict__ hist) {
    __shared__ int c[NCOARSE];
    int blk = blockIdx.x, tid = threadIdx.x;
    for (int j = tid; j < NCOARSE; j += 256) c[j] = 0;
    __syncthreads();
    int s0 = blk * CHUNK, s1 = min(E_CNT, s0 + CHUNK);
    for (int i = s0 + tid; i < s1; i += 256)
        atomicAdd(&c[__builtin_nontemporal_load(&dst[i]) >> 8], 1);
    __syncthreads();
    for (int j = tid; j < NCOARSE; j += 256) hist[blk * NCOARSE + j] = c[j];
}

// ---------------- pass 2a: bucket totals + exclusive bucket bases ----------------
__global__ void __launch_bounds__(512) k_scan_a(const int* __restrict__ hist,
                                                int* __restrict__ exact_base,
                                                int* __restrict__ row_ptr) {
    __shared__ int tot[NCOARSE];
    int tid = threadIdx.x;
    for (int b = tid; b < NCOARSE; b += 512) {
        int s = 0;
        for (int blk = 0; blk < NBLK_BIN; ++blk) s += hist[blk * NCOARSE + b];
        tot[b] = s;
    }
    __syncthreads();
    if (tid == 0) {
        int run = 0;
        for (int b = 0; b < NCOARSE; ++b) {
            exact_base[b] = run;
            run += tot[b];
        }
        exact_base[NCOARSE] = run;
        row_ptr[N_NODES] = run;  // == E_CNT
    }
}

// ---------------- pass 2b: per-bucket scan over blocks -> exclusive (block,bucket) bases ----------------
__global__ void __launch_bounds__(NBLK_BIN) k_scan_b(int* __restrict__ hist,
                                                     const int* __restrict__ exact_base) {
    __shared__ int lds[NBLK_BIN];
    int b = blockIdx.x, tid = threadIdx.x;
    int v = hist[tid * NCOARSE + b];
    lds[tid] = v;
    __syncthreads();
    for (int off = 1; off < NBLK_BIN; off <<= 1) {
        int add = (tid >= off) ? lds[tid - off] : 0;
        __syncthreads();
        lds[tid] += add;
        __syncthreads();
    }
    hist[tid * NCOARSE + b] = exact_base[b] + lds[tid] - v;  // exclusive prefix
}

// ---------------- pass 3: deterministic scatter into exclusive regions ----------------
__global__ void __launch_bounds__(256) k_bin_scatter(const int* __restrict__ dst,
                                                     const int* __restrict__ src,
                                                     const float* __restrict__ val,
                                                     const int* __restrict__ blkbase,
                                                     int2* __restrict__ binned) {
    __shared__ int cur[NCOARSE];
    int blk = blockIdx.x, tid = threadIdx.x;
    for (int b = tid; b < NCOARSE; b += 256) cur[b] = blkbase[blk * NCOARSE + b];
    __syncthreads();
    int s0 = blk * CHUNK, s1 = min(E_CNT, s0 + CHUNK);
    for (int i = s0 + tid; i < s1; i += 256) {
        int d = __builtin_nontemporal_load(&dst[i]);
        int s = __builtin_nontemporal_load(&src[i]);
        float w = __builtin_nontemporal_load(&val[i]);
        int b = d >> 8;
        int pos = atomicAdd(&cur[b], 1);
        binned[pos] = make_int2(s | ((d & 255) << 20), __float_as_int(w));
    }
}

// ---------------- per-bucket exact sort: emit dst-sorted pack + row_ptr ----------------
__global__ void __launch_bounds__(256) k_sort(const int* __restrict__ exact_base,
                                              const int2* __restrict__ binned,
                                              int2* __restrict__ outp,
                                              int* __restrict__ row_ptr) {
    __shared__ int hist[256], scn[256], cur[256];
    __shared__ unsigned short perm[SORT_CAP];
    int b = blockIdx.x, tid = threadIdx.x;
    int ebase = exact_base[b];
    int cnt = exact_base[b + 1] - ebase;
    if (cnt > SORT_CAP) cnt = SORT_CAP;  // safety clamp (never hit for this input)
    const int2* rbase = binned + ebase;
    int n0 = b << 8;
    hist[tid] = 0;
    __syncthreads();
    for (int i = tid; i < cnt; i += 256) atomicAdd(&hist[(rbase[i].x >> 20) & 255], 1);
    __syncthreads();
    scn[tid] = hist[tid];
    __syncthreads();
    for (int off = 1; off < 256; off <<= 1) {
        int v = (tid >= off) ? scn[tid - off] : 0;
        __syncthreads();
        scn[tid] += v;
        __syncthreads();
    }
    int excl = scn[tid] - hist[tid];
    cur[tid] = excl;
    if (n0 + tid < N_NODES) row_ptr[n0 + tid] = ebase + excl;
    __syncthreads();
    for (int i = tid; i < cnt; i += 256) {
        int dloc = (rbase[i].x >> 20) & 255;
        int pos = atomicAdd(&cur[dloc], 1);
        perm[pos] = (unsigned short)i;
    }
    __syncthreads();
    for (int i = tid; i < cnt; i += 256) {
        int2 p = rbase[perm[i]];
        p.x &= 0xFFFFF;
        outp[ebase + i] = p;
    }
}

// u_t = temporal_emb[t] @ W0  (tiny)
__global__ void k_uvec(const float* __restrict__ temb, const float* __restrict__ w0,
                       float* __restrict__ u) {
    int k = threadIdx.x;
    for (int t = 0; t < T_STEPS; ++t) {
        float acc = 0.f;
        for (int j = 0; j < DD; ++j) acc += temb[t * DD + j] * w0[j * DD + k];
        u[t * DD + k] = acc;
    }
}

// ---------------- GEMM: S = x @ W0 (fp32 compute, fp8 e4m3 store, scale 256) ----------------
__global__ void __launch_bounds__(256) k_gemm0(const float* __restrict__ utab,
                                               const float* __restrict__ itab,
                                               const float* __restrict__ W,
                                               unsigned char* __restrict__ outf8) {
    __shared__ float wlds[DD * DD];
    __shared__ float hlds[4][4][DD];
    int tid = threadIdx.x;
    for (int i = tid; i < DD * DD / 4; i += 256)
        reinterpret_cast<float4*>(wlds)[i] = reinterpret_cast<const float4*>(W)[i];
    __syncthreads();
    int wave = tid >> 6, lane = tid & 63;
    const int ntiles = (N_NODES + 15) / 16;
    for (int tile = blockIdx.x; tile < ntiles; tile += gridDim.x) {
        int rbase = tile * 16 + wave * 4;
        for (int j = 0; j < 4; ++j) {
            int row = rbase + j;
            float h0 = 0.f, h1 = 0.f;
            if (row < N_NODES) {
                const float* x = (row < U_CNT) ? &utab[(size_t)row * DD]
                                               : &itab[(size_t)(row - U_CNT) * DD];
                h0 = x[lane];
                h1 = x[lane + 64];
            }
            hlds[wave][j][lane] = h0;
            hlds[wave][j][lane + 64] = h1;
        }
        float2 acc0 = {0.f, 0.f}, acc1 = {0.f, 0.f}, acc2 = {0.f, 0.f}, acc3 = {0.f, 0.f};
        #pragma unroll 8
        for (int k = 0; k < DD; ++k) {
            float2 w2 = *reinterpret_cast<float2*>(&wlds[k * DD + 2 * lane]);
            float hA = hlds[wave][0][k];
            float hB = hlds[wave][1][k];
            float hC = hlds[wave][2][k];
            float hD = hlds[wave][3][k];
            acc0.x += hA * w2.x; acc0.y += hA * w2.y;
            acc1.x += hB * w2.x; acc1.y += hB * w2.y;
            acc2.x += hC * w2.x; acc2.y += hC * w2.y;
            acc3.x += hD * w2.x; acc3.y += hD * w2.y;
        }
        float2 accs[4] = {acc0, acc1, acc2, acc3};
        for (int j = 0; j < 4; ++j) {
            int row = rbase + j;
            if (row < N_NODES) {
                unsigned int pk = __builtin_amdgcn_cvt_pk_fp8_f32(
                    accs[j].x * S_SCALE, accs[j].y * S_SCALE, 0, false);
                *reinterpret_cast<unsigned short*>(&outf8[(size_t)row * DD + 2 * lane]) =
                    (unsigned short)(pk & 0xFFFF);
            }
        }
    }
}

// ---------------- full SpMM: P = A*S (fp8 in, bf16 out), r = A*1 ----------------
// one wave per dst row; 4 edges/iter, 16 lanes x 8B (int2 = 8 fp8 cols) per edge
__global__ void __launch_bounds__(256) k_spmm_full(const int* __restrict__ row_ptr,
                                                   const long long* __restrict__ packll,
                                                   const unsigned char* __restrict__ Sf,
                                                   unsigned short* __restrict__ Pb,
                                                   float* __restrict__ rvec) {
    int wave = (int)((blockIdx.x * blockDim.x + threadIdx.x) >> 6);
    int lane = threadIdx.x & 63;
    if (wave >= N_NODES) return;
    int beg = row_ptr[wave], end = row_ptr[wave + 1];
    int q = lane >> 4;    // which of 4 edges this lane serves
    int cg = lane & 15;   // 16 lanes x 8 cols = 128 cols
    float acc[8] = {0.f, 0.f, 0.f, 0.f, 0.f, 0.f, 0.f, 0.f};
    float vs = 0.f;
    for (int e = beg; e < end; e += 4) {
        int ee = e + q;
        long long pl = 0;
        if (ee < end) pl = __builtin_nontemporal_load(&packll[ee]);
        int sx = (int)(unsigned int)(pl & 0xFFFFFFFFLL);
        float v = __int_as_float((int)(pl >> 32));
        const int2 s2 = *reinterpret_cast<const int2*>(&Sf[((size_t)sx << 7) + (cg << 3)]);
        v2f p01 = __builtin_amdgcn_cvt_pk_f32_fp8(s2.x, false);
        v2f p23 = __builtin_amdgcn_cvt_pk_f32_fp8(s2.x, true);
        v2f p45 = __builtin_amdgcn_cvt_pk_f32_fp8(s2.y, false);
        v2f p67 = __builtin_amdgcn_cvt_pk_f32_fp8(s2.y, true);
        acc[0] += v * p01.x;
        acc[1] += v * p01.y;
        acc[2] += v * p23.x;
        acc[3] += v * p23.y;
        acc[4] += v * p45.x;
        acc[5] += v * p45.y;
        acc[6] += v * p67.x;
        acc[7] += v * p67.y;
        if (cg == 0) vs += v;
    }
    #pragma unroll
    for (int j = 0; j < 8; ++j) {
        acc[j] += __shfl_down(acc[j], 32, 64);
        acc[j] += __shfl_down(acc[j], 16, 64);
        acc[j] *= S_INV;
    }
    vs += __shfl_down(vs, 32, 64);
    vs += __shfl_down(vs, 16, 64);
    if (lane < 16) {
        unsigned w0 = ((unsigned)f2bf(acc[1]) << 16) | f2bf(acc[0]);
        unsigned w1 = ((unsigned)f2bf(acc[3]) << 16) | f2bf(acc[2]);
        unsigned w2 = ((unsigned)f2bf(acc[5]) << 16) | f2bf(acc[4]);
        unsigned w3 = ((unsigned)f2bf(acc[7]) << 16) | f2bf(acc[6]);
        int4 o = make_int4(w0, w1, w2, w3);
        *reinterpret_cast<int4*>(&Pb[((size_t)wave << 7) + (lane << 3)]) = o;
        if (lane == 0) rvec[wave] = vs;
    }
}

// ---------------- restricted SpMM, all 3 t's fused ----------------
__global__ void __launch_bounds__(256) k_spmm_out3(const int* __restrict__ row_ptr,
                                                   const long long* __restrict__ packll,
                                                   const unsigned short* __restrict__ Pb,
                                                   const float* __restrict__ rvec,
                                                   const int* __restrict__ uidx,
                                                   const int* __restrict__ iidx,
                                                   const float* __restrict__ uvec,
                                                   const float* __restrict__ b0,
                                                   float* __restrict__ agg) {
    int slot = (int)((blockIdx.x * blockDim.x + threadIdx.x) >> 6);
    int lane = threadIdx.x & 63;
    if (slot >= 2 * B_SZ) return;
    int b = slot & (B_SZ - 1), side = slot >> 12;
    int row = side ? (U_CNT + iidx[b]) : uidx[b];
    int beg = row_ptr[row], end = row_ptr[row + 1];
    int half = lane >> 5, cg = lane & 31;
    float u0[4], u1[4], u2[4], bb[4];
    #pragma unroll
    for (int j = 0; j < 4; ++j) {
        int c = cg * 4 + j;
        u0[j] = uvec[c];
        u1[j] = uvec[DD + c];
        u2[j] = uvec[2 * DD + c];
        bb[j] = b0[c];
    }
    float a0[4] = {0, 0, 0, 0}, a1[4] = {0, 0, 0, 0}, a2[4] = {0, 0, 0, 0};
    for (int e = beg; e < end; e += 2) {
        int ee = e + half;
        long long pl = 0;
        if (ee < end) pl = __builtin_nontemporal_load(&packll[ee]);
        int sx = (int)(unsigned int)(pl & 0xFFFFFFFFLL);
        float v = __int_as_float((int)(pl >> 32));
        float rr = rvec[sx];
        ushort4 s4 = *reinterpret_cast<const ushort4*>(&Pb[(size_t)sx * DD + cg * 4]);
        float pc[4] = {bf2f(s4.x), bf2f(s4.y), bf2f(s4.z), bf2f(s4.w)};
        #pragma unroll
        for (int j = 0; j < 4; ++j) {
            float base = pc[j] + bb[j];
            a0[j] += v * fmaxf(base + rr * u0[j], 0.f);
            a1[j] += v * fmaxf(base + rr * u1[j], 0.f);
            a2[j] += v * fmaxf(base + rr * u2[j], 0.f);
        }
    }
    #pragma unroll
    for (int j = 0; j < 4; ++j) {
        a0[j] += __shfl_down(a0[j], 32, 64);
        a1[j] += __shfl_down(a1[j], 32, 64);
        a2[j] += __shfl_down(a2[j], 32, 64);
    }
    if (lane < 32) {
        size_t rb = (size_t)slot * 3;
        float4 o0 = {a0[0], a0[1], a0[2], a0[3]};
        float4 o1 = {a1[0], a1[1], a1[2], a1[3]};
        float4 o2 = {a2[0], a2[1], a2[2], a2[3]};
        *reinterpret_cast<float4*>(&agg[(rb + 0) * DD + lane * 4]) = o0;
        *reinterpret_cast<float4*>(&agg[(rb + 1) * DD + lane * 4]) = o1;
        *reinterpret_cast<float4*>(&agg[(rb + 2) * DD + lane * 4]) = o2;
    }
}

// ---------------- head GEMM: tstack = relu(agg @ W1 + b1) ----------------
__global__ void __launch_bounds__(256) k_head(const float* __restrict__ agg,
                                              const float* __restrict__ W,
                                              const float* __restrict__ b1,
                                              float* __restrict__ tstack) {
    __shared__ float wlds[DD * DD];
    __shared__ float blds[DD];
    __shared__ float hlds[4][4][DD];
    int tid = threadIdx.x;
    for (int i = tid; i < DD * DD / 4; i += 256)
        reinterpret_cast<float4*>(wlds)[i] = reinterpret_cast<const float4*>(W)[i];
    if (tid < DD) blds[tid] = b1[tid];
    __syncthreads();
    int wave = tid >> 6, lane = tid & 63;
    const int NR = 2 * B_SZ * T_STEPS;
    const int ntiles = NR / 16;
    for (int tile = blockIdx.x; tile < ntiles; tile += gridDim.x) {
        int rbase = tile * 16 + wave * 4;
        for (int j = 0; j < 4; ++j) {
            int row = rbase + j;
            hlds[wave][j][lane] = agg[(size_t)row * DD + lane];
            hlds[wave][j][lane + 64] = agg[(size_t)row * DD + lane + 64];
        }
        float2 acc0 = {0.f, 0.f}, acc1 = {0.f, 0.f}, acc2 = {0.f, 0.f}, acc3 = {0.f, 0.f};
        #pragma unroll 8
        for (int k = 0; k < DD; ++k) {
            float2 w2 = *reinterpret_cast<float2*>(&wlds[k * DD + 2 * lane]);
            float hA = hlds[wave][0][k];
            float hB = hlds[wave][1][k];
            float hC = hlds[wave][2][k];
            float hD = hlds[wave][3][k];
            acc0.x += hA * w2.x; acc0.y += hA * w2.y;
            acc1.x += hB * w2.x; acc1.y += hB * w2.y;
            acc2.x += hC * w2.x; acc2.y += hC * w2.y;
            acc3.x += hD * w2.x; acc3.y += hD * w2.y;
        }
        float2 accs[4] = {acc0, acc1, acc2, acc3};
        for (int j = 0; j < 4; ++j) {
            int row = rbase + j;
            int slot = row / 3, t = row - slot * 3;
            int b = slot & (B_SZ - 1), side = slot >> 12;
            float2 o;
            o.x = fmaxf(accs[j].x + blds[2 * lane], 0.f);
            o.y = fmaxf(accs[j].y + blds[2 * lane + 1], 0.f);
            *reinterpret_cast<float2*>(
                &tstack[((size_t)b * T_STEPS + t) * 2 * DD + side * DD + 2 * lane]) = o;
        }
    }
}

// ---------------- attention + prediction head ----------------
__global__ void __launch_bounds__(128) k_final(const int* __restrict__ uidx,
                                               const int* __restrict__ iidx,
                                               const float* __restrict__ utab,
                                               const float* __restrict__ itab,
                                               const float* __restrict__ aw1,
                                               const float* __restrict__ ab1,
                                               const float* __restrict__ aw2,
                                               const float* __restrict__ ab2,
                                               const float* __restrict__ pw1,
                                               const float* __restrict__ pb1,
                                               const float* __restrict__ pw2,
                                               const float* __restrict__ pb2,
                                               const float* __restrict__ tstack,
                                               float* __restrict__ outp) {
    __shared__ float s[2 * DD];
    __shared__ float ah[DD];
    __shared__ float attn[T_STEPS];
    __shared__ float summed[2 * DD];
    __shared__ float red[2];
    int b = blockIdx.x, tid = threadIdx.x;
    int u = uidx[b], it = iidx[b];
    s[tid] = utab[(size_t)u * DD + tid];
    s[tid + DD] = itab[(size_t)it * DD + tid];
    __syncthreads();
    float acc = ab1[tid];
    for (int k = 0; k < 2 * DD; ++k) acc += s[k] * aw1[k * DD + tid];
    ah[tid] = fmaxf(acc, 0.f);
    __syncthreads();
    if (tid < T_STEPS) {
        float lg = ab2[tid];
        for (int k = 0; k < DD; ++k) lg += ah[k] * aw2[k * T_STEPS + tid];
        attn[tid] = lg;
    }
    __syncthreads();
    if (tid == 0) {
        float m = fmaxf(attn[0], fmaxf(attn[1], attn[2]));
        float e0 = expf(attn[0] - m), e1 = expf(attn[1] - m), e2 = expf(attn[2] - m);
        float inv = 1.f / (e0 + e1 + e2);
        attn[0] = e0 * inv;
        attn[1] = e1 * inv;
        attn[2] = e2 * inv;
    }
    __syncthreads();
    const float* tb = &tstack[(size_t)b * T_STEPS * 2 * DD];
    for (int k = tid; k < 2 * DD; k += 128)
        summed[k] = attn[0] * tb[k] + attn[1] * tb[2 * DD + k] + attn[2] * tb[4 * DD + k];
    __syncthreads();
    float ph = pb1[tid];
    for (int k = 0; k < 2 * DD; ++k) ph += summed[k] * pw1[k * DD + tid];
    ph = fmaxf(ph, 0.f);
    float contrib = ph * pw2[tid];
    for (int off = 32; off > 0; off >>= 1) contrib += __shfl_down(contrib, off, 64);
    if ((tid & 63) == 0) red[tid >> 6] = contrib;
    __syncthreads();
    if (tid == 0) outp[b] = red[0] + red[1] + pb2[0];
}

extern "C" void kernel_launch(void* const* d_in, const int* in_sizes, int n_in,
                              void* d_out, int out_size, void* d_ws, size_t ws_size,
                              hipStream_t stream) {
    const int* uidx = (const int*)d_in[0];
    const int* iidx = (const int*)d_in[1];
    const int* eidx = (const int*)d_in[2];
    const float* adj = (const float*)d_in[3];
    const float* utab = (const float*)d_in[4];
    const float* itab = (const float*)d_in[5];
    const float* temb = (const float*)d_in[6];
    const float* gw = (const float*)d_in[7];
    const float* gb = (const float*)d_in[8];
    const float* aw1 = (const float*)d_in[9];
    const float* ab1 = (const float*)d_in[10];
    const float* aw2 = (const float*)d_in[11];
    const float* ab2 = (const float*)d_in[12];
    const float* pw1 = (const float*)d_in[13];
    const float* pb1 = (const float*)d_in[14];
    const float* pw2 = (const float*)d_in[15];
    const float* pb2 = (const float*)d_in[16];

    char* ws = (char*)d_ws;
    size_t off = 0;
    auto alloc = [&](size_t bytes) {
        void* p = ws + off;
        off += (bytes + 255) & ~(size_t)255;
        return p;
    };
    int* hist = (int*)alloc((size_t)NBLK_BIN * NCOARSE * 4);
    int* exact_base = (int*)alloc((NCOARSE + 1) * 4);
    int* row_ptr = (int*)alloc((size_t)(N_NODES + 1) * 4);
    int2* sorted = (int2*)alloc((size_t)E_CNT * 8);
    float* rvec = (float*)alloc((size_t)N_NODES * 4);
    float* uvec = (float*)alloc((size_t)T_STEPS * DD * 4);
    // union: binned (consumed by k_sort) then Sf (written by k_gemm0 afterwards)
    void* un = alloc((size_t)E_CNT * 8);
    int2* binned = (int2*)un;
    unsigned char* Sf = (unsigned char*)un;
    unsigned short* Pb = (unsigned short*)alloc((size_t)N_NODES * DD * 2);
    float* agg = (float*)alloc((size_t)2 * B_SZ * T_STEPS * DD * 4);
    float* tstack = (float*)alloc((size_t)B_SZ * T_STEPS * 2 * DD * 4);

    k_bin_count<<<NBLK_BIN, 256, 0, stream>>>(eidx, hist);
    k_scan_a<<<1, 512, 0, stream>>>(hist, exact_base, row_ptr);
    k_scan_b<<<NCOARSE, NBLK_BIN, 0, stream>>>(hist, exact_base);
    k_bin_scatter<<<NBLK_BIN, 256, 0, stream>>>(eidx, eidx + E_CNT, adj, hist, binned);
    k_sort<<<NCOARSE, 256, 0, stream>>>(exact_base, binned, sorted, row_ptr);
    // S = x @ W0 (fp8 store, x256) — overwrites binned, which is dead after k_sort
    k_gemm0<<<2048, 256, 0, stream>>>(utab, itab, gw, Sf);
    k_uvec<<<1, DD, 0, stream>>>(temb, gw, uvec);
    // P = A @ S (fp8 -> bf16), r = A @ 1
    k_spmm_full<<<(N_NODES + 3) / 4, 256, 0, stream>>>(row_ptr, (const long long*)sorted,
                                                       Sf, Pb, rvec);
    // agg[slot][t] = A_restricted @ relu(P + r*u_t + b0), all t fused
    k_spmm_out3<<<(2 * B_SZ * 64) / 256, 256, 0, stream>>>(
        row_ptr, (const long long*)sorted, Pb, rvec, uidx, iidx, uvec, gb, agg);
    // tstack = relu(agg @ W1 + b1)
    k_head<<<512, 256, 0, stream>>>(agg, gw + DD * DD, gb + DD, tstack);
    k_final<<<B_SZ, 128, 0, stream>>>(uidx, iidx, utab, itab, aw1, ab1, aw2, ab2, pw1,
                                      pb1, pw2, pb2, tstack, (float*)d_out);
}

// Round 7
// 384.615 us; speedup vs baseline: 3.6373x; 1.1100x over previous
//
#include <hip/hip_runtime.h>

#define U_CNT 50000
#define I_CNT 50000
#define N_NODES 100000
#define DD 128
#define T_STEPS 3
#define E_CNT 3200000
#define B_SZ 4096

#define NCOARSE 391   // ceil(100000 / 256): coarse bucket = dst >> 8
#define NBLK_BIN 256  // binning blocks; each owns a contiguous edge slice
#define CHUNK ((E_CNT + NBLK_BIN - 1) / NBLK_BIN)
#define SORT_CAP 10240
#define S_SCALE 256.0f
#define S_INV (1.0f / 256.0f)

typedef float v2f __attribute__((ext_vector_type(2)));

__device__ __forceinline__ float bf2f(unsigned short u) {
    return __uint_as_float(((unsigned int)u) << 16);
}
__device__ __forceinline__ unsigned short f2bf(float f) {
    unsigned int x = __float_as_uint(f);
    x += 0x7FFF + ((x >> 16) & 1);
    return (unsigned short)(x >> 16);
}

// ---------------- pass 1: per-block coarse histogram (non-atomic global write) ----------------
__global__ void __launch_bounds__(256) k_bin_count(const int* __restrict__ dst,
                                                   int* __restrict__ hist) {
    __shared__ int c[NCOARSE];
    int blk = blockIdx.x, tid = threadIdx.x;
    for (int j = tid; j < NCOARSE; j += 256) c[j] = 0;
    __syncthreads();
    int s0 = blk * CHUNK, s1 = min(E_CNT, s0 + CHUNK);
    for (int i = s0 + tid; i < s1; i += 256)
        atomicAdd(&c[__builtin_nontemporal_load(&dst[i]) >> 8], 1);
    __syncthreads();
    for (int j = tid; j < NCOARSE; j += 256) hist[blk * NCOARSE + j] = c[j];
}

// ---------------- pass 2a: bucket totals + exclusive bucket bases ----------------
__global__ void __launch_bounds__(512) k_scan_a(const int* __restrict__ hist,
                                                int* __restrict__ exact_base,
                                                int* __restrict__ row_ptr) {
    __shared__ int tot[NCOARSE];
    int tid = threadIdx.x;
    for (int b = tid; b < NCOARSE; b += 512) {
        int s = 0;
        for (int blk = 0; blk < NBLK_BIN; ++blk) s += hist[blk * NCOARSE + b];
        tot[b] = s;
    }
    __syncthreads();
    if (tid == 0) {
        int run = 0;
        for (int b = 0; b < NCOARSE; ++b) {
            exact_base[b] = run;
            run += tot[b];
        }
        exact_base[NCOARSE] = run;
        row_ptr[N_NODES] = run;  // == E_CNT
    }
}

// ---------------- pass 2b: per-bucket scan over blocks -> exclusive (block,bucket) bases ----------------
__global__ void __launch_bounds__(NBLK_BIN) k_scan_b(int* __restrict__ hist,
                                                     const int* __restrict__ exact_base) {
    __shared__ int lds[NBLK_BIN];
    int b = blockIdx.x, tid = threadIdx.x;
    int v = hist[tid * NCOARSE + b];
    lds[tid] = v;
    __syncthreads();
    for (int off = 1; off < NBLK_BIN; off <<= 1) {
        int add = (tid >= off) ? lds[tid - off] : 0;
        __syncthreads();
        lds[tid] += add;
        __syncthreads();
    }
    hist[tid * NCOARSE + b] = exact_base[b] + lds[tid] - v;  // exclusive prefix
}

// ---------------- pass 3: deterministic scatter into exclusive regions ----------------
__global__ void __launch_bounds__(256) k_bin_scatter(const int* __restrict__ dst,
                                                     const int* __restrict__ src,
                                                     const float* __restrict__ val,
                                                     const int* __restrict__ blkbase,
                                                     int2* __restrict__ binned) {
    __shared__ int cur[NCOARSE];
    int blk = blockIdx.x, tid = threadIdx.x;
    for (int b = tid; b < NCOARSE; b += 256) cur[b] = blkbase[blk * NCOARSE + b];
    __syncthreads();
    int s0 = blk * CHUNK, s1 = min(E_CNT, s0 + CHUNK);
    for (int i = s0 + tid; i < s1; i += 256) {
        int d = __builtin_nontemporal_load(&dst[i]);
        int s = __builtin_nontemporal_load(&src[i]);
        float w = __builtin_nontemporal_load(&val[i]);
        int b = d >> 8;
        int pos = atomicAdd(&cur[b], 1);
        binned[pos] = make_int2(s | ((d & 255) << 20), __float_as_int(w));
    }
}

// ---------------- per-bucket exact sort: emit dst-sorted pack + row_ptr ----------------
__global__ void __launch_bounds__(256) k_sort(const int* __restrict__ exact_base,
                                              const int2* __restrict__ binned,
                                              int2* __restrict__ outp,
                                              int* __restrict__ row_ptr) {
    __shared__ int hist[256], scn[256], cur[256];
    __shared__ unsigned short perm[SORT_CAP];
    int b = blockIdx.x, tid = threadIdx.x;
    int ebase = exact_base[b];
    int cnt = exact_base[b + 1] - ebase;
    if (cnt > SORT_CAP) cnt = SORT_CAP;  // safety clamp (never hit for this input)
    const int2* rbase = binned + ebase;
    int n0 = b << 8;
    hist[tid] = 0;
    __syncthreads();
    for (int i = tid; i < cnt; i += 256) atomicAdd(&hist[(rbase[i].x >> 20) & 255], 1);
    __syncthreads();
    scn[tid] = hist[tid];
    __syncthreads();
    for (int off = 1; off < 256; off <<= 1) {
        int v = (tid >= off) ? scn[tid - off] : 0;
        __syncthreads();
        scn[tid] += v;
        __syncthreads();
    }
    int excl = scn[tid] - hist[tid];
    cur[tid] = excl;
    if (n0 + tid < N_NODES) row_ptr[n0 + tid] = ebase + excl;
    __syncthreads();
    for (int i = tid; i < cnt; i += 256) {
        int dloc = (rbase[i].x >> 20) & 255;
        int pos = atomicAdd(&cur[dloc], 1);
        perm[pos] = (unsigned short)i;
    }
    __syncthreads();
    for (int i = tid; i < cnt; i += 256) {
        int2 p = rbase[perm[i]];
        p.x &= 0xFFFFF;
        outp[ebase + i] = p;
    }
}

// u_t = temporal_emb[t] @ W0  (tiny)
__global__ void k_uvec(const float* __restrict__ temb, const float* __restrict__ w0,
                       float* __restrict__ u) {
    int k = threadIdx.x;
    for (int t = 0; t < T_STEPS; ++t) {
        float acc = 0.f;
        for (int j = 0; j < DD; ++j) acc += temb[t * DD + j] * w0[j * DD + k];
        u[t * DD + k] = acc;
    }
}

// ---------------- GEMM: S = x @ W0 (fp32 compute, fp8 e4m3 store, scale 256) ----------------
__global__ void __launch_bounds__(256) k_gemm0(const float* __restrict__ utab,
                                               const float* __restrict__ itab,
                                               const float* __restrict__ W,
                                               unsigned char* __restrict__ outf8) {
    __shared__ float wlds[DD * DD];
    __shared__ float hlds[4][4][DD];
    int tid = threadIdx.x;
    for (int i = tid; i < DD * DD / 4; i += 256)
        reinterpret_cast<float4*>(wlds)[i] = reinterpret_cast<const float4*>(W)[i];
    __syncthreads();
    int wave = tid >> 6, lane = tid & 63;
    const int ntiles = (N_NODES + 15) / 16;
    for (int tile = blockIdx.x; tile < ntiles; tile += gridDim.x) {
        int rbase = tile * 16 + wave * 4;
        for (int j = 0; j < 4; ++j) {
            int row = rbase + j;
            float h0 = 0.f, h1 = 0.f;
            if (row < N_NODES) {
                const float* x = (row < U_CNT) ? &utab[(size_t)row * DD]
                                               : &itab[(size_t)(row - U_CNT) * DD];
                h0 = x[lane];
                h1 = x[lane + 64];
            }
            hlds[wave][j][lane] = h0;
            hlds[wave][j][lane + 64] = h1;
        }
        float2 acc0 = {0.f, 0.f}, acc1 = {0.f, 0.f}, acc2 = {0.f, 0.f}, acc3 = {0.f, 0.f};
        #pragma unroll 8
        for (int k = 0; k < DD; ++k) {
            float2 w2 = *reinterpret_cast<float2*>(&wlds[k * DD + 2 * lane]);
            float hA = hlds[wave][0][k];
            float hB = hlds[wave][1][k];
            float hC = hlds[wave][2][k];
            float hD = hlds[wave][3][k];
            acc0.x += hA * w2.x; acc0.y += hA * w2.y;
            acc1.x += hB * w2.x; acc1.y += hB * w2.y;
            acc2.x += hC * w2.x; acc2.y += hC * w2.y;
            acc3.x += hD * w2.x; acc3.y += hD * w2.y;
        }
        float2 accs[4] = {acc0, acc1, acc2, acc3};
        for (int j = 0; j < 4; ++j) {
            int row = rbase + j;
            if (row < N_NODES) {
                unsigned int pk = __builtin_amdgcn_cvt_pk_fp8_f32(
                    accs[j].x * S_SCALE, accs[j].y * S_SCALE, 0, false);
                *reinterpret_cast<unsigned short*>(&outf8[(size_t)row * DD + 2 * lane]) =
                    (unsigned short)(pk & 0xFFFF);
            }
        }
    }
}

// ---------------- full SpMM: P = A*S (fp8 in, bf16 out), r = A*1 ----------------
// one wave per dst row; 8 edges/iter, 8 lanes x 16B (int4 = 16 fp8 cols) per edge,
// next-iteration pack prefetch to break the pack->gather dependence chain
__global__ void __launch_bounds__(256) k_spmm_full(const int* __restrict__ row_ptr,
                                                   const long long* __restrict__ packll,
                                                   const unsigned char* __restrict__ Sf,
                                                   unsigned short* __restrict__ Pb,
                                                   float* __restrict__ rvec) {
    int wave = (int)((blockIdx.x * blockDim.x + threadIdx.x) >> 6);
    int lane = threadIdx.x & 63;
    if (wave >= N_NODES) return;
    int beg = row_ptr[wave], end = row_ptr[wave + 1];
    int q = lane >> 3;   // which of 8 edges this lane serves
    int cg = lane & 7;   // 8 lanes x 16 cols = 128 cols
    float acc[16];
    #pragma unroll
    for (int j = 0; j < 16; ++j) acc[j] = 0.f;
    float vs = 0.f;
    int e0 = beg + q;
    long long pl = (e0 < end) ? __builtin_nontemporal_load(&packll[e0]) : 0;
    for (int e = beg; e < end; e += 8) {
        long long cur = pl;
        int en = e + 8 + q;
        pl = (en < end) ? __builtin_nontemporal_load(&packll[en]) : 0;
        int sx = (int)(unsigned int)(cur & 0xFFFFFFFFLL);
        float v = __int_as_float((int)(cur >> 32));
        const int4 s4 = *reinterpret_cast<const int4*>(&Sf[((size_t)sx << 7) + (cg << 4)]);
        v2f p01 = __builtin_amdgcn_cvt_pk_f32_fp8(s4.x, false);
        v2f p23 = __builtin_amdgcn_cvt_pk_f32_fp8(s4.x, true);
        v2f p45 = __builtin_amdgcn_cvt_pk_f32_fp8(s4.y, false);
        v2f p67 = __builtin_amdgcn_cvt_pk_f32_fp8(s4.y, true);
        v2f p89 = __builtin_amdgcn_cvt_pk_f32_fp8(s4.z, false);
        v2f pab = __builtin_amdgcn_cvt_pk_f32_fp8(s4.z, true);
        v2f pcd = __builtin_amdgcn_cvt_pk_f32_fp8(s4.w, false);
        v2f pef = __builtin_amdgcn_cvt_pk_f32_fp8(s4.w, true);
        acc[0] += v * p01.x;  acc[1] += v * p01.y;
        acc[2] += v * p23.x;  acc[3] += v * p23.y;
        acc[4] += v * p45.x;  acc[5] += v * p45.y;
        acc[6] += v * p67.x;  acc[7] += v * p67.y;
        acc[8] += v * p89.x;  acc[9] += v * p89.y;
        acc[10] += v * pab.x; acc[11] += v * pab.y;
        acc[12] += v * pcd.x; acc[13] += v * pcd.y;
        acc[14] += v * pef.x; acc[15] += v * pef.y;
        if (cg == 0) vs += v;
    }
    #pragma unroll
    for (int j = 0; j < 16; ++j) {
        acc[j] += __shfl_down(acc[j], 32, 64);
        acc[j] += __shfl_down(acc[j], 16, 64);
        acc[j] += __shfl_down(acc[j], 8, 64);
        acc[j] *= S_INV;
    }
    vs += __shfl_down(vs, 32, 64);
    vs += __shfl_down(vs, 16, 64);
    vs += __shfl_down(vs, 8, 64);
    if (lane < 8) {
        unsigned w0 = ((unsigned)f2bf(acc[1]) << 16) | f2bf(acc[0]);
        unsigned w1 = ((unsigned)f2bf(acc[3]) << 16) | f2bf(acc[2]);
        unsigned w2 = ((unsigned)f2bf(acc[5]) << 16) | f2bf(acc[4]);
        unsigned w3 = ((unsigned)f2bf(acc[7]) << 16) | f2bf(acc[6]);
        unsigned w4 = ((unsigned)f2bf(acc[9]) << 16) | f2bf(acc[8]);
        unsigned w5 = ((unsigned)f2bf(acc[11]) << 16) | f2bf(acc[10]);
        unsigned w6 = ((unsigned)f2bf(acc[13]) << 16) | f2bf(acc[12]);
        unsigned w7 = ((unsigned)f2bf(acc[15]) << 16) | f2bf(acc[14]);
        unsigned short* base = &Pb[((size_t)wave << 7) + (lane << 4)];
        *reinterpret_cast<int4*>(base) = make_int4(w0, w1, w2, w3);
        *reinterpret_cast<int4*>(base + 8) = make_int4(w4, w5, w6, w7);
        if (lane == 0) rvec[wave] = vs;
    }
}

// ---------------- restricted SpMM, all 3 t's fused ----------------
__global__ void __launch_bounds__(256) k_spmm_out3(const int* __restrict__ row_ptr,
                                                   const long long* __restrict__ packll,
                                                   const unsigned short* __restrict__ Pb,
                                                   const float* __restrict__ rvec,
                                                   const int* __restrict__ uidx,
                                                   const int* __restrict__ iidx,
                                                   const float* __restrict__ uvec,
                                                   const float* __restrict__ b0,
                                                   float* __restrict__ agg) {
    int slot = (int)((blockIdx.x * blockDim.x + threadIdx.x) >> 6);
    int lane = threadIdx.x & 63;
    if (slot >= 2 * B_SZ) return;
    int b = slot & (B_SZ - 1), side = slot >> 12;
    int row = side ? (U_CNT + iidx[b]) : uidx[b];
    int beg = row_ptr[row], end = row_ptr[row + 1];
    int half = lane >> 5, cg = lane & 31;
    float u0[4], u1[4], u2[4], bb[4];
    #pragma unroll
    for (int j = 0; j < 4; ++j) {
        int c = cg * 4 + j;
        u0[j] = uvec[c];
        u1[j] = uvec[DD + c];
        u2[j] = uvec[2 * DD + c];
        bb[j] = b0[c];
    }
    float a0[4] = {0, 0, 0, 0}, a1[4] = {0, 0, 0, 0}, a2[4] = {0, 0, 0, 0};
    for (int e = beg; e < end; e += 2) {
        int ee = e + half;
        long long pl = 0;
        if (ee < end) pl = __builtin_nontemporal_load(&packll[ee]);
        int sx = (int)(unsigned int)(pl & 0xFFFFFFFFLL);
        float v = __int_as_float((int)(pl >> 32));
        float rr = rvec[sx];
        ushort4 s4 = *reinterpret_cast<const ushort4*>(&Pb[(size_t)sx * DD + cg * 4]);
        float pc[4] = {bf2f(s4.x), bf2f(s4.y), bf2f(s4.z), bf2f(s4.w)};
        #pragma unroll
        for (int j = 0; j < 4; ++j) {
            float base = pc[j] + bb[j];
            a0[j] += v * fmaxf(base + rr * u0[j], 0.f);
            a1[j] += v * fmaxf(base + rr * u1[j], 0.f);
            a2[j] += v * fmaxf(base + rr * u2[j], 0.f);
        }
    }
    #pragma unroll
    for (int j = 0; j < 4; ++j) {
        a0[j] += __shfl_down(a0[j], 32, 64);
        a1[j] += __shfl_down(a1[j], 32, 64);
        a2[j] += __shfl_down(a2[j], 32, 64);
    }
    if (lane < 32) {
        size_t rb = (size_t)slot * 3;
        float4 o0 = {a0[0], a0[1], a0[2], a0[3]};
        float4 o1 = {a1[0], a1[1], a1[2], a1[3]};
        float4 o2 = {a2[0], a2[1], a2[2], a2[3]};
        *reinterpret_cast<float4*>(&agg[(rb + 0) * DD + lane * 4]) = o0;
        *reinterpret_cast<float4*>(&agg[(rb + 1) * DD + lane * 4]) = o1;
        *reinterpret_cast<float4*>(&agg[(rb + 2) * DD + lane * 4]) = o2;
    }
}

// ---------------- head GEMM: tstack = relu(agg @ W1 + b1) ----------------
__global__ void __launch_bounds__(256) k_head(const float* __restrict__ agg,
                                              const float* __restrict__ W,
                                              const float* __restrict__ b1,
                                              float* __restrict__ tstack) {
    __shared__ float wlds[DD * DD];
    __shared__ float blds[DD];
    __shared__ float hlds[4][4][DD];
    int tid = threadIdx.x;
    for (int i = tid; i < DD * DD / 4; i += 256)
        reinterpret_cast<float4*>(wlds)[i] = reinterpret_cast<const float4*>(W)[i];
    if (tid < DD) blds[tid] = b1[tid];
    __syncthreads();
    int wave = tid >> 6, lane = tid & 63;
    const int NR = 2 * B_SZ * T_STEPS;
    const int ntiles = NR / 16;
    for (int tile = blockIdx.x; tile < ntiles; tile += gridDim.x) {
        int rbase = tile * 16 + wave * 4;
        for (int j = 0; j < 4; ++j) {
            int row = rbase + j;
            hlds[wave][j][lane] = agg[(size_t)row * DD + lane];
            hlds[wave][j][lane + 64] = agg[(size_t)row * DD + lane + 64];
        }
        float2 acc0 = {0.f, 0.f}, acc1 = {0.f, 0.f}, acc2 = {0.f, 0.f}, acc3 = {0.f, 0.f};
        #pragma unroll 8
        for (int k = 0; k < DD; ++k) {
            float2 w2 = *reinterpret_cast<float2*>(&wlds[k * DD + 2 * lane]);
            float hA = hlds[wave][0][k];
            float hB = hlds[wave][1][k];
            float hC = hlds[wave][2][k];
            float hD = hlds[wave][3][k];
            acc0.x += hA * w2.x; acc0.y += hA * w2.y;
            acc1.x += hB * w2.x; acc1.y += hB * w2.y;
            acc2.x += hC * w2.x; acc2.y += hC * w2.y;
            acc3.x += hD * w2.x; acc3.y += hD * w2.y;
        }
        float2 accs[4] = {acc0, acc1, acc2, acc3};
        for (int j = 0; j < 4; ++j) {
            int row = rbase + j;
            int slot = row / 3, t = row - slot * 3;
            int b = slot & (B_SZ - 1), side = slot >> 12;
            float2 o;
            o.x = fmaxf(accs[j].x + blds[2 * lane], 0.f);
            o.y = fmaxf(accs[j].y + blds[2 * lane + 1], 0.f);
            *reinterpret_cast<float2*>(
                &tstack[((size_t)b * T_STEPS + t) * 2 * DD + side * DD + 2 * lane]) = o;
        }
    }
}

// ---------------- attention + prediction head ----------------
__global__ void __launch_bounds__(128) k_final(const int* __restrict__ uidx,
                                               const int* __restrict__ iidx,
                                               const float* __restrict__ utab,
                                               const float* __restrict__ itab,
                                               const float* __restrict__ aw1,
                                               const float* __restrict__ ab1,
                                               const float* __restrict__ aw2,
                                               const float* __restrict__ ab2,
                                               const float* __restrict__ pw1,
                                               const float* __restrict__ pb1,
                                               const float* __restrict__ pw2,
                                               const float* __restrict__ pb2,
                                               const float* __restrict__ tstack,
                                               float* __restrict__ outp) {
    __shared__ float s[2 * DD];
    __shared__ float ah[DD];
    __shared__ float attn[T_STEPS];
    __shared__ float summed[2 * DD];
    __shared__ float red[2];
    int b = blockIdx.x, tid = threadIdx.x;
    int u = uidx[b], it = iidx[b];
    s[tid] = utab[(size_t)u * DD + tid];
    s[tid + DD] = itab[(size_t)it * DD + tid];
    __syncthreads();
    float acc = ab1[tid];
    for (int k = 0; k < 2 * DD; ++k) acc += s[k] * aw1[k * DD + tid];
    ah[tid] = fmaxf(acc, 0.f);
    __syncthreads();
    if (tid < T_STEPS) {
        float lg = ab2[tid];
        for (int k = 0; k < DD; ++k) lg += ah[k] * aw2[k * T_STEPS + tid];
        attn[tid] = lg;
    }
    __syncthreads();
    if (tid == 0) {
        float m = fmaxf(attn[0], fmaxf(attn[1], attn[2]));
        float e0 = expf(attn[0] - m), e1 = expf(attn[1] - m), e2 = expf(attn[2] - m);
        float inv = 1.f / (e0 + e1 + e2);
        attn[0] = e0 * inv;
        attn[1] = e1 * inv;
        attn[2] = e2 * inv;
    }
    __syncthreads();
    const float* tb = &tstack[(size_t)b * T_STEPS * 2 * DD];
    for (int k = tid; k < 2 * DD; k += 128)
        summed[k] = attn[0] * tb[k] + attn[1] * tb[2 * DD + k] + attn[2] * tb[4 * DD + k];
    __syncthreads();
    float ph = pb1[tid];
    for (int k = 0; k < 2 * DD; ++k) ph += summed[k] * pw1[k * DD + tid];
    ph = fmaxf(ph, 0.f);
    float contrib = ph * pw2[tid];
    for (int off = 32; off > 0; off >>= 1) contrib += __shfl_down(contrib, off, 64);
    if ((tid & 63) == 0) red[tid >> 6] = contrib;
    __syncthreads();
    if (tid == 0) outp[b] = red[0] + red[1] + pb2[0];
}

extern "C" void kernel_launch(void* const* d_in, const int* in_sizes, int n_in,
                              void* d_out, int out_size, void* d_ws, size_t ws_size,
                              hipStream_t stream) {
    const int* uidx = (const int*)d_in[0];
    const int* iidx = (const int*)d_in[1];
    const int* eidx = (const int*)d_in[2];
    const float* adj = (const float*)d_in[3];
    const float* utab = (const float*)d_in[4];
    const float* itab = (const float*)d_in[5];
    const float* temb = (const float*)d_in[6];
    const float* gw = (const float*)d_in[7];
    const float* gb = (const float*)d_in[8];
    const float* aw1 = (const float*)d_in[9];
    const float* ab1 = (const float*)d_in[10];
    const float* aw2 = (const float*)d_in[11];
    const float* ab2 = (const float*)d_in[12];
    const float* pw1 = (const float*)d_in[13];
    const float* pb1 = (const float*)d_in[14];
    const float* pw2 = (const float*)d_in[15];
    const float* pb2 = (const float*)d_in[16];

    char* ws = (char*)d_ws;
    size_t off = 0;
    auto alloc = [&](size_t bytes) {
        void* p = ws + off;
        off += (bytes + 255) & ~(size_t)255;
        return p;
    };
    int* hist = (int*)alloc((size_t)NBLK_BIN * NCOARSE * 4);
    int* exact_base = (int*)alloc((NCOARSE + 1) * 4);
    int* row_ptr = (int*)alloc((size_t)(N_NODES + 1) * 4);
    int2* sorted = (int2*)alloc((size_t)E_CNT * 8);
    float* rvec = (float*)alloc((size_t)N_NODES * 4);
    float* uvec = (float*)alloc((size_t)T_STEPS * DD * 4);
    // union: binned (consumed by k_sort) then Sf (written by k_gemm0 afterwards)
    void* un = alloc((size_t)E_CNT * 8);
    int2* binned = (int2*)un;
    unsigned char* Sf = (unsigned char*)un;
    unsigned short* Pb = (unsigned short*)alloc((size_t)N_NODES * DD * 2);
    float* agg = (float*)alloc((size_t)2 * B_SZ * T_STEPS * DD * 4);
    float* tstack = (float*)alloc((size_t)B_SZ * T_STEPS * 2 * DD * 4);

    k_bin_count<<<NBLK_BIN, 256, 0, stream>>>(eidx, hist);
    k_scan_a<<<1, 512, 0, stream>>>(hist, exact_base, row_ptr);
    k_scan_b<<<NCOARSE, NBLK_BIN, 0, stream>>>(hist, exact_base);
    k_bin_scatter<<<NBLK_BIN, 256, 0, stream>>>(eidx, eidx + E_CNT, adj, hist, binned);
    k_sort<<<NCOARSE, 256, 0, stream>>>(exact_base, binned, sorted, row_ptr);
    // S = x @ W0 (fp8 store, x256) — overwrites binned, which is dead after k_sort
    k_gemm0<<<2048, 256, 0, stream>>>(utab, itab, gw, Sf);
    k_uvec<<<1, DD, 0, stream>>>(temb, gw, uvec);
    // P = A @ S (fp8 -> bf16), r = A @ 1
    k_spmm_full<<<(N_NODES + 3) / 4, 256, 0, stream>>>(row_ptr, (const long long*)sorted,
                                                       Sf, Pb, rvec);
    // agg[slot][t] = A_restricted @ relu(P + r*u_t + b0), all t fused
    k_spmm_out3<<<(2 * B_SZ * 64) / 256, 256, 0, stream>>>(
        row_ptr, (const long long*)sorted, Pb, rvec, uidx, iidx, uvec, gb, agg);
    // tstack = relu(agg @ W1 + b1)
    k_head<<<512, 256, 0, stream>>>(agg, gw + DD * DD, gb + DD, tstack);
    k_final<<<B_SZ, 128, 0, stream>>>(uidx, iidx, utab, itab, aw1, ab1, aw2, ab2, pw1,
                                      pb1, pw2, pb2, tstack, (float*)d_out);
}

// Round 8
// 323.445 us; speedup vs baseline: 4.3252x; 1.1891x over previous
//
#include <hip/hip_runtime.h>

#define U_CNT 50000
#define I_CNT 50000
#define N_NODES 100000
#define DD 128
#define T_STEPS 3
#define E_CNT 3200000
#define B_SZ 4096

#define NCOARSE 391   // ceil(100000 / 256): coarse bucket = dst >> 8
#define NBLK_BIN 256  // binning blocks; each owns a contiguous edge slice
#define CHUNK ((E_CNT + NBLK_BIN - 1) / NBLK_BIN)
#define SORT_CAP 10240
#define S_SCALE 256.0f
#define S_INV (1.0f / 256.0f)

typedef float v2f __attribute__((ext_vector_type(2)));
typedef short bf16x8 __attribute__((ext_vector_type(8)));
typedef float f32x4 __attribute__((ext_vector_type(4)));

__device__ __forceinline__ float bf2f(unsigned short u) {
    return __uint_as_float(((unsigned int)u) << 16);
}
__device__ __forceinline__ unsigned short f2bf(float f) {
    unsigned int x = __float_as_uint(f);
    x += 0x7FFF + ((x >> 16) & 1);
    return (unsigned short)(x >> 16);
}

// ---------------- pass 1: per-block coarse histogram (non-atomic global write) ----------------
__global__ void __launch_bounds__(256) k_bin_count(const int* __restrict__ dst,
                                                   int* __restrict__ hist) {
    __shared__ int c[NCOARSE];
    int blk = blockIdx.x, tid = threadIdx.x;
    for (int j = tid; j < NCOARSE; j += 256) c[j] = 0;
    __syncthreads();
    int s0 = blk * CHUNK, s1 = min(E_CNT, s0 + CHUNK);
    for (int i = s0 + tid; i < s1; i += 256)
        atomicAdd(&c[__builtin_nontemporal_load(&dst[i]) >> 8], 1);
    __syncthreads();
    for (int j = tid; j < NCOARSE; j += 256) hist[blk * NCOARSE + j] = c[j];
}

// ---------------- pass 2a: bucket totals + exclusive bucket bases ----------------
__global__ void __launch_bounds__(512) k_scan_a(const int* __restrict__ hist,
                                                int* __restrict__ exact_base,
                                                int* __restrict__ row_ptr) {
    __shared__ int tot[NCOARSE];
    int tid = threadIdx.x;
    for (int b = tid; b < NCOARSE; b += 512) {
        int s = 0;
        for (int blk = 0; blk < NBLK_BIN; ++blk) s += hist[blk * NCOARSE + b];
        tot[b] = s;
    }
    __syncthreads();
    if (tid == 0) {
        int run = 0;
        for (int b = 0; b < NCOARSE; ++b) {
            exact_base[b] = run;
            run += tot[b];
        }
        exact_base[NCOARSE] = run;
        row_ptr[N_NODES] = run;  // == E_CNT
    }
}

// ---------------- pass 2b: per-bucket scan over blocks -> exclusive (block,bucket) bases ----------------
__global__ void __launch_bounds__(NBLK_BIN) k_scan_b(int* __restrict__ hist,
                                                     const int* __restrict__ exact_base) {
    __shared__ int lds[NBLK_BIN];
    int b = blockIdx.x, tid = threadIdx.x;
    int v = hist[tid * NCOARSE + b];
    lds[tid] = v;
    __syncthreads();
    for (int off = 1; off < NBLK_BIN; off <<= 1) {
        int add = (tid >= off) ? lds[tid - off] : 0;
        __syncthreads();
        lds[tid] += add;
        __syncthreads();
    }
    hist[tid * NCOARSE + b] = exact_base[b] + lds[tid] - v;  // exclusive prefix
}

// ---------------- pass 3: deterministic scatter into exclusive regions ----------------
__global__ void __launch_bounds__(256) k_bin_scatter(const int* __restrict__ dst,
                                                     const int* __restrict__ src,
                                                     const float* __restrict__ val,
                                                     const int* __restrict__ blkbase,
                                                     int2* __restrict__ binned) {
    __shared__ int cur[NCOARSE];
    int blk = blockIdx.x, tid = threadIdx.x;
    for (int b = tid; b < NCOARSE; b += 256) cur[b] = blkbase[blk * NCOARSE + b];
    __syncthreads();
    int s0 = blk * CHUNK, s1 = min(E_CNT, s0 + CHUNK);
    for (int i = s0 + tid; i < s1; i += 256) {
        int d = __builtin_nontemporal_load(&dst[i]);
        int s = __builtin_nontemporal_load(&src[i]);
        float w = __builtin_nontemporal_load(&val[i]);
        int b = d >> 8;
        int pos = atomicAdd(&cur[b], 1);
        binned[pos] = make_int2(s | ((d & 255) << 20), __float_as_int(w));
    }
}

// ---------------- per-bucket exact sort: emit dst-sorted pack + row_ptr ----------------
__global__ void __launch_bounds__(256) k_sort(const int* __restrict__ exact_base,
                                              const int2* __restrict__ binned,
                                              int2* __restrict__ outp,
                                              int* __restrict__ row_ptr) {
    __shared__ int hist[256], scn[256], cur[256];
    __shared__ unsigned short perm[SORT_CAP];
    int b = blockIdx.x, tid = threadIdx.x;
    int ebase = exact_base[b];
    int cnt = exact_base[b + 1] - ebase;
    if (cnt > SORT_CAP) cnt = SORT_CAP;  // safety clamp (never hit for this input)
    const int2* rbase = binned + ebase;
    int n0 = b << 8;
    hist[tid] = 0;
    __syncthreads();
    for (int i = tid; i < cnt; i += 256) atomicAdd(&hist[(rbase[i].x >> 20) & 255], 1);
    __syncthreads();
    scn[tid] = hist[tid];
    __syncthreads();
    for (int off = 1; off < 256; off <<= 1) {
        int v = (tid >= off) ? scn[tid - off] : 0;
        __syncthreads();
        scn[tid] += v;
        __syncthreads();
    }
    int excl = scn[tid] - hist[tid];
    cur[tid] = excl;
    if (n0 + tid < N_NODES) row_ptr[n0 + tid] = ebase + excl;
    __syncthreads();
    for (int i = tid; i < cnt; i += 256) {
        int dloc = (rbase[i].x >> 20) & 255;
        int pos = atomicAdd(&cur[dloc], 1);
        perm[pos] = (unsigned short)i;
    }
    __syncthreads();
    for (int i = tid; i < cnt; i += 256) {
        int2 p = rbase[perm[i]];
        p.x &= 0xFFFFF;
        outp[ebase + i] = p;
    }
}

// u_t = temporal_emb[t] @ W0  (tiny)
__global__ void k_uvec(const float* __restrict__ temb, const float* __restrict__ w0,
                       float* __restrict__ u) {
    int k = threadIdx.x;
    for (int t = 0; t < T_STEPS; ++t) {
        float acc = 0.f;
        for (int j = 0; j < DD; ++j) acc += temb[t * DD + j] * w0[j * DD + k];
        u[t * DD + k] = acc;
    }
}

// ---------------- MFMA GEMM: S = x @ W0 (bf16 MFMA, fp8 e4m3 store, scale 256) ----------------
// W0 staged in LDS as B-fragments for mfma_f32_16x16x32_bf16:
//   frag(c,s): lane l holds W[32s + (l>>4)*8 + j][16c + (l&15)], j=0..7 (bf16x8, 16B)
// A loaded from global per wave: lane l holds x[rbase + (l&15)][32s + (l>>4)*8 + j]
// C/D layout (verified): col = lane&15, row = (lane>>4)*4 + reg
__global__ void __launch_bounds__(256) k_gemm0(const float* __restrict__ utab,
                                               const float* __restrict__ itab,
                                               const float* __restrict__ W,
                                               unsigned char* __restrict__ outf8) {
    __shared__ unsigned short wfrag[8][4][64][8];  // [c][s][lane][j], 32 KB
    int tid = threadIdx.x;
    // build W fragments: coalesced float4 global reads, scattered ds_write_b16
    #pragma unroll
    for (int ii = 0; ii < 16; ++ii) {
        int idx = tid * 64 + ii * 4;
        int k = idx >> 7, n0 = idx & 127;
        float4 w4 = *reinterpret_cast<const float4*>(&W[idx]);
        int s = k >> 5, kb = (k >> 3) & 3, j = k & 7;
        float wv[4] = {w4.x, w4.y, w4.z, w4.w};
        #pragma unroll
        for (int m = 0; m < 4; ++m) {
            int n = n0 + m;
            wfrag[n >> 4][s][(n & 15) | (kb << 4)][j] = f2bf(wv[m]);
        }
    }
    __syncthreads();
    int lane = tid & 63, wid = tid >> 6;
    int r16 = lane & 15, kb = lane >> 4;
    const int ntiles = (N_NODES + 63) / 64;
    for (int tile = blockIdx.x; tile < ntiles; tile += gridDim.x) {
        int wbase = tile * 64 + wid * 16;
        int row = wbase + r16;
        bool ok = row < N_NODES;  // N_NODES % 16 == 0 -> wave-uniform
        const float* xrow = ok ? ((row < U_CNT) ? &utab[(size_t)row * DD]
                                                : &itab[(size_t)(row - U_CNT) * DD])
                               : &utab[0];
        bf16x8 afrag[4];
        #pragma unroll
        for (int s = 0; s < 4; ++s) {
            float4 a0, a1;
            if (ok) {
                a0 = *reinterpret_cast<const float4*>(&xrow[s * 32 + kb * 8]);
                a1 = *reinterpret_cast<const float4*>(&xrow[s * 32 + kb * 8 + 4]);
            } else {
                a0 = make_float4(0.f, 0.f, 0.f, 0.f);
                a1 = a0;
            }
            afrag[s][0] = (short)f2bf(a0.x);
            afrag[s][1] = (short)f2bf(a0.y);
            afrag[s][2] = (short)f2bf(a0.z);
            afrag[s][3] = (short)f2bf(a0.w);
            afrag[s][4] = (short)f2bf(a1.x);
            afrag[s][5] = (short)f2bf(a1.y);
            afrag[s][6] = (short)f2bf(a1.z);
            afrag[s][7] = (short)f2bf(a1.w);
        }
        #pragma unroll
        for (int c = 0; c < 8; ++c) {
            f32x4 acc = {0.f, 0.f, 0.f, 0.f};
            #pragma unroll
            for (int s = 0; s < 4; ++s) {
                bf16x8 bfrag = *reinterpret_cast<bf16x8*>(&wfrag[c][s][lane][0]);
                acc = __builtin_amdgcn_mfma_f32_16x16x32_bf16(afrag[s], bfrag, acc, 0, 0, 0);
            }
            int orow0 = wbase + (lane >> 4) * 4;
            int ocol = c * 16 + (lane & 15);
            #pragma unroll
            for (int r = 0; r < 4; ++r) {
                int orow = orow0 + r;
                if (orow < N_NODES) {
                    unsigned pk = __builtin_amdgcn_cvt_pk_fp8_f32(acc[r] * S_SCALE,
                                                                  acc[r] * S_SCALE, 0, false);
                    outf8[(size_t)orow * DD + ocol] = (unsigned char)(pk & 0xFF);
                }
            }
        }
    }
}

// ---------------- full SpMM: P = A*S (fp8 in, bf16 out), r = A*1 ----------------
// one wave per dst row; 8 edges/iter, 8 lanes x 16B (int4 = 16 fp8 cols) per edge,
// next-iteration pack prefetch to break the pack->gather dependence chain
__global__ void __launch_bounds__(256) k_spmm_full(const int* __restrict__ row_ptr,
                                                   const long long* __restrict__ packll,
                                                   const unsigned char* __restrict__ Sf,
                                                   unsigned short* __restrict__ Pb,
                                                   float* __restrict__ rvec) {
    int wave = (int)((blockIdx.x * blockDim.x + threadIdx.x) >> 6);
    int lane = threadIdx.x & 63;
    if (wave >= N_NODES) return;
    int beg = row_ptr[wave], end = row_ptr[wave + 1];
    int q = lane >> 3;   // which of 8 edges this lane serves
    int cg = lane & 7;   // 8 lanes x 16 cols = 128 cols
    float acc[16];
    #pragma unroll
    for (int j = 0; j < 16; ++j) acc[j] = 0.f;
    float vs = 0.f;
    int e0 = beg + q;
    long long pl = (e0 < end) ? __builtin_nontemporal_load(&packll[e0]) : 0;
    for (int e = beg; e < end; e += 8) {
        long long cur = pl;
        int en = e + 8 + q;
        pl = (en < end) ? __builtin_nontemporal_load(&packll[en]) : 0;
        int sx = (int)(unsigned int)(cur & 0xFFFFFFFFLL);
        float v = __int_as_float((int)(cur >> 32));
        const int4 s4 = *reinterpret_cast<const int4*>(&Sf[((size_t)sx << 7) + (cg << 4)]);
        v2f p01 = __builtin_amdgcn_cvt_pk_f32_fp8(s4.x, false);
        v2f p23 = __builtin_amdgcn_cvt_pk_f32_fp8(s4.x, true);
        v2f p45 = __builtin_amdgcn_cvt_pk_f32_fp8(s4.y, false);
        v2f p67 = __builtin_amdgcn_cvt_pk_f32_fp8(s4.y, true);
        v2f p89 = __builtin_amdgcn_cvt_pk_f32_fp8(s4.z, false);
        v2f pab = __builtin_amdgcn_cvt_pk_f32_fp8(s4.z, true);
        v2f pcd = __builtin_amdgcn_cvt_pk_f32_fp8(s4.w, false);
        v2f pef = __builtin_amdgcn_cvt_pk_f32_fp8(s4.w, true);
        acc[0] += v * p01.x;  acc[1] += v * p01.y;
        acc[2] += v * p23.x;  acc[3] += v * p23.y;
        acc[4] += v * p45.x;  acc[5] += v * p45.y;
        acc[6] += v * p67.x;  acc[7] += v * p67.y;
        acc[8] += v * p89.x;  acc[9] += v * p89.y;
        acc[10] += v * pab.x; acc[11] += v * pab.y;
        acc[12] += v * pcd.x; acc[13] += v * pcd.y;
        acc[14] += v * pef.x; acc[15] += v * pef.y;
        if (cg == 0) vs += v;
    }
    #pragma unroll
    for (int j = 0; j < 16; ++j) {
        acc[j] += __shfl_down(acc[j], 32, 64);
        acc[j] += __shfl_down(acc[j], 16, 64);
        acc[j] += __shfl_down(acc[j], 8, 64);
        acc[j] *= S_INV;
    }
    vs += __shfl_down(vs, 32, 64);
    vs += __shfl_down(vs, 16, 64);
    vs += __shfl_down(vs, 8, 64);
    if (lane < 8) {
        unsigned w0 = ((unsigned)f2bf(acc[1]) << 16) | f2bf(acc[0]);
        unsigned w1 = ((unsigned)f2bf(acc[3]) << 16) | f2bf(acc[2]);
        unsigned w2 = ((unsigned)f2bf(acc[5]) << 16) | f2bf(acc[4]);
        unsigned w3 = ((unsigned)f2bf(acc[7]) << 16) | f2bf(acc[6]);
        unsigned w4 = ((unsigned)f2bf(acc[9]) << 16) | f2bf(acc[8]);
        unsigned w5 = ((unsigned)f2bf(acc[11]) << 16) | f2bf(acc[10]);
        unsigned w6 = ((unsigned)f2bf(acc[13]) << 16) | f2bf(acc[12]);
        unsigned w7 = ((unsigned)f2bf(acc[15]) << 16) | f2bf(acc[14]);
        unsigned short* base = &Pb[((size_t)wave << 7) + (lane << 4)];
        *reinterpret_cast<int4*>(base) = make_int4(w0, w1, w2, w3);
        *reinterpret_cast<int4*>(base + 8) = make_int4(w4, w5, w6, w7);
        if (lane == 0) rvec[wave] = vs;
    }
}

// ---------------- restricted SpMM, all 3 t's fused ----------------
__global__ void __launch_bounds__(256) k_spmm_out3(const int* __restrict__ row_ptr,
                                                   const long long* __restrict__ packll,
                                                   const unsigned short* __restrict__ Pb,
                                                   const float* __restrict__ rvec,
                                                   const int* __restrict__ uidx,
                                                   const int* __restrict__ iidx,
                                                   const float* __restrict__ uvec,
                                                   const float* __restrict__ b0,
                                                   float* __restrict__ agg) {
    int slot = (int)((blockIdx.x * blockDim.x + threadIdx.x) >> 6);
    int lane = threadIdx.x & 63;
    if (slot >= 2 * B_SZ) return;
    int b = slot & (B_SZ - 1), side = slot >> 12;
    int row = side ? (U_CNT + iidx[b]) : uidx[b];
    int beg = row_ptr[row], end = row_ptr[row + 1];
    int half = lane >> 5, cg = lane & 31;
    float u0[4], u1[4], u2[4], bb[4];
    #pragma unroll
    for (int j = 0; j < 4; ++j) {
        int c = cg * 4 + j;
        u0[j] = uvec[c];
        u1[j] = uvec[DD + c];
        u2[j] = uvec[2 * DD + c];
        bb[j] = b0[c];
    }
    float a0[4] = {0, 0, 0, 0}, a1[4] = {0, 0, 0, 0}, a2[4] = {0, 0, 0, 0};
    for (int e = beg; e < end; e += 2) {
        int ee = e + half;
        long long pl = 0;
        if (ee < end) pl = __builtin_nontemporal_load(&packll[ee]);
        int sx = (int)(unsigned int)(pl & 0xFFFFFFFFLL);
        float v = __int_as_float((int)(pl >> 32));
        float rr = rvec[sx];
        ushort4 s4 = *reinterpret_cast<const ushort4*>(&Pb[(size_t)sx * DD + cg * 4]);
        float pc[4] = {bf2f(s4.x), bf2f(s4.y), bf2f(s4.z), bf2f(s4.w)};
        #pragma unroll
        for (int j = 0; j < 4; ++j) {
            float base = pc[j] + bb[j];
            a0[j] += v * fmaxf(base + rr * u0[j], 0.f);
            a1[j] += v * fmaxf(base + rr * u1[j], 0.f);
            a2[j] += v * fmaxf(base + rr * u2[j], 0.f);
        }
    }
    #pragma unroll
    for (int j = 0; j < 4; ++j) {
        a0[j] += __shfl_down(a0[j], 32, 64);
        a1[j] += __shfl_down(a1[j], 32, 64);
        a2[j] += __shfl_down(a2[j], 32, 64);
    }
    if (lane < 32) {
        size_t rb = (size_t)slot * 3;
        float4 o0 = {a0[0], a0[1], a0[2], a0[3]};
        float4 o1 = {a1[0], a1[1], a1[2], a1[3]};
        float4 o2 = {a2[0], a2[1], a2[2], a2[3]};
        *reinterpret_cast<float4*>(&agg[(rb + 0) * DD + lane * 4]) = o0;
        *reinterpret_cast<float4*>(&agg[(rb + 1) * DD + lane * 4]) = o1;
        *reinterpret_cast<float4*>(&agg[(rb + 2) * DD + lane * 4]) = o2;
    }
}

// ---------------- head GEMM: tstack = relu(agg @ W1 + b1) ----------------
__global__ void __launch_bounds__(256) k_head(const float* __restrict__ agg,
                                              const float* __restrict__ W,
                                              const float* __restrict__ b1,
                                              float* __restrict__ tstack) {
    __shared__ float wlds[DD * DD];
    __shared__ float blds[DD];
    __shared__ float hlds[4][4][DD];
    int tid = threadIdx.x;
    for (int i = tid; i < DD * DD / 4; i += 256)
        reinterpret_cast<float4*>(wlds)[i] = reinterpret_cast<const float4*>(W)[i];
    if (tid < DD) blds[tid] = b1[tid];
    __syncthreads();
    int wave = tid >> 6, lane = tid & 63;
    const int NR = 2 * B_SZ * T_STEPS;
    const int ntiles = NR / 16;
    for (int tile = blockIdx.x; tile < ntiles; tile += gridDim.x) {
        int rbase = tile * 16 + wave * 4;
        for (int j = 0; j < 4; ++j) {
            int row = rbase + j;
            hlds[wave][j][lane] = agg[(size_t)row * DD + lane];
            hlds[wave][j][lane + 64] = agg[(size_t)row * DD + lane + 64];
        }
        float2 acc0 = {0.f, 0.f}, acc1 = {0.f, 0.f}, acc2 = {0.f, 0.f}, acc3 = {0.f, 0.f};
        #pragma unroll 8
        for (int k = 0; k < DD; ++k) {
            float2 w2 = *reinterpret_cast<float2*>(&wlds[k * DD + 2 * lane]);
            float hA = hlds[wave][0][k];
            float hB = hlds[wave][1][k];
            float hC = hlds[wave][2][k];
            float hD = hlds[wave][3][k];
            acc0.x += hA * w2.x; acc0.y += hA * w2.y;
            acc1.x += hB * w2.x; acc1.y += hB * w2.y;
            acc2.x += hC * w2.x; acc2.y += hC * w2.y;
            acc3.x += hD * w2.x; acc3.y += hD * w2.y;
        }
        float2 accs[4] = {acc0, acc1, acc2, acc3};
        for (int j = 0; j < 4; ++j) {
            int row = rbase + j;
            int slot = row / 3, t = row - slot * 3;
            int b = slot & (B_SZ - 1), side = slot >> 12;
            float2 o;
            o.x = fmaxf(accs[j].x + blds[2 * lane], 0.f);
            o.y = fmaxf(accs[j].y + blds[2 * lane + 1], 0.f);
            *reinterpret_cast<float2*>(
                &tstack[((size_t)b * T_STEPS + t) * 2 * DD + side * DD + 2 * lane]) = o;
        }
    }
}

// ---------------- attention + prediction head ----------------
__global__ void __launch_bounds__(128) k_final(const int* __restrict__ uidx,
                                               const int* __restrict__ iidx,
                                               const float* __restrict__ utab,
                                               const float* __restrict__ itab,
                                               const float* __restrict__ aw1,
                                               const float* __restrict__ ab1,
                                               const float* __restrict__ aw2,
                                               const float* __restrict__ ab2,
                                               const float* __restrict__ pw1,
                                               const float* __restrict__ pb1,
                                               const float* __restrict__ pw2,
                                               const float* __restrict__ pb2,
                                               const float* __restrict__ tstack,
                                               float* __restrict__ outp) {
    __shared__ float s[2 * DD];
    __shared__ float ah[DD];
    __shared__ float attn[T_STEPS];
    __shared__ float summed[2 * DD];
    __shared__ float red[2];
    int b = blockIdx.x, tid = threadIdx.x;
    int u = uidx[b], it = iidx[b];
    s[tid] = utab[(size_t)u * DD + tid];
    s[tid + DD] = itab[(size_t)it * DD + tid];
    __syncthreads();
    float acc = ab1[tid];
    for (int k = 0; k < 2 * DD; ++k) acc += s[k] * aw1[k * DD + tid];
    ah[tid] = fmaxf(acc, 0.f);
    __syncthreads();
    if (tid < T_STEPS) {
        float lg = ab2[tid];
        for (int k = 0; k < DD; ++k) lg += ah[k] * aw2[k * T_STEPS + tid];
        attn[tid] = lg;
    }
    __syncthreads();
    if (tid == 0) {
        float m = fmaxf(attn[0], fmaxf(attn[1], attn[2]));
        float e0 = expf(attn[0] - m), e1 = expf(attn[1] - m), e2 = expf(attn[2] - m);
        float inv = 1.f / (e0 + e1 + e2);
        attn[0] = e0 * inv;
        attn[1] = e1 * inv;
        attn[2] = e2 * inv;
    }
    __syncthreads();
    const float* tb = &tstack[(size_t)b * T_STEPS * 2 * DD];
    for (int k = tid; k < 2 * DD; k += 128)
        summed[k] = attn[0] * tb[k] + attn[1] * tb[2 * DD + k] + attn[2] * tb[4 * DD + k];
    __syncthreads();
    float ph = pb1[tid];
    for (int k = 0; k < 2 * DD; ++k) ph += summed[k] * pw1[k * DD + tid];
    ph = fmaxf(ph, 0.f);
    float contrib = ph * pw2[tid];
    for (int off = 32; off > 0; off >>= 1) contrib += __shfl_down(contrib, off, 64);
    if ((tid & 63) == 0) red[tid >> 6] = contrib;
    __syncthreads();
    if (tid == 0) outp[b] = red[0] + red[1] + pb2[0];
}

extern "C" void kernel_launch(void* const* d_in, const int* in_sizes, int n_in,
                              void* d_out, int out_size, void* d_ws, size_t ws_size,
                              hipStream_t stream) {
    const int* uidx = (const int*)d_in[0];
    const int* iidx = (const int*)d_in[1];
    const int* eidx = (const int*)d_in[2];
    const float* adj = (const float*)d_in[3];
    const float* utab = (const float*)d_in[4];
    const float* itab = (const float*)d_in[5];
    const float* temb = (const float*)d_in[6];
    const float* gw = (const float*)d_in[7];
    const float* gb = (const float*)d_in[8];
    const float* aw1 = (const float*)d_in[9];
    const float* ab1 = (const float*)d_in[10];
    const float* aw2 = (const float*)d_in[11];
    const float* ab2 = (const float*)d_in[12];
    const float* pw1 = (const float*)d_in[13];
    const float* pb1 = (const float*)d_in[14];
    const float* pw2 = (const float*)d_in[15];
    const float* pb2 = (const float*)d_in[16];

    char* ws = (char*)d_ws;
    size_t off = 0;
    auto alloc = [&](size_t bytes) {
        void* p = ws + off;
        off += (bytes + 255) & ~(size_t)255;
        return p;
    };
    int* hist = (int*)alloc((size_t)NBLK_BIN * NCOARSE * 4);
    int* exact_base = (int*)alloc((NCOARSE + 1) * 4);
    int* row_ptr = (int*)alloc((size_t)(N_NODES + 1) * 4);
    int2* sorted = (int2*)alloc((size_t)E_CNT * 8);
    float* rvec = (float*)alloc((size_t)N_NODES * 4);
    float* uvec = (float*)alloc((size_t)T_STEPS * DD * 4);
    // union: binned (consumed by k_sort) then Sf (written by k_gemm0 afterwards)
    void* un = alloc((size_t)E_CNT * 8);
    int2* binned = (int2*)un;
    unsigned char* Sf = (unsigned char*)un;
    unsigned short* Pb = (unsigned short*)alloc((size_t)N_NODES * DD * 2);
    float* agg = (float*)alloc((size_t)2 * B_SZ * T_STEPS * DD * 4);
    float* tstack = (float*)alloc((size_t)B_SZ * T_STEPS * 2 * DD * 4);

    k_bin_count<<<NBLK_BIN, 256, 0, stream>>>(eidx, hist);
    k_scan_a<<<1, 512, 0, stream>>>(hist, exact_base, row_ptr);
    k_scan_b<<<NCOARSE, NBLK_BIN, 0, stream>>>(hist, exact_base);
    k_bin_scatter<<<NBLK_BIN, 256, 0, stream>>>(eidx, eidx + E_CNT, adj, hist, binned);
    k_sort<<<NCOARSE, 256, 0, stream>>>(exact_base, binned, sorted, row_ptr);
    // S = x @ W0 (MFMA bf16, fp8 store x256) — overwrites binned, dead after k_sort
    k_gemm0<<<512, 256, 0, stream>>>(utab, itab, gw, Sf);
    k_uvec<<<1, DD, 0, stream>>>(temb, gw, uvec);
    // P = A @ S (fp8 -> bf16), r = A @ 1
    k_spmm_full<<<(N_NODES + 3) / 4, 256, 0, stream>>>(row_ptr, (const long long*)sorted,
                                                       Sf, Pb, rvec);
    // agg[slot][t] = A_restricted @ relu(P + r*u_t + b0), all t fused
    k_spmm_out3<<<(2 * B_SZ * 64) / 256, 256, 0, stream>>>(
        row_ptr, (const long long*)sorted, Pb, rvec, uidx, iidx, uvec, gb, agg);
    // tstack = relu(agg @ W1 + b1)
    k_head<<<512, 256, 0, stream>>>(agg, gw + DD * DD, gb + DD, tstack);
    k_final<<<B_SZ, 128, 0, stream>>>(uidx, iidx, utab, itab, aw1, ab1, aw2, ab2, pw1,
                                      pb1, pw2, pb2, tstack, (float*)d_out);
}

// Round 9
// 306.582 us; speedup vs baseline: 4.5631x; 1.0550x over previous
//
#include <hip/hip_runtime.h>

#define U_CNT 50000
#define I_CNT 50000
#define N_NODES 100000
#define DD 128
#define T_STEPS 3
#define E_CNT 3200000
#define B_SZ 4096

#define NCOARSE 391   // ceil(100000 / 256): coarse bucket = dst >> 8
#define NBLK_BIN 256  // binning blocks; each owns a contiguous edge slice
#define CHUNK ((E_CNT + NBLK_BIN - 1) / NBLK_BIN)
#define SORT_CAP 10240
#define S_SCALE 256.0f
#define S_INV (1.0f / 256.0f)
#define VQ 32767.0f
#define VQ_INV (1.0f / 32767.0f)

typedef float v2f __attribute__((ext_vector_type(2)));
typedef short bf16x8 __attribute__((ext_vector_type(8)));
typedef float f32x4 __attribute__((ext_vector_type(4)));

__device__ __forceinline__ float bf2f(unsigned short u) {
    return __uint_as_float(((unsigned int)u) << 16);
}
__device__ __forceinline__ unsigned short f2bf(float f) {
    unsigned int x = __float_as_uint(f);
    x += 0x7FFF + ((x >> 16) & 1);
    return (unsigned short)(x >> 16);
}

// ---------------- pass 1: per-block coarse histogram (non-atomic global write) ----------------
__global__ void __launch_bounds__(256) k_bin_count(const int* __restrict__ dst,
                                                   int* __restrict__ hist) {
    __shared__ int c[NCOARSE];
    int blk = blockIdx.x, tid = threadIdx.x;
    for (int j = tid; j < NCOARSE; j += 256) c[j] = 0;
    __syncthreads();
    int s0 = blk * CHUNK, s1 = min(E_CNT, s0 + CHUNK);
    for (int i = s0 + tid; i < s1; i += 256)
        atomicAdd(&c[__builtin_nontemporal_load(&dst[i]) >> 8], 1);
    __syncthreads();
    for (int j = tid; j < NCOARSE; j += 256) hist[blk * NCOARSE + j] = c[j];
}

// ---------------- pass 2a: bucket totals + exclusive bucket bases ----------------
__global__ void __launch_bounds__(512) k_scan_a(const int* __restrict__ hist,
                                                int* __restrict__ exact_base,
                                                int* __restrict__ row_ptr) {
    __shared__ int tot[NCOARSE];
    int tid = threadIdx.x;
    for (int b = tid; b < NCOARSE; b += 512) {
        int s = 0;
        for (int blk = 0; blk < NBLK_BIN; ++blk) s += hist[blk * NCOARSE + b];
        tot[b] = s;
    }
    __syncthreads();
    if (tid == 0) {
        int run = 0;
        for (int b = 0; b < NCOARSE; ++b) {
            exact_base[b] = run;
            run += tot[b];
        }
        exact_base[NCOARSE] = run;
        row_ptr[N_NODES] = run;  // == E_CNT
    }
}

// ---------------- pass 2b: per-bucket scan over blocks -> exclusive (block,bucket) bases ----------------
__global__ void __launch_bounds__(NBLK_BIN) k_scan_b(int* __restrict__ hist,
                                                     const int* __restrict__ exact_base) {
    __shared__ int lds[NBLK_BIN];
    int b = blockIdx.x, tid = threadIdx.x;
    int v = hist[tid * NCOARSE + b];
    lds[tid] = v;
    __syncthreads();
    for (int off = 1; off < NBLK_BIN; off <<= 1) {
        int add = (tid >= off) ? lds[tid - off] : 0;
        __syncthreads();
        lds[tid] += add;
        __syncthreads();
    }
    hist[tid * NCOARSE + b] = exact_base[b] + lds[tid] - v;  // exclusive prefix
}

// ---------------- pass 3: deterministic scatter into exclusive regions ----------------
__global__ void __launch_bounds__(256) k_bin_scatter(const int* __restrict__ dst,
                                                     const int* __restrict__ src,
                                                     const float* __restrict__ val,
                                                     const int* __restrict__ blkbase,
                                                     int2* __restrict__ binned) {
    __shared__ int cur[NCOARSE];
    int blk = blockIdx.x, tid = threadIdx.x;
    for (int b = tid; b < NCOARSE; b += 256) cur[b] = blkbase[blk * NCOARSE + b];
    __syncthreads();
    int s0 = blk * CHUNK, s1 = min(E_CNT, s0 + CHUNK);
    for (int i = s0 + tid; i < s1; i += 256) {
        int d = __builtin_nontemporal_load(&dst[i]);
        int s = __builtin_nontemporal_load(&src[i]);
        float w = __builtin_nontemporal_load(&val[i]);
        int b = d >> 8;
        int pos = atomicAdd(&cur[b], 1);
        binned[pos] = make_int2(s | ((d & 255) << 20), __float_as_int(w));
    }
}

// ---------------- per-bucket exact sort: emit dst-sorted 4B pack + row_ptr ----------------
// packed edge: (valq:15 << 17) | src:17, valq = round(val * 32767)
__global__ void __launch_bounds__(256) k_sort(const int* __restrict__ exact_base,
                                              const int2* __restrict__ binned,
                                              unsigned int* __restrict__ outp,
                                              int* __restrict__ row_ptr) {
    __shared__ int hist[256], scn[256], cur[256];
    __shared__ unsigned short perm[SORT_CAP];
    int b = blockIdx.x, tid = threadIdx.x;
    int ebase = exact_base[b];
    int cnt = exact_base[b + 1] - ebase;
    if (cnt > SORT_CAP) cnt = SORT_CAP;  // safety clamp (never hit for this input)
    const int2* rbase = binned + ebase;
    int n0 = b << 8;
    hist[tid] = 0;
    __syncthreads();
    for (int i = tid; i < cnt; i += 256) atomicAdd(&hist[(rbase[i].x >> 20) & 255], 1);
    __syncthreads();
    scn[tid] = hist[tid];
    __syncthreads();
    for (int off = 1; off < 256; off <<= 1) {
        int v = (tid >= off) ? scn[tid - off] : 0;
        __syncthreads();
        scn[tid] += v;
        __syncthreads();
    }
    int excl = scn[tid] - hist[tid];
    cur[tid] = excl;
    if (n0 + tid < N_NODES) row_ptr[n0 + tid] = ebase + excl;
    __syncthreads();
    for (int i = tid; i < cnt; i += 256) {
        int dloc = (rbase[i].x >> 20) & 255;
        int pos = atomicAdd(&cur[dloc], 1);
        perm[pos] = (unsigned short)i;
    }
    __syncthreads();
    for (int i = tid; i < cnt; i += 256) {
        int2 p = rbase[perm[i]];
        unsigned vq = (unsigned)(__int_as_float(p.y) * VQ + 0.5f);
        outp[ebase + i] = (vq << 17) | (unsigned)(p.x & 0x1FFFF);
    }
}

// u_t = temporal_emb[t] @ W0  (tiny)
__global__ void k_uvec(const float* __restrict__ temb, const float* __restrict__ w0,
                       float* __restrict__ u) {
    int k = threadIdx.x;
    for (int t = 0; t < T_STEPS; ++t) {
        float acc = 0.f;
        for (int j = 0; j < DD; ++j) acc += temb[t * DD + j] * w0[j * DD + k];
        u[t * DD + k] = acc;
    }
}

// ---------------- MFMA GEMM: S = x @ W0 (bf16 MFMA, fp8 e4m3 store, scale 256) ----------------
__global__ void __launch_bounds__(256) k_gemm0(const float* __restrict__ utab,
                                               const float* __restrict__ itab,
                                               const float* __restrict__ W,
                                               unsigned char* __restrict__ outf8) {
    __shared__ unsigned short wfrag[8][4][64][8];  // [c][s][lane][j], 32 KB
    int tid = threadIdx.x;
    #pragma unroll
    for (int ii = 0; ii < 16; ++ii) {
        int idx = tid * 64 + ii * 4;
        int k = idx >> 7, n0 = idx & 127;
        float4 w4 = *reinterpret_cast<const float4*>(&W[idx]);
        int s = k >> 5, kb = (k >> 3) & 3, j = k & 7;
        float wv[4] = {w4.x, w4.y, w4.z, w4.w};
        #pragma unroll
        for (int m = 0; m < 4; ++m) {
            int n = n0 + m;
            wfrag[n >> 4][s][(n & 15) | (kb << 4)][j] = f2bf(wv[m]);
        }
    }
    __syncthreads();
    int lane = tid & 63, wid = tid >> 6;
    int r16 = lane & 15, kb = lane >> 4;
    const int ntiles = (N_NODES + 63) / 64;
    for (int tile = blockIdx.x; tile < ntiles; tile += gridDim.x) {
        int wbase = tile * 64 + wid * 16;
        int row = wbase + r16;
        bool ok = row < N_NODES;
        const float* xrow = ok ? ((row < U_CNT) ? &utab[(size_t)row * DD]
                                                : &itab[(size_t)(row - U_CNT) * DD])
                               : &utab[0];
        bf16x8 afrag[4];
        #pragma unroll
        for (int s = 0; s < 4; ++s) {
            float4 a0, a1;
            if (ok) {
                a0 = *reinterpret_cast<const float4*>(&xrow[s * 32 + kb * 8]);
                a1 = *reinterpret_cast<const float4*>(&xrow[s * 32 + kb * 8 + 4]);
            } else {
                a0 = make_float4(0.f, 0.f, 0.f, 0.f);
                a1 = a0;
            }
            afrag[s][0] = (short)f2bf(a0.x);
            afrag[s][1] = (short)f2bf(a0.y);
            afrag[s][2] = (short)f2bf(a0.z);
            afrag[s][3] = (short)f2bf(a0.w);
            afrag[s][4] = (short)f2bf(a1.x);
            afrag[s][5] = (short)f2bf(a1.y);
            afrag[s][6] = (short)f2bf(a1.z);
            afrag[s][7] = (short)f2bf(a1.w);
        }
        #pragma unroll
        for (int c = 0; c < 8; ++c) {
            f32x4 acc = {0.f, 0.f, 0.f, 0.f};
            #pragma unroll
            for (int s = 0; s < 4; ++s) {
                bf16x8 bfrag = *reinterpret_cast<bf16x8*>(&wfrag[c][s][lane][0]);
                acc = __builtin_amdgcn_mfma_f32_16x16x32_bf16(afrag[s], bfrag, acc, 0, 0, 0);
            }
            int orow0 = wbase + (lane >> 4) * 4;
            int ocol = c * 16 + (lane & 15);
            #pragma unroll
            for (int r = 0; r < 4; ++r) {
                int orow = orow0 + r;
                if (orow < N_NODES) {
                    unsigned pk = __builtin_amdgcn_cvt_pk_fp8_f32(acc[r] * S_SCALE,
                                                                  acc[r] * S_SCALE, 0, false);
                    outf8[(size_t)orow * DD + ocol] = (unsigned char)(pk & 0xFF);
                }
            }
        }
    }
}

// ---------------- full SpMM: P = A*S (fp8 in, bf16 out), r = A*1 ----------------
// one wave per dst row; 8 edges/iter, 8 lanes x 16B per edge; 4B packed edges;
// packed v2f accumulate (v_pk_fma_f32); next-iter pack prefetch
__global__ void __launch_bounds__(256) k_spmm_full(const int* __restrict__ row_ptr,
                                                   const unsigned int* __restrict__ pack,
                                                   const unsigned char* __restrict__ Sf,
                                                   unsigned short* __restrict__ Pb,
                                                   float* __restrict__ rvec) {
    int wave = (int)((blockIdx.x * blockDim.x + threadIdx.x) >> 6);
    int lane = threadIdx.x & 63;
    if (wave >= N_NODES) return;
    int beg = row_ptr[wave], end = row_ptr[wave + 1];
    int q = lane >> 3;   // which of 8 edges this lane serves
    int cg = lane & 7;   // 8 lanes x 16 cols = 128 cols
    v2f acc[8];
    #pragma unroll
    for (int j = 0; j < 8; ++j) acc[j] = (v2f){0.f, 0.f};
    float vs = 0.f;
    int e0 = beg + q;
    unsigned pl = (e0 < end) ? __builtin_nontemporal_load(&pack[e0]) : 0u;
    for (int e = beg; e < end; e += 8) {
        unsigned cur = pl;
        int en = e + 8 + q;
        pl = (en < end) ? __builtin_nontemporal_load(&pack[en]) : 0u;
        int sx = (int)(cur & 0x1FFFF);
        float v = (float)(cur >> 17) * VQ_INV;
        const int4 s4 = *reinterpret_cast<const int4*>(&Sf[((size_t)sx << 7) + (cg << 4)]);
        v2f vv = {v, v};
        acc[0] += vv * __builtin_amdgcn_cvt_pk_f32_fp8(s4.x, false);
        acc[1] += vv * __builtin_amdgcn_cvt_pk_f32_fp8(s4.x, true);
        acc[2] += vv * __builtin_amdgcn_cvt_pk_f32_fp8(s4.y, false);
        acc[3] += vv * __builtin_amdgcn_cvt_pk_f32_fp8(s4.y, true);
        acc[4] += vv * __builtin_amdgcn_cvt_pk_f32_fp8(s4.z, false);
        acc[5] += vv * __builtin_amdgcn_cvt_pk_f32_fp8(s4.z, true);
        acc[6] += vv * __builtin_amdgcn_cvt_pk_f32_fp8(s4.w, false);
        acc[7] += vv * __builtin_amdgcn_cvt_pk_f32_fp8(s4.w, true);
        if (cg == 0) vs += v;
    }
    float out[16];
    #pragma unroll
    for (int j = 0; j < 8; ++j) {
        out[2 * j] = acc[j].x;
        out[2 * j + 1] = acc[j].y;
    }
    #pragma unroll
    for (int j = 0; j < 16; ++j) {
        out[j] += __shfl_down(out[j], 32, 64);
        out[j] += __shfl_down(out[j], 16, 64);
        out[j] += __shfl_down(out[j], 8, 64);
        out[j] *= S_INV;
    }
    vs += __shfl_down(vs, 32, 64);
    vs += __shfl_down(vs, 16, 64);
    vs += __shfl_down(vs, 8, 64);
    if (lane < 8) {
        unsigned w0 = ((unsigned)f2bf(out[1]) << 16) | f2bf(out[0]);
        unsigned w1 = ((unsigned)f2bf(out[3]) << 16) | f2bf(out[2]);
        unsigned w2 = ((unsigned)f2bf(out[5]) << 16) | f2bf(out[4]);
        unsigned w3 = ((unsigned)f2bf(out[7]) << 16) | f2bf(out[6]);
        unsigned w4 = ((unsigned)f2bf(out[9]) << 16) | f2bf(out[8]);
        unsigned w5 = ((unsigned)f2bf(out[11]) << 16) | f2bf(out[10]);
        unsigned w6 = ((unsigned)f2bf(out[13]) << 16) | f2bf(out[12]);
        unsigned w7 = ((unsigned)f2bf(out[15]) << 16) | f2bf(out[14]);
        unsigned short* base = &Pb[((size_t)wave << 7) + (lane << 4)];
        *reinterpret_cast<int4*>(base) = make_int4(w0, w1, w2, w3);
        *reinterpret_cast<int4*>(base + 8) = make_int4(w4, w5, w6, w7);
        if (lane == 0) rvec[wave] = vs;
    }
}

// ---------------- restricted SpMM, all 3 t's fused ----------------
__global__ void __launch_bounds__(256) k_spmm_out3(const int* __restrict__ row_ptr,
                                                   const unsigned int* __restrict__ pack,
                                                   const unsigned short* __restrict__ Pb,
                                                   const float* __restrict__ rvec,
                                                   const int* __restrict__ uidx,
                                                   const int* __restrict__ iidx,
                                                   const float* __restrict__ uvec,
                                                   const float* __restrict__ b0,
                                                   float* __restrict__ agg) {
    int slot = (int)((blockIdx.x * blockDim.x + threadIdx.x) >> 6);
    int lane = threadIdx.x & 63;
    if (slot >= 2 * B_SZ) return;
    int b = slot & (B_SZ - 1), side = slot >> 12;
    int row = side ? (U_CNT + iidx[b]) : uidx[b];
    int beg = row_ptr[row], end = row_ptr[row + 1];
    int half = lane >> 5, cg = lane & 31;
    float u0[4], u1[4], u2[4], bb[4];
    #pragma unroll
    for (int j = 0; j < 4; ++j) {
        int c = cg * 4 + j;
        u0[j] = uvec[c];
        u1[j] = uvec[DD + c];
        u2[j] = uvec[2 * DD + c];
        bb[j] = b0[c];
    }
    float a0[4] = {0, 0, 0, 0}, a1[4] = {0, 0, 0, 0}, a2[4] = {0, 0, 0, 0};
    for (int e = beg; e < end; e += 2) {
        int ee = e + half;
        unsigned pw = (ee < end) ? __builtin_nontemporal_load(&pack[ee]) : 0u;
        int sx = (int)(pw & 0x1FFFF);
        float v = (float)(pw >> 17) * VQ_INV;
        float rr = rvec[sx];
        ushort4 s4 = *reinterpret_cast<const ushort4*>(&Pb[(size_t)sx * DD + cg * 4]);
        float pc[4] = {bf2f(s4.x), bf2f(s4.y), bf2f(s4.z), bf2f(s4.w)};
        #pragma unroll
        for (int j = 0; j < 4; ++j) {
            float base = pc[j] + bb[j];
            a0[j] += v * fmaxf(base + rr * u0[j], 0.f);
            a1[j] += v * fmaxf(base + rr * u1[j], 0.f);
            a2[j] += v * fmaxf(base + rr * u2[j], 0.f);
        }
    }
    #pragma unroll
    for (int j = 0; j < 4; ++j) {
        a0[j] += __shfl_down(a0[j], 32, 64);
        a1[j] += __shfl_down(a1[j], 32, 64);
        a2[j] += __shfl_down(a2[j], 32, 64);
    }
    if (lane < 32) {
        size_t rb = (size_t)slot * 3;
        float4 o0 = {a0[0], a0[1], a0[2], a0[3]};
        float4 o1 = {a1[0], a1[1], a1[2], a1[3]};
        float4 o2 = {a2[0], a2[1], a2[2], a2[3]};
        *reinterpret_cast<float4*>(&agg[(rb + 0) * DD + lane * 4]) = o0;
        *reinterpret_cast<float4*>(&agg[(rb + 1) * DD + lane * 4]) = o1;
        *reinterpret_cast<float4*>(&agg[(rb + 2) * DD + lane * 4]) = o2;
    }
}

// ---------------- head GEMM (MFMA): tstack = relu(agg @ W1 + b1), scattered store ----------------
__global__ void __launch_bounds__(256) k_head(const float* __restrict__ agg,
                                              const float* __restrict__ W,
                                              const float* __restrict__ b1,
                                              float* __restrict__ tstack) {
    __shared__ unsigned short wfrag[8][4][64][8];  // 32 KB
    __shared__ float blds[DD];
    int tid = threadIdx.x;
    #pragma unroll
    for (int ii = 0; ii < 16; ++ii) {
        int idx = tid * 64 + ii * 4;
        int k = idx >> 7, n0 = idx & 127;
        float4 w4 = *reinterpret_cast<const float4*>(&W[idx]);
        int s = k >> 5, kb = (k >> 3) & 3, j = k & 7;
        float wv[4] = {w4.x, w4.y, w4.z, w4.w};
        #pragma unroll
        for (int m = 0; m < 4; ++m) {
            int n = n0 + m;
            wfrag[n >> 4][s][(n & 15) | (kb << 4)][j] = f2bf(wv[m]);
        }
    }
    if (tid < DD) blds[tid] = b1[tid];
    __syncthreads();
    int lane = tid & 63, wid = tid >> 6;
    int r16 = lane & 15, kb = lane >> 4;
    const int NR = 2 * B_SZ * T_STEPS;  // 24576, divisible by 64
    const int ntiles = NR / 64;
    for (int tile = blockIdx.x; tile < ntiles; tile += gridDim.x) {
        int wbase = tile * 64 + wid * 16;
        int row = wbase + r16;
        const float* arow = &agg[(size_t)row * DD];
        bf16x8 afrag[4];
        #pragma unroll
        for (int s = 0; s < 4; ++s) {
            float4 a0 = *reinterpret_cast<const float4*>(&arow[s * 32 + kb * 8]);
            float4 a1 = *reinterpret_cast<const float4*>(&arow[s * 32 + kb * 8 + 4]);
            afrag[s][0] = (short)f2bf(a0.x);
            afrag[s][1] = (short)f2bf(a0.y);
            afrag[s][2] = (short)f2bf(a0.z);
            afrag[s][3] = (short)f2bf(a0.w);
            afrag[s][4] = (short)f2bf(a1.x);
            afrag[s][5] = (short)f2bf(a1.y);
            afrag[s][6] = (short)f2bf(a1.z);
            afrag[s][7] = (short)f2bf(a1.w);
        }
        #pragma unroll
        for (int c = 0; c < 8; ++c) {
            f32x4 acc = {0.f, 0.f, 0.f, 0.f};
            #pragma unroll
            for (int s = 0; s < 4; ++s) {
                bf16x8 bfrag = *reinterpret_cast<bf16x8*>(&wfrag[c][s][lane][0]);
                acc = __builtin_amdgcn_mfma_f32_16x16x32_bf16(afrag[s], bfrag, acc, 0, 0, 0);
            }
            int orow0 = wbase + (lane >> 4) * 4;
            int ocol = c * 16 + (lane & 15);
            float bb = blds[ocol];
            #pragma unroll
            for (int r = 0; r < 4; ++r) {
                int orow = orow0 + r;
                int slot = orow / 3, t = orow - slot * 3;
                int bi = slot & (B_SZ - 1), side = slot >> 12;
                float o = fmaxf(acc[r] + bb, 0.f);
                tstack[((size_t)bi * T_STEPS + t) * 2 * DD + side * DD + ocol] = o;
            }
        }
    }
}

// ---------------- attention + prediction head ----------------
__global__ void __launch_bounds__(128) k_final(const int* __restrict__ uidx,
                                               const int* __restrict__ iidx,
                                               const float* __restrict__ utab,
                                               const float* __restrict__ itab,
                                               const float* __restrict__ aw1,
                                               const float* __restrict__ ab1,
                                               const float* __restrict__ aw2,
                                               const float* __restrict__ ab2,
                                               const float* __restrict__ pw1,
                                               const float* __restrict__ pb1,
                                               const float* __restrict__ pw2,
                                               const float* __restrict__ pb2,
                                               const float* __restrict__ tstack,
                                               float* __restrict__ outp) {
    __shared__ float s[2 * DD];
    __shared__ float ah[DD];
    __shared__ float attn[T_STEPS];
    __shared__ float summed[2 * DD];
    __shared__ float red[2];
    int b = blockIdx.x, tid = threadIdx.x;
    int u = uidx[b], it = iidx[b];
    s[tid] = utab[(size_t)u * DD + tid];
    s[tid + DD] = itab[(size_t)it * DD + tid];
    __syncthreads();
    float acc = ab1[tid];
    for (int k = 0; k < 2 * DD; ++k) acc += s[k] * aw1[k * DD + tid];
    ah[tid] = fmaxf(acc, 0.f);
    __syncthreads();
    if (tid < T_STEPS) {
        float lg = ab2[tid];
        for (int k = 0; k < DD; ++k) lg += ah[k] * aw2[k * T_STEPS + tid];
        attn[tid] = lg;
    }
    __syncthreads();
    if (tid == 0) {
        float m = fmaxf(attn[0], fmaxf(attn[1], attn[2]));
        float e0 = expf(attn[0] - m), e1 = expf(attn[1] - m), e2 = expf(attn[2] - m);
        float inv = 1.f / (e0 + e1 + e2);
        attn[0] = e0 * inv;
        attn[1] = e1 * inv;
        attn[2] = e2 * inv;
    }
    __syncthreads();
    const float* tb = &tstack[(size_t)b * T_STEPS * 2 * DD];
    for (int k = tid; k < 2 * DD; k += 128)
        summed[k] = attn[0] * tb[k] + attn[1] * tb[2 * DD + k] + attn[2] * tb[4 * DD + k];
    __syncthreads();
    float ph = pb1[tid];
    for (int k = 0; k < 2 * DD; ++k) ph += summed[k] * pw1[k * DD + tid];
    ph = fmaxf(ph, 0.f);
    float contrib = ph * pw2[tid];
    for (int off = 32; off > 0; off >>= 1) contrib += __shfl_down(contrib, off, 64);
    if ((tid & 63) == 0) red[tid >> 6] = contrib;
    __syncthreads();
    if (tid == 0) outp[b] = red[0] + red[1] + pb2[0];
}

extern "C" void kernel_launch(void* const* d_in, const int* in_sizes, int n_in,
                              void* d_out, int out_size, void* d_ws, size_t ws_size,
                              hipStream_t stream) {
    const int* uidx = (const int*)d_in[0];
    const int* iidx = (const int*)d_in[1];
    const int* eidx = (const int*)d_in[2];
    const float* adj = (const float*)d_in[3];
    const float* utab = (const float*)d_in[4];
    const float* itab = (const float*)d_in[5];
    const float* temb = (const float*)d_in[6];
    const float* gw = (const float*)d_in[7];
    const float* gb = (const float*)d_in[8];
    const float* aw1 = (const float*)d_in[9];
    const float* ab1 = (const float*)d_in[10];
    const float* aw2 = (const float*)d_in[11];
    const float* ab2 = (const float*)d_in[12];
    const float* pw1 = (const float*)d_in[13];
    const float* pb1 = (const float*)d_in[14];
    const float* pw2 = (const float*)d_in[15];
    const float* pb2 = (const float*)d_in[16];

    char* ws = (char*)d_ws;
    size_t off = 0;
    auto alloc = [&](size_t bytes) {
        void* p = ws + off;
        off += (bytes + 255) & ~(size_t)255;
        return p;
    };
    int* hist = (int*)alloc((size_t)NBLK_BIN * NCOARSE * 4);
    int* exact_base = (int*)alloc((NCOARSE + 1) * 4);
    int* row_ptr = (int*)alloc((size_t)(N_NODES + 1) * 4);
    unsigned int* sorted = (unsigned int*)alloc((size_t)E_CNT * 4);
    float* rvec = (float*)alloc((size_t)N_NODES * 4);
    float* uvec = (float*)alloc((size_t)T_STEPS * DD * 4);
    // union: binned (consumed by k_sort) then Sf (written by k_gemm0 afterwards)
    void* un = alloc((size_t)E_CNT * 8);
    int2* binned = (int2*)un;
    unsigned char* Sf = (unsigned char*)un;
    unsigned short* Pb = (unsigned short*)alloc((size_t)N_NODES * DD * 2);
    float* agg = (float*)alloc((size_t)2 * B_SZ * T_STEPS * DD * 4);
    float* tstack = (float*)alloc((size_t)B_SZ * T_STEPS * 2 * DD * 4);

    k_bin_count<<<NBLK_BIN, 256, 0, stream>>>(eidx, hist);
    k_scan_a<<<1, 512, 0, stream>>>(hist, exact_base, row_ptr);
    k_scan_b<<<NCOARSE, NBLK_BIN, 0, stream>>>(hist, exact_base);
    k_bin_scatter<<<NBLK_BIN, 256, 0, stream>>>(eidx, eidx + E_CNT, adj, hist, binned);
    k_sort<<<NCOARSE, 256, 0, stream>>>(exact_base, binned, sorted, row_ptr);
    // S = x @ W0 (MFMA bf16, fp8 store x256) — overwrites binned, dead after k_sort
    k_gemm0<<<512, 256, 0, stream>>>(utab, itab, gw, Sf);
    k_uvec<<<1, DD, 0, stream>>>(temb, gw, uvec);
    // P = A @ S (fp8 -> bf16), r = A @ 1
    k_spmm_full<<<(N_NODES + 3) / 4, 256, 0, stream>>>(row_ptr, sorted, Sf, Pb, rvec);
    // agg[slot][t] = A_restricted @ relu(P + r*u_t + b0), all t fused
    k_spmm_out3<<<(2 * B_SZ * 64) / 256, 256, 0, stream>>>(row_ptr, sorted, Pb, rvec,
                                                           uidx, iidx, uvec, gb, agg);
    // tstack = relu(agg @ W1 + b1)  (MFMA)
    k_head<<<384, 256, 0, stream>>>(agg, gw + DD * DD, gb + DD, tstack);
    k_final<<<B_SZ, 128, 0, stream>>>(uidx, iidx, utab, itab, aw1, ab1, aw2, ab2, pw1,
                                      pb1, pw2, pb2, tstack, (float*)d_out);
}

// Round 10
// 303.678 us; speedup vs baseline: 4.6067x; 1.0096x over previous
//
#include <hip/hip_runtime.h>

#define U_CNT 50000
#define I_CNT 50000
#define N_NODES 100000
#define DD 128
#define T_STEPS 3
#define E_CNT 3200000
#define B_SZ 4096

#define NCOARSE 391   // ceil(100000 / 256): coarse bucket = dst >> 8
#define NBLK_BIN 256  // binning blocks; each owns a contiguous edge slice
#define CHUNK ((E_CNT + NBLK_BIN - 1) / NBLK_BIN)
#define SORT_CAP 10240
#define S_SCALE 256.0f
#define S_INV (1.0f / 256.0f)
#define VQ 32767.0f
#define VQ_INV (1.0f / 32767.0f)
#define FB 8   // k_final rows per block

typedef float v2f __attribute__((ext_vector_type(2)));
typedef short bf16x8 __attribute__((ext_vector_type(8)));
typedef float f32x4 __attribute__((ext_vector_type(4)));

__device__ __forceinline__ float bf2f(unsigned short u) {
    return __uint_as_float(((unsigned int)u) << 16);
}
__device__ __forceinline__ unsigned short f2bf(float f) {
    unsigned int x = __float_as_uint(f);
    x += 0x7FFF + ((x >> 16) & 1);
    return (unsigned short)(x >> 16);
}

// ---------------- pass 1: per-block coarse histogram (non-atomic global write) ----------------
__global__ void __launch_bounds__(256) k_bin_count(const int* __restrict__ dst,
                                                   int* __restrict__ hist) {
    __shared__ int c[NCOARSE];
    int blk = blockIdx.x, tid = threadIdx.x;
    for (int j = tid; j < NCOARSE; j += 256) c[j] = 0;
    __syncthreads();
    int s0 = blk * CHUNK, s1 = min(E_CNT, s0 + CHUNK);
    for (int i = s0 + tid; i < s1; i += 256)
        atomicAdd(&c[__builtin_nontemporal_load(&dst[i]) >> 8], 1);
    __syncthreads();
    for (int j = tid; j < NCOARSE; j += 256) hist[blk * NCOARSE + j] = c[j];
}

// ---------------- pass 2a: bucket totals + exclusive bucket bases ----------------
__global__ void __launch_bounds__(512) k_scan_a(const int* __restrict__ hist,
                                                int* __restrict__ exact_base,
                                                int* __restrict__ row_ptr) {
    __shared__ int tot[NCOARSE];
    int tid = threadIdx.x;
    for (int b = tid; b < NCOARSE; b += 512) {
        int s = 0;
        for (int blk = 0; blk < NBLK_BIN; ++blk) s += hist[blk * NCOARSE + b];
        tot[b] = s;
    }
    __syncthreads();
    if (tid == 0) {
        int run = 0;
        for (int b = 0; b < NCOARSE; ++b) {
            exact_base[b] = run;
            run += tot[b];
        }
        exact_base[NCOARSE] = run;
        row_ptr[N_NODES] = run;  // == E_CNT
    }
}

// ---------------- pass 2b: per-bucket scan over blocks -> exclusive (block,bucket) bases ----------------
__global__ void __launch_bounds__(NBLK_BIN) k_scan_b(int* __restrict__ hist,
                                                     const int* __restrict__ exact_base) {
    __shared__ int lds[NBLK_BIN];
    int b = blockIdx.x, tid = threadIdx.x;
    int v = hist[tid * NCOARSE + b];
    lds[tid] = v;
    __syncthreads();
    for (int off = 1; off < NBLK_BIN; off <<= 1) {
        int add = (tid >= off) ? lds[tid - off] : 0;
        __syncthreads();
        lds[tid] += add;
        __syncthreads();
    }
    hist[tid * NCOARSE + b] = exact_base[b] + lds[tid] - v;  // exclusive prefix
}

// ---------------- pass 3: deterministic scatter into exclusive regions ----------------
__global__ void __launch_bounds__(256) k_bin_scatter(const int* __restrict__ dst,
                                                     const int* __restrict__ src,
                                                     const float* __restrict__ val,
                                                     const int* __restrict__ blkbase,
                                                     int2* __restrict__ binned) {
    __shared__ int cur[NCOARSE];
    int blk = blockIdx.x, tid = threadIdx.x;
    for (int b = tid; b < NCOARSE; b += 256) cur[b] = blkbase[blk * NCOARSE + b];
    __syncthreads();
    int s0 = blk * CHUNK, s1 = min(E_CNT, s0 + CHUNK);
    for (int i = s0 + tid; i < s1; i += 256) {
        int d = __builtin_nontemporal_load(&dst[i]);
        int s = __builtin_nontemporal_load(&src[i]);
        float w = __builtin_nontemporal_load(&val[i]);
        int b = d >> 8;
        int pos = atomicAdd(&cur[b], 1);
        binned[pos] = make_int2(s | ((d & 255) << 20), __float_as_int(w));
    }
}

// ---------------- per-bucket exact sort: emit dst-sorted 4B pack + row_ptr ----------------
// packed edge: (valq:15 << 17) | src:17, valq = round(val * 32767)
__global__ void __launch_bounds__(256) k_sort(const int* __restrict__ exact_base,
                                              const int2* __restrict__ binned,
                                              unsigned int* __restrict__ outp,
                                              int* __restrict__ row_ptr) {
    __shared__ int hist[256], scn[256], cur[256];
    __shared__ unsigned short perm[SORT_CAP];
    int b = blockIdx.x, tid = threadIdx.x;
    int ebase = exact_base[b];
    int cnt = exact_base[b + 1] - ebase;
    if (cnt > SORT_CAP) cnt = SORT_CAP;  // safety clamp (never hit for this input)
    const int2* rbase = binned + ebase;
    int n0 = b << 8;
    hist[tid] = 0;
    __syncthreads();
    for (int i = tid; i < cnt; i += 256) atomicAdd(&hist[(rbase[i].x >> 20) & 255], 1);
    __syncthreads();
    scn[tid] = hist[tid];
    __syncthreads();
    for (int off = 1; off < 256; off <<= 1) {
        int v = (tid >= off) ? scn[tid - off] : 0;
        __syncthreads();
        scn[tid] += v;
        __syncthreads();
    }
    int excl = scn[tid] - hist[tid];
    cur[tid] = excl;
    if (n0 + tid < N_NODES) row_ptr[n0 + tid] = ebase + excl;
    __syncthreads();
    for (int i = tid; i < cnt; i += 256) {
        int dloc = (rbase[i].x >> 20) & 255;
        int pos = atomicAdd(&cur[dloc], 1);
        perm[pos] = (unsigned short)i;
    }
    __syncthreads();
    for (int i = tid; i < cnt; i += 256) {
        int2 p = rbase[perm[i]];
        unsigned vq = (unsigned)(__int_as_float(p.y) * VQ + 0.5f);
        outp[ebase + i] = (vq << 17) | (unsigned)(p.x & 0x1FFFF);
    }
}

// u_t = temporal_emb[t] @ W0  (tiny)
__global__ void k_uvec(const float* __restrict__ temb, const float* __restrict__ w0,
                       float* __restrict__ u) {
    int k = threadIdx.x;
    for (int t = 0; t < T_STEPS; ++t) {
        float acc = 0.f;
        for (int j = 0; j < DD; ++j) acc += temb[t * DD + j] * w0[j * DD + k];
        u[t * DD + k] = acc;
    }
}

// ---------------- MFMA GEMM: S = x @ W0 (bf16 MFMA, fp8 e4m3 store, scale 256) ----------------
// x-tile staged coalesced into swizzled row-major bf16 LDS, A-frags via ds_read_b128
__global__ void __launch_bounds__(256) k_gemm0(const float* __restrict__ utab,
                                               const float* __restrict__ itab,
                                               const float* __restrict__ W,
                                               unsigned char* __restrict__ outf8) {
    __shared__ unsigned short wfrag[8][4][64][8];  // [c][s][lane][j], 32 KB
    __shared__ unsigned short xs[64 * 128];        // 16 KB, swizzled row-major
    int tid = threadIdx.x;
    #pragma unroll
    for (int ii = 0; ii < 16; ++ii) {
        int idx = tid * 64 + ii * 4;
        int k = idx >> 7, n0 = idx & 127;
        float4 w4 = *reinterpret_cast<const float4*>(&W[idx]);
        int s = k >> 5, kb = (k >> 3) & 3, j = k & 7;
        float wv[4] = {w4.x, w4.y, w4.z, w4.w};
        #pragma unroll
        for (int m = 0; m < 4; ++m) {
            int n = n0 + m;
            wfrag[n >> 4][s][(n & 15) | (kb << 4)][j] = f2bf(wv[m]);
        }
    }
    int lane = tid & 63, wid = tid >> 6;
    const int ntiles = (N_NODES + 63) / 64;
    for (int tile = blockIdx.x; tile < ntiles; tile += gridDim.x) {
        __syncthreads();  // wfrag ready / xs free from previous tile
        int tbase = tile * 64;
        #pragma unroll
        for (int p = 0; p < 8; ++p) {
            int idx = p * 1024 + tid * 4;
            int row = idx >> 7, c = idx & 127;
            int grow = tbase + row;
            float4 a = make_float4(0.f, 0.f, 0.f, 0.f);
            if (grow < N_NODES) {
                const float* src = (grow < U_CNT) ? &utab[(size_t)grow * DD + c]
                                                  : &itab[(size_t)(grow - U_CNT) * DD + c];
                a = *reinterpret_cast<const float4*>(src);
            }
            int si = (row * 128 + c) ^ ((row & 7) << 3);
            ushort4 o = {f2bf(a.x), f2bf(a.y), f2bf(a.z), f2bf(a.w)};
            *reinterpret_cast<ushort4*>(&xs[si]) = o;
        }
        __syncthreads();
        int rowt = wid * 16 + (lane & 15);
        int kb = lane >> 4;
        bf16x8 afrag[4];
        #pragma unroll
        for (int s = 0; s < 4; ++s) {
            int si = (rowt * 128 + s * 32 + kb * 8) ^ ((rowt & 7) << 3);
            afrag[s] = *reinterpret_cast<bf16x8*>(&xs[si]);
        }
        int wbase = tbase + wid * 16;
        #pragma unroll
        for (int c = 0; c < 8; ++c) {
            f32x4 acc = {0.f, 0.f, 0.f, 0.f};
            #pragma unroll
            for (int s = 0; s < 4; ++s) {
                bf16x8 bfrag = *reinterpret_cast<bf16x8*>(&wfrag[c][s][lane][0]);
                acc = __builtin_amdgcn_mfma_f32_16x16x32_bf16(afrag[s], bfrag, acc, 0, 0, 0);
            }
            int orow0 = wbase + (lane >> 4) * 4;
            int ocol = c * 16 + (lane & 15);
            #pragma unroll
            for (int r = 0; r < 4; ++r) {
                int orow = orow0 + r;
                if (orow < N_NODES) {
                    unsigned pk = __builtin_amdgcn_cvt_pk_fp8_f32(acc[r] * S_SCALE,
                                                                  acc[r] * S_SCALE, 0, false);
                    outf8[(size_t)orow * DD + ocol] = (unsigned char)(pk & 0xFF);
                }
            }
        }
    }
}

// ---------------- full SpMM: P = A*S (fp8 in, bf16 out), r = A*1 ----------------
__global__ void __launch_bounds__(256) k_spmm_full(const int* __restrict__ row_ptr,
                                                   const unsigned int* __restrict__ pack,
                                                   const unsigned char* __restrict__ Sf,
                                                   unsigned short* __restrict__ Pb,
                                                   float* __restrict__ rvec) {
    int wave = (int)((blockIdx.x * blockDim.x + threadIdx.x) >> 6);
    int lane = threadIdx.x & 63;
    if (wave >= N_NODES) return;
    int beg = row_ptr[wave], end = row_ptr[wave + 1];
    int q = lane >> 3;   // which of 8 edges this lane serves
    int cg = lane & 7;   // 8 lanes x 16 cols = 128 cols
    v2f acc[8];
    #pragma unroll
    for (int j = 0; j < 8; ++j) acc[j] = (v2f){0.f, 0.f};
    float vs = 0.f;
    int e0 = beg + q;
    unsigned pl = (e0 < end) ? __builtin_nontemporal_load(&pack[e0]) : 0u;
    for (int e = beg; e < end; e += 8) {
        unsigned cur = pl;
        int en = e + 8 + q;
        pl = (en < end) ? __builtin_nontemporal_load(&pack[en]) : 0u;
        int sx = (int)(cur & 0x1FFFF);
        float v = (float)(cur >> 17) * VQ_INV;
        const int4 s4 = *reinterpret_cast<const int4*>(&Sf[((size_t)sx << 7) + (cg << 4)]);
        v2f vv = {v, v};
        acc[0] += vv * __builtin_amdgcn_cvt_pk_f32_fp8(s4.x, false);
        acc[1] += vv * __builtin_amdgcn_cvt_pk_f32_fp8(s4.x, true);
        acc[2] += vv * __builtin_amdgcn_cvt_pk_f32_fp8(s4.y, false);
        acc[3] += vv * __builtin_amdgcn_cvt_pk_f32_fp8(s4.y, true);
        acc[4] += vv * __builtin_amdgcn_cvt_pk_f32_fp8(s4.z, false);
        acc[5] += vv * __builtin_amdgcn_cvt_pk_f32_fp8(s4.z, true);
        acc[6] += vv * __builtin_amdgcn_cvt_pk_f32_fp8(s4.w, false);
        acc[7] += vv * __builtin_amdgcn_cvt_pk_f32_fp8(s4.w, true);
        if (cg == 0) vs += v;
    }
    float out[16];
    #pragma unroll
    for (int j = 0; j < 8; ++j) {
        out[2 * j] = acc[j].x;
        out[2 * j + 1] = acc[j].y;
    }
    #pragma unroll
    for (int j = 0; j < 16; ++j) {
        out[j] += __shfl_down(out[j], 32, 64);
        out[j] += __shfl_down(out[j], 16, 64);
        out[j] += __shfl_down(out[j], 8, 64);
        out[j] *= S_INV;
    }
    vs += __shfl_down(vs, 32, 64);
    vs += __shfl_down(vs, 16, 64);
    vs += __shfl_down(vs, 8, 64);
    if (lane < 8) {
        unsigned w0 = ((unsigned)f2bf(out[1]) << 16) | f2bf(out[0]);
        unsigned w1 = ((unsigned)f2bf(out[3]) << 16) | f2bf(out[2]);
        unsigned w2 = ((unsigned)f2bf(out[5]) << 16) | f2bf(out[4]);
        unsigned w3 = ((unsigned)f2bf(out[7]) << 16) | f2bf(out[6]);
        unsigned w4 = ((unsigned)f2bf(out[9]) << 16) | f2bf(out[8]);
        unsigned w5 = ((unsigned)f2bf(out[11]) << 16) | f2bf(out[10]);
        unsigned w6 = ((unsigned)f2bf(out[13]) << 16) | f2bf(out[12]);
        unsigned w7 = ((unsigned)f2bf(out[15]) << 16) | f2bf(out[14]);
        unsigned short* base = &Pb[((size_t)wave << 7) + (lane << 4)];
        *reinterpret_cast<int4*>(base) = make_int4(w0, w1, w2, w3);
        *reinterpret_cast<int4*>(base + 8) = make_int4(w4, w5, w6, w7);
        if (lane == 0) rvec[wave] = vs;
    }
}

// ---------------- restricted SpMM, all 3 t's fused ----------------
__global__ void __launch_bounds__(256) k_spmm_out3(const int* __restrict__ row_ptr,
                                                   const unsigned int* __restrict__ pack,
                                                   const unsigned short* __restrict__ Pb,
                                                   const float* __restrict__ rvec,
                                                   const int* __restrict__ uidx,
                                                   const int* __restrict__ iidx,
                                                   const float* __restrict__ uvec,
                                                   const float* __restrict__ b0,
                                                   float* __restrict__ agg) {
    int slot = (int)((blockIdx.x * blockDim.x + threadIdx.x) >> 6);
    int lane = threadIdx.x & 63;
    if (slot >= 2 * B_SZ) return;
    int b = slot & (B_SZ - 1), side = slot >> 12;
    int row = side ? (U_CNT + iidx[b]) : uidx[b];
    int beg = row_ptr[row], end = row_ptr[row + 1];
    int half = lane >> 5, cg = lane & 31;
    float u0[4], u1[4], u2[4], bb[4];
    #pragma unroll
    for (int j = 0; j < 4; ++j) {
        int c = cg * 4 + j;
        u0[j] = uvec[c];
        u1[j] = uvec[DD + c];
        u2[j] = uvec[2 * DD + c];
        bb[j] = b0[c];
    }
    float a0[4] = {0, 0, 0, 0}, a1[4] = {0, 0, 0, 0}, a2[4] = {0, 0, 0, 0};
    for (int e = beg; e < end; e += 2) {
        int ee = e + half;
        unsigned pw = (ee < end) ? __builtin_nontemporal_load(&pack[ee]) : 0u;
        int sx = (int)(pw & 0x1FFFF);
        float v = (float)(pw >> 17) * VQ_INV;
        float rr = rvec[sx];
        ushort4 s4 = *reinterpret_cast<const ushort4*>(&Pb[(size_t)sx * DD + cg * 4]);
        float pc[4] = {bf2f(s4.x), bf2f(s4.y), bf2f(s4.z), bf2f(s4.w)};
        #pragma unroll
        for (int j = 0; j < 4; ++j) {
            float base = pc[j] + bb[j];
            a0[j] += v * fmaxf(base + rr * u0[j], 0.f);
            a1[j] += v * fmaxf(base + rr * u1[j], 0.f);
            a2[j] += v * fmaxf(base + rr * u2[j], 0.f);
        }
    }
    #pragma unroll
    for (int j = 0; j < 4; ++j) {
        a0[j] += __shfl_down(a0[j], 32, 64);
        a1[j] += __shfl_down(a1[j], 32, 64);
        a2[j] += __shfl_down(a2[j], 32, 64);
    }
    if (lane < 32) {
        size_t rb = (size_t)slot * 3;
        float4 o0 = {a0[0], a0[1], a0[2], a0[3]};
        float4 o1 = {a1[0], a1[1], a1[2], a1[3]};
        float4 o2 = {a2[0], a2[1], a2[2], a2[3]};
        *reinterpret_cast<float4*>(&agg[(rb + 0) * DD + lane * 4]) = o0;
        *reinterpret_cast<float4*>(&agg[(rb + 1) * DD + lane * 4]) = o1;
        *reinterpret_cast<float4*>(&agg[(rb + 2) * DD + lane * 4]) = o2;
    }
}

// ---------------- head GEMM (MFMA): tstack = relu(agg @ W1 + b1), staged A ----------------
__global__ void __launch_bounds__(256) k_head(const float* __restrict__ agg,
                                              const float* __restrict__ W,
                                              const float* __restrict__ b1,
                                              float* __restrict__ tstack) {
    __shared__ unsigned short wfrag[8][4][64][8];  // 32 KB
    __shared__ unsigned short xs[64 * 128];        // 16 KB
    __shared__ float blds[DD];
    int tid = threadIdx.x;
    #pragma unroll
    for (int ii = 0; ii < 16; ++ii) {
        int idx = tid * 64 + ii * 4;
        int k = idx >> 7, n0 = idx & 127;
        float4 w4 = *reinterpret_cast<const float4*>(&W[idx]);
        int s = k >> 5, kb = (k >> 3) & 3, j = k & 7;
        float wv[4] = {w4.x, w4.y, w4.z, w4.w};
        #pragma unroll
        for (int m = 0; m < 4; ++m) {
            int n = n0 + m;
            wfrag[n >> 4][s][(n & 15) | (kb << 4)][j] = f2bf(wv[m]);
        }
    }
    if (tid < DD) blds[tid] = b1[tid];
    int lane = tid & 63, wid = tid >> 6;
    const int NR = 2 * B_SZ * T_STEPS;  // 24576, divisible by 64
    const int ntiles = NR / 64;
    for (int tile = blockIdx.x; tile < ntiles; tile += gridDim.x) {
        __syncthreads();
        int tbase = tile * 64;
        #pragma unroll
        for (int p = 0; p < 8; ++p) {
            int idx = p * 1024 + tid * 4;
            int row = idx >> 7, c = idx & 127;
            float4 a = *reinterpret_cast<const float4*>(&agg[(size_t)(tbase + row) * DD + c]);
            int si = (row * 128 + c) ^ ((row & 7) << 3);
            ushort4 o = {f2bf(a.x), f2bf(a.y), f2bf(a.z), f2bf(a.w)};
            *reinterpret_cast<ushort4*>(&xs[si]) = o;
        }
        __syncthreads();
        int rowt = wid * 16 + (lane & 15);
        int kb = lane >> 4;
        bf16x8 afrag[4];
        #pragma unroll
        for (int s = 0; s < 4; ++s) {
            int si = (rowt * 128 + s * 32 + kb * 8) ^ ((rowt & 7) << 3);
            afrag[s] = *reinterpret_cast<bf16x8*>(&xs[si]);
        }
        int wbase = tbase + wid * 16;
        #pragma unroll
        for (int c = 0; c < 8; ++c) {
            f32x4 acc = {0.f, 0.f, 0.f, 0.f};
            #pragma unroll
            for (int s = 0; s < 4; ++s) {
                bf16x8 bfrag = *reinterpret_cast<bf16x8*>(&wfrag[c][s][lane][0]);
                acc = __builtin_amdgcn_mfma_f32_16x16x32_bf16(afrag[s], bfrag, acc, 0, 0, 0);
            }
            int orow0 = wbase + (lane >> 4) * 4;
            int ocol = c * 16 + (lane & 15);
            float bb = blds[ocol];
            #pragma unroll
            for (int r = 0; r < 4; ++r) {
                int orow = orow0 + r;
                int slot = orow / 3, t = orow - slot * 3;
                int bi = slot & (B_SZ - 1), side = slot >> 12;
                float o = fmaxf(acc[r] + bb, 0.f);
                tstack[((size_t)bi * T_STEPS + t) * 2 * DD + side * DD + ocol] = o;
            }
        }
    }
}

// ---------------- attention + prediction head: 8 batch rows per block ----------------
__global__ void __launch_bounds__(256) k_final(const int* __restrict__ uidx,
                                               const int* __restrict__ iidx,
                                               const float* __restrict__ utab,
                                               const float* __restrict__ itab,
                                               const float* __restrict__ aw1,
                                               const float* __restrict__ ab1,
                                               const float* __restrict__ aw2,
                                               const float* __restrict__ ab2,
                                               const float* __restrict__ pw1,
                                               const float* __restrict__ pb1,
                                               const float* __restrict__ pw2,
                                               const float* __restrict__ pb2,
                                               const float* __restrict__ tstack,
                                               float* __restrict__ outp) {
    __shared__ float s[FB][2 * DD];
    __shared__ float ah[FB][DD];
    __shared__ float attn[FB][4];
    __shared__ float summed[FB][2 * DD];
    __shared__ float red[FB][DD];
    __shared__ int uu[FB], ii[FB];
    int b0 = blockIdx.x * FB, tid = threadIdx.x;
    if (tid < FB) {
        uu[tid] = uidx[b0 + tid];
        ii[tid] = iidx[b0 + tid];
    }
    __syncthreads();
    #pragma unroll
    for (int r = 0; r < FB; ++r)
        s[r][tid] = (tid < DD) ? utab[(size_t)uu[r] * DD + tid]
                               : itab[(size_t)ii[r] * DD + (tid - DD)];
    __syncthreads();
    {
        int c = tid & 127, g = tid >> 7;
        float acc0 = ab1[c], acc1 = acc0, acc2 = acc0, acc3 = acc0;
        for (int k = 0; k < 2 * DD; ++k) {
            float w = aw1[k * DD + c];
            acc0 += s[g][k] * w;
            acc1 += s[g + 2][k] * w;
            acc2 += s[g + 4][k] * w;
            acc3 += s[g + 6][k] * w;
        }
        ah[g][c] = fmaxf(acc0, 0.f);
        ah[g + 2][c] = fmaxf(acc1, 0.f);
        ah[g + 4][c] = fmaxf(acc2, 0.f);
        ah[g + 6][c] = fmaxf(acc3, 0.f);
    }
    __syncthreads();
    if (tid < FB * T_STEPS) {
        int r = tid / 3, t = tid - r * 3;
        float lg = ab2[t];
        for (int k = 0; k < DD; ++k) lg += ah[r][k] * aw2[k * T_STEPS + t];
        attn[r][t] = lg;
    }
    __syncthreads();
    if (tid < FB) {
        float m = fmaxf(attn[tid][0], fmaxf(attn[tid][1], attn[tid][2]));
        float e0 = expf(attn[tid][0] - m), e1 = expf(attn[tid][1] - m),
              e2 = expf(attn[tid][2] - m);
        float inv = 1.f / (e0 + e1 + e2);
        attn[tid][0] = e0 * inv;
        attn[tid][1] = e1 * inv;
        attn[tid][2] = e2 * inv;
    }
    __syncthreads();
    #pragma unroll
    for (int r = 0; r < FB; ++r) {
        const float* tb = &tstack[(size_t)(b0 + r) * T_STEPS * 2 * DD];
        summed[r][tid] =
            attn[r][0] * tb[tid] + attn[r][1] * tb[2 * DD + tid] + attn[r][2] * tb[4 * DD + tid];
    }
    __syncthreads();
    {
        int c = tid & 127, g = tid >> 7;
        float p0 = pb1[c], p1 = p0, p2 = p0, p3 = p0;
        for (int k = 0; k < 2 * DD; ++k) {
            float w = pw1[k * DD + c];
            p0 += summed[g][k] * w;
            p1 += summed[g + 2][k] * w;
            p2 += summed[g + 4][k] * w;
            p3 += summed[g + 6][k] * w;
        }
        float wc = pw2[c];
        red[g][c] = fmaxf(p0, 0.f) * wc;
        red[g + 2][c] = fmaxf(p1, 0.f) * wc;
        red[g + 4][c] = fmaxf(p2, 0.f) * wc;
        red[g + 6][c] = fmaxf(p3, 0.f) * wc;
    }
    __syncthreads();
    if (tid < FB) {
        float sum = pb2[0];
        for (int k = 0; k < DD; ++k) sum += red[tid][k];
        outp[b0 + tid] = sum;
    }
}

extern "C" void kernel_launch(void* const* d_in, const int* in_sizes, int n_in,
                              void* d_out, int out_size, void* d_ws, size_t ws_size,
                              hipStream_t stream) {
    const int* uidx = (const int*)d_in[0];
    const int* iidx = (const int*)d_in[1];
    const int* eidx = (const int*)d_in[2];
    const float* adj = (const float*)d_in[3];
    const float* utab = (const float*)d_in[4];
    const float* itab = (const float*)d_in[5];
    const float* temb = (const float*)d_in[6];
    const float* gw = (const float*)d_in[7];
    const float* gb = (const float*)d_in[8];
    const float* aw1 = (const float*)d_in[9];
    const float* ab1 = (const float*)d_in[10];
    const float* aw2 = (const float*)d_in[11];
    const float* ab2 = (const float*)d_in[12];
    const float* pw1 = (const float*)d_in[13];
    const float* pb1 = (const float*)d_in[14];
    const float* pw2 = (const float*)d_in[15];
    const float* pb2 = (const float*)d_in[16];

    char* ws = (char*)d_ws;
    size_t off = 0;
    auto alloc = [&](size_t bytes) {
        void* p = ws + off;
        off += (bytes + 255) & ~(size_t)255;
        return p;
    };
    int* hist = (int*)alloc((size_t)NBLK_BIN * NCOARSE * 4);
    int* exact_base = (int*)alloc((NCOARSE + 1) * 4);
    int* row_ptr = (int*)alloc((size_t)(N_NODES + 1) * 4);
    unsigned int* sorted = (unsigned int*)alloc((size_t)E_CNT * 4);
    float* rvec = (float*)alloc((size_t)N_NODES * 4);
    float* uvec = (float*)alloc((size_t)T_STEPS * DD * 4);
    // union: binned (consumed by k_sort) then Sf (written by k_gemm0 afterwards)
    void* un = alloc((size_t)E_CNT * 8);
    int2* binned = (int2*)un;
    unsigned char* Sf = (unsigned char*)un;
    unsigned short* Pb = (unsigned short*)alloc((size_t)N_NODES * DD * 2);
    float* agg = (float*)alloc((size_t)2 * B_SZ * T_STEPS * DD * 4);
    float* tstack = (float*)alloc((size_t)B_SZ * T_STEPS * 2 * DD * 4);

    k_bin_count<<<NBLK_BIN, 256, 0, stream>>>(eidx, hist);
    k_scan_a<<<1, 512, 0, stream>>>(hist, exact_base, row_ptr);
    k_scan_b<<<NCOARSE, NBLK_BIN, 0, stream>>>(hist, exact_base);
    k_bin_scatter<<<NBLK_BIN, 256, 0, stream>>>(eidx, eidx + E_CNT, adj, hist, binned);
    k_sort<<<NCOARSE, 256, 0, stream>>>(exact_base, binned, sorted, row_ptr);
    // S = x @ W0 (MFMA bf16, fp8 store x256) — overwrites binned, dead after k_sort
    k_gemm0<<<512, 256, 0, stream>>>(utab, itab, gw, Sf);
    k_uvec<<<1, DD, 0, stream>>>(temb, gw, uvec);
    // P = A @ S (fp8 -> bf16), r = A @ 1
    k_spmm_full<<<(N_NODES + 3) / 4, 256, 0, stream>>>(row_ptr, sorted, Sf, Pb, rvec);
    // agg[slot][t] = A_restricted @ relu(P + r*u_t + b0), all t fused
    k_spmm_out3<<<(2 * B_SZ * 64) / 256, 256, 0, stream>>>(row_ptr, sorted, Pb, rvec,
                                                           uidx, iidx, uvec, gb, agg);
    // tstack = relu(agg @ W1 + b1)  (MFMA, staged A)
    k_head<<<384, 256, 0, stream>>>(agg, gw + DD * DD, gb + DD, tstack);
    k_final<<<B_SZ / FB, 256, 0, stream>>>(uidx, iidx, utab, itab, aw1, ab1, aw2, ab2,
                                           pw1, pb1, pw2, pb2, tstack, (float*)d_out);
}